// Round 12
// baseline (604.351 us; speedup 1.0000x reference)
//
#include <hip/hip_runtime.h>
#include <math.h>

#define B_ 8
#define N_ 2048
#define KNN 16

typedef __attribute__((ext_vector_type(4))) float f32x4;
typedef __attribute__((ext_vector_type(8))) short bf16x8;
typedef __attribute__((address_space(3))) unsigned int lds_u32_t;
typedef __attribute__((address_space(1))) const unsigned int glb_u32_t;

__device__ inline unsigned short f2bf(float f) {
    unsigned int x = __float_as_uint(f);
    unsigned int r = (x + 0x7fffu + ((x >> 16) & 1u)) >> 16;  // RNE
    return (unsigned short)r;
}

// Monotone bijection fp32 -> u32 (handles negatives; order-preserving).
__device__ inline unsigned int fflip(float f) {
    unsigned int u = __float_as_uint(f);
    return u ^ (0x80000000u | (unsigned int)((int)u >> 31));
}

// 64-bit shuffle-xor across the 64-lane wave.
__device__ inline unsigned long long shflx64(unsigned long long v, int m) {
    int lo = __shfl_xor((int)(unsigned int)(v & 0xffffffffull), m, 64);
    int hi = __shfl_xor((int)(unsigned int)(v >> 32), m, 64);
    return ((unsigned long long)(unsigned int)hi << 32) | (unsigned int)lo;
}

// Compare-exchange: a=min, b=max (u64 keys are unique -> total order).
__device__ inline void ce(unsigned long long& a, unsigned long long& b) {
    bool c = a < b;
    unsigned long long lo = c ? a : b;
    unsigned long long hi = c ? b : a;
    a = lo;
    b = hi;
}

// Bitonic sort 16 (ascending), fully unrolled, static indices only.
#define SORT16(q)                                                         \
    _Pragma("unroll") for (int kk_ = 2; kk_ <= 16; kk_ <<= 1)             \
    _Pragma("unroll") for (int jj_ = kk_ >> 1; jj_ > 0; jj_ >>= 1)        \
    _Pragma("unroll") for (int ii_ = 0; ii_ < 16; ii_++) {                \
        int ll_ = ii_ ^ jj_;                                              \
        if (ll_ > ii_) {                                                  \
            if ((ii_ & kk_) == 0) ce(q[ii_], q[ll_]);                     \
            else ce(q[ll_], q[ii_]);                                      \
        }                                                                 \
    }

// Bitonic merge 16 (input bitonic -> ascending).
#define MERGE16(q)                                                        \
    _Pragma("unroll") for (int jj_ = 8; jj_ > 0; jj_ >>= 1)               \
    _Pragma("unroll") for (int ii_ = 0; ii_ < 16; ii_++) {                \
        int ll_ = ii_ ^ jj_;                                              \
        if (ll_ > ii_) ce(q[ii_], q[ll_]);                                \
    }

// Reduce 32 keys (kA[16], kB[16]) -> q[16] = sorted ascending local top-16.
#define TOP16OF32(kA, kB, q)                                              \
    SORT16(kA);                                                           \
    SORT16(kB);                                                           \
    _Pragma("unroll") for (int ii_ = 0; ii_ < 16; ii_++) {                \
        unsigned long long b_ = kB[15 - ii_];                             \
        q[ii_] = kA[ii_] < b_ ? kA[ii_] : b_;                             \
    }                                                                     \
    MERGE16(q);

// Extract the wave's 16 smallest keys in ascending order.
#define EXTRACT16(q, op)                                                  \
    for (int r_ = 0; r_ < KNN; r_++) {                                    \
        unsigned long long mk_ = q[0];                                    \
        _Pragma("unroll") for (int s_ = 32; s_ > 0; s_ >>= 1) {           \
            unsigned long long ok_ = shflx64(mk_, s_);                    \
            if (ok_ < mk_) mk_ = ok_;                                     \
        }                                                                 \
        if (lane == 0) (op)[r_] = (int)(mk_ & 2047u);                     \
        bool pop_ = (q[0] == mk_);                                        \
        _Pragma("unroll") for (int t_ = 0; t_ < 15; t_++)                 \
            q[t_] = pop_ ? q[t_ + 1] : q[t_];                             \
        q[15] = pop_ ? ~0ull : q[15];                                     \
    }

// ---------------------------------------------------------------------------
// KNN on 3D input points + fused covariance features (h0 (B,12,N)).
// ---------------------------------------------------------------------------
__global__ __launch_bounds__(256, 4) void knn3_kernel(const float* __restrict__ x,
                                                      int* __restrict__ idx,
                                                      float* __restrict__ h0) {
    __shared__ float px[N_], py[N_], pz[N_];
    int b = blockIdx.y;
    const float* xb = x + (size_t)b * N_ * 3;
    for (int e = threadIdx.x; e < N_; e += 256) {
        px[e] = xb[e * 3 + 0];
        py[e] = xb[e * 3 + 1];
        pz[e] = xb[e * 3 + 2];
    }
    __syncthreads();

    int wave = threadIdx.x >> 6, lane = threadIdx.x & 63;
    int i = blockIdx.x * 4 + wave;
    float qx = px[i], qy = py[i], qz = pz[i];

    unsigned long long kA[16], kB[16];
#pragma unroll
    for (int t = 0; t < 16; t++) {
        int j = lane + t * 64;
        float dx = px[j] - qx, dy = py[j] - qy, dz = pz[j] - qz;
        float d = dx * dx + dy * dy + dz * dz;
        kA[t] = ((unsigned long long)fflip(d) << 11) | (unsigned int)j;
    }
#pragma unroll
    for (int t = 0; t < 16; t++) {
        int j = lane + (t + 16) * 64;
        float dx = px[j] - qx, dy = py[j] - qy, dz = pz[j] - qz;
        float d = dx * dx + dy * dy + dz * dz;
        kB[t] = ((unsigned long long)fflip(d) << 11) | (unsigned int)j;
    }

    unsigned long long q[16];
    TOP16OF32(kA, kB, q);

    int* op = idx + ((size_t)b * N_ + i) * KNN;
    unsigned int jr[16];
#pragma unroll
    for (int r_ = 0; r_ < KNN; r_++) {
        unsigned long long mk_ = q[0];
#pragma unroll
        for (int s_ = 32; s_ > 0; s_ >>= 1) {
            unsigned long long ok_ = shflx64(mk_, s_);
            if (ok_ < mk_) mk_ = ok_;
        }
        jr[r_] = (unsigned int)(mk_ & 2047u);
        if (lane == 0) op[r_] = (int)jr[r_];
        bool pop_ = (q[0] == mk_);
#pragma unroll
        for (int t_ = 0; t_ < 15; t_++) q[t_] = pop_ ? q[t_ + 1] : q[t_];
        q[15] = pop_ ? ~0ull : q[15];
    }

    // fused covariance (same accumulation order as the old cov_kernel)
    float nx[16], ny[16], nz[16];
    float mx = 0.f, my = 0.f, mz = 0.f;
#pragma unroll
    for (int r_ = 0; r_ < 16; r_++) {
        int j = (int)jr[r_];
        nx[r_] = px[j]; ny[r_] = py[j]; nz[r_] = pz[j];
        mx += nx[r_]; my += ny[r_]; mz += nz[r_];
    }
    mx *= (1.f / KNN); my *= (1.f / KNN); mz *= (1.f / KNN);
    float c00 = 0, c01 = 0, c02 = 0, c11 = 0, c12 = 0, c22 = 0;
#pragma unroll
    for (int r_ = 0; r_ < 16; r_++) {
        float dx = nx[r_] - mx, dy = ny[r_] - my, dz = nz[r_] - mz;
        c00 += dx * dx; c01 += dx * dy; c02 += dx * dz;
        c11 += dy * dy; c12 += dy * dz; c22 += dz * dz;
    }
    if (lane == 0) {
        float* hb = h0 + (size_t)b * 12 * N_;
        hb[0 * N_ + i] = qx;
        hb[1 * N_ + i] = qy;
        hb[2 * N_ + i] = qz;
        hb[3 * N_ + i] = c00; hb[4 * N_ + i] = c01; hb[5 * N_ + i] = c02;
        hb[6 * N_ + i] = c01; hb[7 * N_ + i] = c11; hb[8 * N_ + i] = c12;
        hb[9 * N_ + i] = c02; hb[10 * N_ + i] = c12; hb[11 * N_ + i] = c22;
    }
}

// ---------------------------------------------------------------------------
// Old fp32 GEMM (kept only for conv1: C=12 needs bounds checks).
// ---------------------------------------------------------------------------
__global__ __launch_bounds__(256) void gemm_kernel(const float* __restrict__ A,
                                                   const float* __restrict__ X,
                                                   const float* __restrict__ bias,
                                                   float* __restrict__ Y,
                                                   int O, int C) {
    __shared__ float Wt[16][132];
    __shared__ float Xt[16][132];
    const int N = N_;
    int b = blockIdx.z;
    int oB = blockIdx.y * 128, nB = blockIdx.x * 128;
    const float* Xb = X + (size_t)b * C * N;
    int tid = threadIdx.x;
    int tn = tid & 15, to = tid >> 4;

    float acc[8][8];
#pragma unroll
    for (int i = 0; i < 8; i++)
#pragma unroll
        for (int j = 0; j < 8; j++) acc[i][j] = 0.f;

    for (int c0 = 0; c0 < C; c0 += 16) {
#pragma unroll
        for (int r = 0; r < 8; r++) {
            int e = tid + r * 256;
            int k = e & 15, o = e >> 4;
            float v = 0.f;
            if (c0 + k < C && oB + o < O) v = A[(size_t)(oB + o) * C + c0 + k];
            Wt[k][o] = v;
        }
#pragma unroll
        for (int r = 0; r < 8; r++) {
            int e = tid + r * 256;
            int n = e & 127, k = e >> 7;
            float v = 0.f;
            if (c0 + k < C) v = Xb[(size_t)(c0 + k) * N + nB + n];
            Xt[k][n] = v;
        }
        __syncthreads();
#pragma unroll
        for (int k = 0; k < 16; k++) {
            float a[8], xv[8];
#pragma unroll
            for (int i = 0; i < 8; i++) a[i] = Wt[k][to * 8 + i];
#pragma unroll
            for (int m = 0; m < 4; m++) {
                xv[2 * m] = Xt[k][tn * 2 + 32 * m];
                xv[2 * m + 1] = Xt[k][tn * 2 + 32 * m + 1];
            }
#pragma unroll
            for (int i = 0; i < 8; i++)
#pragma unroll
                for (int j = 0; j < 8; j++) acc[i][j] = fmaf(a[i], xv[j], acc[i][j]);
        }
        __syncthreads();
    }

#pragma unroll
    for (int i = 0; i < 8; i++) {
        int o = oB + to * 8 + i;
        if (o >= O) continue;
        float bv = bias[o];
#pragma unroll
        for (int m = 0; m < 4; m++) {
            int n0 = nB + tn * 2 + 32 * m;
            float2 st = make_float2(acc[i][2 * m] + bv, acc[i][2 * m + 1] + bv);
            *reinterpret_cast<float2*>(&Y[((size_t)b * O + o) * N + n0]) = st;
        }
    }
}

// ---------------------------------------------------------------------------
// Symmetric distance GEMM v5: both operands from (z,C,N) (already BN'd);
// float4 micro-tile cols; upper-triangle tiles + mirrored writes. D stored
// as PRE-FLIPPED u32 keys. C%32==0.
// ---------------------------------------------------------------------------
__global__ __launch_bounds__(256, 4) void dgemm_kernel(const float* __restrict__ X,
                                                       const float* __restrict__ nrm,
                                                       float* __restrict__ D,
                                                       int C) {
    __shared__ float Wt[32][132];
    __shared__ float Xt[32][132];
    int bz = blockIdx.z;
    int t = blockIdx.x;
    int bx = (int)((sqrtf(8.f * (float)t + 1.f) - 1.f) * 0.5f);
    while ((bx + 1) * (bx + 2) / 2 <= t) bx++;
    while (bx * (bx + 1) / 2 > t) bx--;
    int by = t - bx * (bx + 1) / 2;  // by <= bx
    int oB = by * 128, nB = bx * 128;
    const float* Xb = X + (size_t)bz * C * N_;
    const float* nb = nrm + (size_t)bz * N_;
    float* Db = D + (size_t)bz * N_ * N_;
    int tid = threadIdx.x;
    int tn = tid & 15, to = tid >> 4;

    float acc[8][8];
#pragma unroll
    for (int i = 0; i < 8; i++)
#pragma unroll
        for (int j = 0; j < 8; j++) acc[i][j] = 0.f;

    for (int c0 = 0; c0 < C; c0 += 32) {
#pragma unroll
        for (int r = 0; r < 4; r++) {
            int e = tid + r * 256;
            int k = e >> 5, n4 = e & 31;
            float4 v = *reinterpret_cast<const float4*>(&Xb[(size_t)(c0 + k) * N_ + oB + n4 * 4]);
            *reinterpret_cast<float4*>(&Wt[k][n4 * 4]) = v;
        }
#pragma unroll
        for (int r = 0; r < 4; r++) {
            int e = tid + r * 256;
            int k = e >> 5, n4 = e & 31;
            float4 v = *reinterpret_cast<const float4*>(&Xb[(size_t)(c0 + k) * N_ + nB + n4 * 4]);
            *reinterpret_cast<float4*>(&Xt[k][n4 * 4]) = v;
        }
        __syncthreads();
#pragma unroll
        for (int k = 0; k < 32; k++) {
            float a[8], xv[8];
            *reinterpret_cast<float4*>(&a[0]) = *reinterpret_cast<const float4*>(&Wt[k][to * 8]);
            *reinterpret_cast<float4*>(&a[4]) = *reinterpret_cast<const float4*>(&Wt[k][to * 8 + 4]);
            *reinterpret_cast<float4*>(&xv[0]) = *reinterpret_cast<const float4*>(&Xt[k][tn * 4]);
            *reinterpret_cast<float4*>(&xv[4]) = *reinterpret_cast<const float4*>(&Xt[k][64 + tn * 4]);
#pragma unroll
            for (int i = 0; i < 8; i++)
#pragma unroll
                for (int j = 0; j < 8; j++) acc[i][j] = fmaf(a[i], xv[j], acc[i][j]);
        }
        __syncthreads();
    }

#pragma unroll
    for (int i = 0; i < 8; i++) {
        int o = oB + to * 8 + i;
        float nr = nb[o];
        int n0 = nB + tn * 4;
        float4 w0, w1;
        w0.x = __uint_as_float(fflip(nr + nb[n0 + 0] - 2.f * acc[i][0]));
        w0.y = __uint_as_float(fflip(nr + nb[n0 + 1] - 2.f * acc[i][1]));
        w0.z = __uint_as_float(fflip(nr + nb[n0 + 2] - 2.f * acc[i][2]));
        w0.w = __uint_as_float(fflip(nr + nb[n0 + 3] - 2.f * acc[i][3]));
        w1.x = __uint_as_float(fflip(nr + nb[n0 + 64] - 2.f * acc[i][4]));
        w1.y = __uint_as_float(fflip(nr + nb[n0 + 65] - 2.f * acc[i][5]));
        w1.z = __uint_as_float(fflip(nr + nb[n0 + 66] - 2.f * acc[i][6]));
        w1.w = __uint_as_float(fflip(nr + nb[n0 + 67] - 2.f * acc[i][7]));
        *reinterpret_cast<float4*>(&Db[(size_t)o * N_ + n0]) = w0;
        *reinterpret_cast<float4*>(&Db[(size_t)o * N_ + n0 + 64]) = w1;
        acc[i][0] = w0.x; acc[i][1] = w0.y; acc[i][2] = w0.z; acc[i][3] = w0.w;
        acc[i][4] = w1.x; acc[i][5] = w1.y; acc[i][6] = w1.z; acc[i][7] = w1.w;
    }

    if (bx != by) {
        for (int p = 0; p < 4; p++) {
            __syncthreads();
            if ((to >> 2) == p) {
                int rl = (to & 3) * 8;
#pragma unroll
                for (int i = 0; i < 8; i++)
#pragma unroll
                    for (int qj = 0; qj < 4; qj++) {
                        Xt[rl + i][tn * 4 + qj] = acc[i][qj];
                        Xt[rl + i][64 + tn * 4 + qj] = acc[i][4 + qj];
                    }
            }
            __syncthreads();
#pragma unroll
            for (int r = 0; r < 4; r++) {
                int e = tid + r * 256;
                int j = e >> 3, i4 = e & 7;
                float4 v;
                v.x = Xt[i4 * 4 + 0][j];
                v.y = Xt[i4 * 4 + 1][j];
                v.z = Xt[i4 * 4 + 2][j];
                v.w = Xt[i4 * 4 + 3][j];
                *reinterpret_cast<float4*>(&Db[(size_t)(nB + j) * N_ + oB + p * 32 + i4 * 4]) = v;
            }
        }
    }
}

// ---------------------------------------------------------------------------
// Conv fp32 GEMM: 64x64 tile, BK=32, float4 micro-tile cols.
// FUSE=1 (XLAYOUT 0): X-load applies y=relu(fmaf(x,xs[c],xh[c])).
// DUALT=1: also write transposed raw output Yt[(b*N+n)*O+o] (bias included).
// ---------------------------------------------------------------------------
template <int XLAYOUT, int FUSE, int DUALT>
__global__ __launch_bounds__(256, 4) void cgemm_kernel(const float* __restrict__ A,
                                                       const float* __restrict__ X,
                                                       const float* __restrict__ bias,
                                                       float* __restrict__ Y,
                                                       int O, int C,
                                                       const float* __restrict__ xs,
                                                       const float* __restrict__ xh,
                                                       float* __restrict__ Yt) {
    __shared__ float Wt[32][68];
    __shared__ float Xt[32][68];
    int b = blockIdx.z;
    int oB = blockIdx.y * 64, nB = blockIdx.x * 64;
    const float* Xb = X + (XLAYOUT == 0 ? (size_t)b * C * N_ : (size_t)b * N_ * C);
    int tid = threadIdx.x;
    int tn = tid & 15, to = tid >> 4;

    float acc[4][4];
#pragma unroll
    for (int i = 0; i < 4; i++)
#pragma unroll
        for (int j = 0; j < 4; j++) acc[i][j] = 0.f;

    for (int c0 = 0; c0 < C; c0 += 32) {
#pragma unroll
        for (int r = 0; r < 2; r++) {
            int e = tid + r * 256;
            int row = e >> 3, c4 = e & 7;
            float4 v = *reinterpret_cast<const float4*>(&A[(size_t)(oB + row) * C + c0 + c4 * 4]);
            Wt[c4 * 4 + 0][row] = v.x;
            Wt[c4 * 4 + 1][row] = v.y;
            Wt[c4 * 4 + 2][row] = v.z;
            Wt[c4 * 4 + 3][row] = v.w;
        }
        if (XLAYOUT == 0) {
#pragma unroll
            for (int r = 0; r < 2; r++) {
                int e = tid + r * 256;
                int k = e >> 4, n4 = e & 15;
                float4 v = *reinterpret_cast<const float4*>(&Xb[(size_t)(c0 + k) * N_ + nB + n4 * 4]);
                if (FUSE) {
                    float sc = xs[c0 + k], sh = xh[c0 + k];
                    v.x = fmaxf(fmaf(v.x, sc, sh), 0.f);
                    v.y = fmaxf(fmaf(v.y, sc, sh), 0.f);
                    v.z = fmaxf(fmaf(v.z, sc, sh), 0.f);
                    v.w = fmaxf(fmaf(v.w, sc, sh), 0.f);
                }
                *reinterpret_cast<float4*>(&Xt[k][n4 * 4]) = v;
            }
        } else {
#pragma unroll
            for (int r = 0; r < 2; r++) {
                int e = tid + r * 256;
                int n = e >> 3, c4 = e & 7;
                float4 v = *reinterpret_cast<const float4*>(&Xb[(size_t)(nB + n) * C + c0 + c4 * 4]);
                Xt[c4 * 4 + 0][n] = v.x;
                Xt[c4 * 4 + 1][n] = v.y;
                Xt[c4 * 4 + 2][n] = v.z;
                Xt[c4 * 4 + 3][n] = v.w;
            }
        }
        __syncthreads();
#pragma unroll
        for (int k = 0; k < 32; k++) {
            float a[4], xv[4];
            *reinterpret_cast<float4*>(&a[0]) = *reinterpret_cast<const float4*>(&Wt[k][to * 4]);
            *reinterpret_cast<float4*>(&xv[0]) = *reinterpret_cast<const float4*>(&Xt[k][tn * 4]);
#pragma unroll
            for (int i = 0; i < 4; i++)
#pragma unroll
                for (int j = 0; j < 4; j++) acc[i][j] = fmaf(a[i], xv[j], acc[i][j]);
        }
        __syncthreads();
    }

    float fin[4][4];
#pragma unroll
    for (int i = 0; i < 4; i++) {
        float bv = bias[oB + to * 4 + i];
#pragma unroll
        for (int j = 0; j < 4; j++) fin[i][j] = acc[i][j] + bv;
    }
#pragma unroll
    for (int i = 0; i < 4; i++) {
        int o = oB + to * 4 + i;
        int n0 = nB + tn * 4;
        float4 st;
        st.x = fin[i][0]; st.y = fin[i][1]; st.z = fin[i][2]; st.w = fin[i][3];
        *reinterpret_cast<float4*>(&Y[((size_t)b * O + o) * N_ + n0]) = st;
    }
    if (DUALT) {
#pragma unroll
        for (int j = 0; j < 4; j++) {
            int n = nB + tn * 4 + j;
            float4 st;
            st.x = fin[0][j]; st.y = fin[1][j]; st.z = fin[2][j]; st.w = fin[3][j];
            *reinterpret_cast<float4*>(&Yt[((size_t)b * N_ + n) * (size_t)O + oB + to * 4]) = st;
        }
    }
}

// ---------------------------------------------------------------------------
// bf16 MFMA GEMM (value path).
// EPI=1 (conv4): no bias/Y — per-block (max,min,sum,sumsq) partials.
// EPI=2 (g2): Y = transposed fp32 (B,N,O) with bias; (sum,sumsq) partials.
// ---------------------------------------------------------------------------
template <int EPI>
__global__ __launch_bounds__(256) void mgemm_kernel(const unsigned short* __restrict__ A,
                                                    const unsigned short* __restrict__ X,
                                                    const float* __restrict__ bias,
                                                    float* __restrict__ Y,
                                                    int O, int C,
                                                    float* __restrict__ part) {
    __shared__ unsigned short At[128 * 64];
    __shared__ unsigned short Bt[128 * 64];
    __shared__ float sred[2][2][64][4];
    int b = blockIdx.z;
    int oB = blockIdx.y * 128, nB = blockIdx.x * 128;
    const unsigned short* Xb = X + (size_t)b * N_ * C;
    int tid = threadIdx.x;
    int lane = tid & 63, w = tid >> 6;
    int wm = w & 1, wn = w >> 1;
    int lr = lane & 15, lg = lane >> 4;
    int lrow = lane >> 3;
    int lcol = ((lane & 7) ^ lrow) * 8;

    f32x4 acc[4][4];
#pragma unroll
    for (int m = 0; m < 4; m++)
#pragma unroll
        for (int n = 0; n < 4; n++) acc[m][n] = (f32x4){0.f, 0.f, 0.f, 0.f};

    for (int c0 = 0; c0 < C; c0 += 64) {
#pragma unroll
        for (int r = 0; r < 4; r++) {
            int seg = r * 4 + w;
            int row = seg * 8 + lrow;
            const unsigned short* ga = &A[(size_t)(oB + row) * C + c0 + lcol];
            const unsigned short* gb = &Xb[(size_t)(nB + row) * C + c0 + lcol];
            __builtin_amdgcn_global_load_lds((glb_u32_t*)ga, (lds_u32_t*)&At[seg * 512], 16, 0, 0);
            __builtin_amdgcn_global_load_lds((glb_u32_t*)gb, (lds_u32_t*)&Bt[seg * 512], 16, 0, 0);
        }
        __syncthreads();
#pragma unroll
        for (int kk = 0; kk < 2; kk++) {
            bf16x8 af[4], bfv[4];
#pragma unroll
            for (int m = 0; m < 4; m++) {
                int row = wm * 64 + m * 16 + lr;
                int slot = (kk * 4 + lg) ^ (lr & 7);
                af[m] = *reinterpret_cast<const bf16x8*>(&At[row * 64 + slot * 8]);
            }
#pragma unroll
            for (int n = 0; n < 4; n++) {
                int row = wn * 64 + n * 16 + lr;
                int slot = (kk * 4 + lg) ^ (lr & 7);
                bfv[n] = *reinterpret_cast<const bf16x8*>(&Bt[row * 64 + slot * 8]);
            }
#pragma unroll
            for (int m = 0; m < 4; m++)
#pragma unroll
                for (int n = 0; n < 4; n++)
                    acc[m][n] = __builtin_amdgcn_mfma_f32_16x16x32_bf16(af[m], bfv[n], acc[m][n], 0, 0, 0);
        }
        __syncthreads();
    }

    if (EPI == 1) {
#pragma unroll
        for (int m = 0; m < 4; m++) {
#pragma unroll
            for (int r = 0; r < 4; r++) {
                float v0 = acc[m][0][r], v1 = acc[m][1][r];
                float v2 = acc[m][2][r], v3 = acc[m][3][r];
                float mx = fmaxf(fmaxf(v0, v1), fmaxf(v2, v3));
                float mn = fminf(fminf(v0, v1), fminf(v2, v3));
                float s = (v0 + v1) + (v2 + v3);
                float s2 = fmaf(v0, v0, fmaf(v1, v1, fmaf(v2, v2, v3 * v3)));
#pragma unroll
                for (int msk = 1; msk <= 8; msk <<= 1) {
                    mx = fmaxf(mx, __shfl_xor(mx, msk, 64));
                    mn = fminf(mn, __shfl_xor(mn, msk, 64));
                    s += __shfl_xor(s, msk, 64);
                    s2 += __shfl_xor(s2, msk, 64);
                }
                if (lr == 0) {
                    int ol = m * 16 + lg * 4 + r;
                    sred[wm][wn][ol][0] = mx;
                    sred[wm][wn][ol][1] = mn;
                    sred[wm][wn][ol][2] = s;
                    sred[wm][wn][ol][3] = s2;
                }
            }
        }
        __syncthreads();
        if (tid < 128) {
            int wmv = tid >> 6, ol = tid & 63;
            float mx = fmaxf(sred[wmv][0][ol][0], sred[wmv][1][ol][0]);
            float mn = fminf(sred[wmv][0][ol][1], sred[wmv][1][ol][1]);
            float s = sred[wmv][0][ol][2] + sred[wmv][1][ol][2];
            float s2 = sred[wmv][0][ol][3] + sred[wmv][1][ol][3];
            int o = oB + wmv * 64 + ol;
            float* pp = &part[((size_t)(o * 8 + b) * 16 + blockIdx.x) * 4];
            pp[0] = mx; pp[1] = mn; pp[2] = s; pp[3] = s2;
        }
    } else {
        // EPI == 2: transposed write + (sum,sumsq) partials
#pragma unroll
        for (int m = 0; m < 4; m++) {
            int o0 = oB + wm * 64 + m * 16 + lg * 4;
            float4 bv = *reinterpret_cast<const float4*>(&bias[o0]);
            float s[4] = {0.f, 0.f, 0.f, 0.f};
            float s2[4] = {0.f, 0.f, 0.f, 0.f};
#pragma unroll
            for (int n = 0; n < 4; n++) {
                int nv = nB + wn * 64 + n * 16 + lr;
                float4 st;
                st.x = acc[m][n][0] + bv.x;
                st.y = acc[m][n][1] + bv.y;
                st.z = acc[m][n][2] + bv.z;
                st.w = acc[m][n][3] + bv.w;
                *reinterpret_cast<float4*>(&Y[((size_t)b * N_ + nv) * (size_t)O + o0]) = st;
                s[0] += st.x; s2[0] = fmaf(st.x, st.x, s2[0]);
                s[1] += st.y; s2[1] = fmaf(st.y, st.y, s2[1]);
                s[2] += st.z; s2[2] = fmaf(st.z, st.z, s2[2]);
                s[3] += st.w; s2[3] = fmaf(st.w, st.w, s2[3]);
            }
#pragma unroll
            for (int r = 0; r < 4; r++) {
#pragma unroll
                for (int msk = 1; msk <= 8; msk <<= 1) {
                    s[r] += __shfl_xor(s[r], msk, 64);
                    s2[r] += __shfl_xor(s2[r], msk, 64);
                }
                if (lr == 0) {
                    int ol = m * 16 + lg * 4 + r;
                    sred[wm][wn][ol][0] = s[r];
                    sred[wm][wn][ol][1] = s2[r];
                }
            }
        }
        __syncthreads();
        if (tid < 128) {
            int wmv = tid >> 6, ol = tid & 63;
            float s = sred[wmv][0][ol][0] + sred[wmv][1][ol][0];
            float s2 = sred[wmv][0][ol][1] + sred[wmv][1][ol][1];
            int o = oB + wmv * 64 + ol;
            float* pp = &part[((size_t)(o * 8 + b) * 16 + blockIdx.x) * 2];
            pp[0] = s; pp[1] = s2;
        }
    }
}

// ---------------------------------------------------------------------------
// g2 stats finish: reduce 8b x 16nb (sum,sumsq) partials -> scale/shift.
// ---------------------------------------------------------------------------
__global__ __launch_bounds__(128) void bnfin_kernel(const float* __restrict__ part,
                                                    const float* __restrict__ gm,
                                                    const float* __restrict__ bt,
                                                    float* __restrict__ scale,
                                                    float* __restrict__ shift) {
    int o = blockIdx.x;
    int t = threadIdx.x;  // 128 = 8 b x 16 nb
    const float* p = &part[((size_t)(o * 8 + (t >> 4)) * 16 + (t & 15)) * 2];
    float s = p[0], s2 = p[1];
#pragma unroll
    for (int msk = 1; msk <= 32; msk <<= 1) {
        s += __shfl_xor(s, msk, 64);
        s2 += __shfl_xor(s2, msk, 64);
    }
    __shared__ float red[4];
    int wv = t >> 6, lane = t & 63;
    if (lane == 0) { red[wv] = s; red[2 + wv] = s2; }
    __syncthreads();
    if (t == 0) {
        float S = red[0] + red[1], S2 = red[2] + red[3];
        float mu = S * (1.f / (B_ * N_));
        float var = S2 * (1.f / (B_ * N_)) - mu * mu;
        float inv = 1.f / sqrtf(var + 1e-5f);
        float sc = gm[o] * inv;
        scale[o] = sc;
        shift[o] = fmaf(-mu, sc, bt[o]);
    }
}

// ---------------------------------------------------------------------------
// g2 apply: (B,N,1024) fp32 -> BN+ReLU -> bf16 (B,N,1024). Elementwise.
// ---------------------------------------------------------------------------
__global__ __launch_bounds__(256) void applycvt_kernel(const float* __restrict__ yt,
                                                       const float* __restrict__ scale,
                                                       const float* __restrict__ shift,
                                                       unsigned short* __restrict__ outh) {
    size_t i = ((size_t)blockIdx.x * 256 + threadIdx.x) * 8;
    int o = (int)(i & 1023u);
    float4 a = *reinterpret_cast<const float4*>(&yt[i]);
    float4 c = *reinterpret_cast<const float4*>(&yt[i + 4]);
    float4 s0 = *reinterpret_cast<const float4*>(&scale[o]);
    float4 s1 = *reinterpret_cast<const float4*>(&scale[o + 4]);
    float4 h0 = *reinterpret_cast<const float4*>(&shift[o]);
    float4 h1 = *reinterpret_cast<const float4*>(&shift[o + 4]);
    unsigned short u[8];
    u[0] = f2bf(fmaxf(fmaf(a.x, s0.x, h0.x), 0.f));
    u[1] = f2bf(fmaxf(fmaf(a.y, s0.y, h0.y), 0.f));
    u[2] = f2bf(fmaxf(fmaf(a.z, s0.z, h0.z), 0.f));
    u[3] = f2bf(fmaxf(fmaf(a.w, s0.w, h0.w), 0.f));
    u[4] = f2bf(fmaxf(fmaf(c.x, s1.x, h1.x), 0.f));
    u[5] = f2bf(fmaxf(fmaf(c.y, s1.y, h1.y), 0.f));
    u[6] = f2bf(fmaxf(fmaf(c.z, s1.z, h1.z), 0.f));
    u[7] = f2bf(fmaxf(fmaf(c.w, s1.w, h1.w), 0.f));
    uint4 pk;
    pk.x = (unsigned)u[0] | ((unsigned)u[1] << 16);
    pk.y = (unsigned)u[2] | ((unsigned)u[3] << 16);
    pk.z = (unsigned)u[4] | ((unsigned)u[5] << 16);
    pk.w = (unsigned)u[6] | ((unsigned)u[7] << 16);
    *reinterpret_cast<uint4*>(&outh[i]) = pk;
}

// ---------------------------------------------------------------------------
// conv4 finish: reduce partials -> BN stats; out = scale*max+shift (min if <0).
// ---------------------------------------------------------------------------
__global__ __launch_bounds__(128) void bnmax_kernel(const float* __restrict__ part,
                                                    const float* __restrict__ gm,
                                                    const float* __restrict__ bt,
                                                    float* __restrict__ out) {
    int o = blockIdx.x;
    int t = threadIdx.x;          // 128 = 8 b x 16 nb
    int b = t >> 4, nb = t & 15;
    const float* p = &part[((size_t)(o * 8 + b) * 16 + nb) * 4];
    float mx = p[0], mn = p[1], s = p[2], s2 = p[3];

    float ss = s, ss2 = s2;
#pragma unroll
    for (int msk = 1; msk <= 32; msk <<= 1) {
        ss += __shfl_xor(ss, msk, 64);
        ss2 += __shfl_xor(ss2, msk, 64);
    }
    __shared__ float red[4];
    int wv = t >> 6, lane = t & 63;
    if (lane == 0) { red[wv] = ss; red[2 + wv] = ss2; }
    __syncthreads();
    float S = red[0] + red[1], S2 = red[2] + red[3];
    float mu = S * (1.f / (B_ * N_));
    float var = S2 * (1.f / (B_ * N_)) - mu * mu;
    float inv = 1.f / sqrtf(var + 1e-5f);
    float sc = gm[o] * inv;
    float sh = fmaf(-mu, sc, bt[o]);

#pragma unroll
    for (int msk = 1; msk <= 8; msk <<= 1) {
        mx = fmaxf(mx, __shfl_xor(mx, msk, 64));
        mn = fminf(mn, __shfl_xor(mn, msk, 64));
    }
    if (nb == 0) out[b * 512 + o] = fmaf(sc, sc >= 0.f ? mx : mn, sh);
}

// ---------------------------------------------------------------------------
// Per-channel BN stats over (B,N)  (unchanged — raw-input, exact order)
// ---------------------------------------------------------------------------
__global__ __launch_bounds__(256) void bnstats_kernel(const float* __restrict__ y,
                                                      const float* __restrict__ gm,
                                                      const float* __restrict__ bt,
                                                      float* __restrict__ scale,
                                                      float* __restrict__ shift, int O) {
    int o = blockIdx.x;
    float s = 0.f, s2 = 0.f;
    for (int e = threadIdx.x; e < B_ * N_; e += 256) {
        int b = e >> 11, n = e & (N_ - 1);
        float v = y[((size_t)b * O + o) * N_ + n];
        s += v;
        s2 = fmaf(v, v, s2);
    }
#pragma unroll
    for (int off = 32; off; off >>= 1) {
        s += __shfl_down(s, off, 64);
        s2 += __shfl_down(s2, off, 64);
    }
    __shared__ float red[8];
    int lane = threadIdx.x & 63, w = threadIdx.x >> 6;
    if (lane == 0) { red[w] = s; red[4 + w] = s2; }
    __syncthreads();
    if (threadIdx.x == 0) {
        s = red[0] + red[1] + red[2] + red[3];
        s2 = red[4] + red[5] + red[6] + red[7];
        float mu = s * (1.f / (B_ * N_));
        float var = s2 * (1.f / (B_ * N_)) - mu * mu;
        float inv = 1.f / sqrtf(var + 1e-5f);
        float sc = gm[o] * inv;
        scale[o] = sc;
        shift[o] = fmaf(-mu, sc, bt[o]);
    }
}

// ---------------------------------------------------------------------------
// Fused BN-apply + norms: reads raw (z,C,N), applies relu(fmaf(v,sc,sh)),
// writes BN'd value back IN PLACE, accumulates squared norm (ascending c —
// same op chain as the old bnapply+norms pair -> bitwise identical).
// ---------------------------------------------------------------------------
__global__ __launch_bounds__(256) void normsbn_kernel(float* __restrict__ h,
                                                      const float* __restrict__ scale,
                                                      const float* __restrict__ shift,
                                                      float* __restrict__ nrm, int C) {
    int b = blockIdx.y;
    int i = blockIdx.x * 256 + threadIdx.x;
    float* hp = h + (size_t)b * C * N_;
    float s = 0.f;
    for (int c = 0; c < C; c++) {
        float v = hp[(size_t)c * N_ + i];
        v = fmaxf(fmaf(v, scale[c], shift[c]), 0.f);
        hp[(size_t)c * N_ + i] = v;
        s = fmaf(v, v, s);
    }
    nrm[(b << 11) + i] = s;
}

// ---------------------------------------------------------------------------
// Top-16 per row of a (4*2048) x 2048 distance block (PRE-FLIPPED u32 keys).
// ---------------------------------------------------------------------------
__global__ __launch_bounds__(256, 4) void topk_kernel(const float* __restrict__ D,
                                                      int* __restrict__ idx) {
    int wave = threadIdx.x >> 6, lane = threadIdx.x & 63;
    int i = blockIdx.x * 4 + wave;
    const unsigned int* dp = (const unsigned int*)(D + (size_t)i * N_);

    unsigned long long kA[16], kB[16];
#pragma unroll
    for (int t = 0; t < 4; t++) {
        uint4 v = *reinterpret_cast<const uint4*>(&dp[t * 256 + lane * 4]);
        int j0 = t * 256 + lane * 4;
        kA[t * 4 + 0] = ((unsigned long long)v.x << 11) | (unsigned int)(j0 + 0);
        kA[t * 4 + 1] = ((unsigned long long)v.y << 11) | (unsigned int)(j0 + 1);
        kA[t * 4 + 2] = ((unsigned long long)v.z << 11) | (unsigned int)(j0 + 2);
        kA[t * 4 + 3] = ((unsigned long long)v.w << 11) | (unsigned int)(j0 + 3);
    }
#pragma unroll
    for (int t = 4; t < 8; t++) {
        uint4 v = *reinterpret_cast<const uint4*>(&dp[t * 256 + lane * 4]);
        int j0 = t * 256 + lane * 4;
        kB[(t - 4) * 4 + 0] = ((unsigned long long)v.x << 11) | (unsigned int)(j0 + 0);
        kB[(t - 4) * 4 + 1] = ((unsigned long long)v.y << 11) | (unsigned int)(j0 + 1);
        kB[(t - 4) * 4 + 2] = ((unsigned long long)v.z << 11) | (unsigned int)(j0 + 2);
        kB[(t - 4) * 4 + 3] = ((unsigned long long)v.w << 11) | (unsigned int)(j0 + 3);
    }

    unsigned long long q[16];
    TOP16OF32(kA, kB, q);

    int* op = idx + (size_t)i * KNN;
    EXTRACT16(q, op);
}

// ---------------------------------------------------------------------------
// Gather 16 neighbor RAW fp32 rows (B,N,C), apply BN+ReLU per element, max
// over k -> BN'd fp32 (B,N,C). Per-element op chain == old bnapply+gathermax.
// ---------------------------------------------------------------------------
__global__ __launch_bounds__(256) void gathermax_kernel(const float* __restrict__ ftraw,
                                                        const int* __restrict__ idx,
                                                        const float* __restrict__ scale,
                                                        const float* __restrict__ shift,
                                                        float* __restrict__ out, int cLog) {
    int C = 1 << cLog;
    int b = blockIdx.y;
    int nb = (blockIdx.x << (8 - cLog)) + (threadIdx.x >> cLog);
    int c = threadIdx.x & (C - 1);
    float sc = scale[c], sh = shift[c];
    const int* ip = idx + (((size_t)b << 11) + nb) * KNN;
    float m = -3.4e38f;
#pragma unroll
    for (int k = 0; k < KNN; k++) {
        int j = ip[k];
        float v = ftraw[(((size_t)b << 11) + j) * C + c];
        m = fmaxf(m, fmaxf(fmaf(v, sc, sh), 0.f));
    }
    out[(((size_t)b << 11) + nb) * C + c] = m;
}

// ---------------------------------------------------------------------------
// Gather-max: RAW fp32 (B,N,128) in, BN+ReLU per element, max -> bf16.
// ---------------------------------------------------------------------------
__global__ __launch_bounds__(256) void gmaxh2_kernel(const float* __restrict__ ftraw,
                                                     const int* __restrict__ idx,
                                                     const float* __restrict__ scale,
                                                     const float* __restrict__ shift,
                                                     unsigned short* __restrict__ out) {
    const int C = 128;
    int b = blockIdx.y;
    int nb = blockIdx.x * 16 + (threadIdx.x >> 4);
    int cc = (threadIdx.x & 15) * 8;
    float4 s0 = *reinterpret_cast<const float4*>(&scale[cc]);
    float4 s1 = *reinterpret_cast<const float4*>(&scale[cc + 4]);
    float4 h0 = *reinterpret_cast<const float4*>(&shift[cc]);
    float4 h1 = *reinterpret_cast<const float4*>(&shift[cc + 4]);
    const int* ip = idx + (((size_t)b << 11) + nb) * KNN;
    float m[8];
#pragma unroll
    for (int q = 0; q < 8; q++) m[q] = -3.4e38f;
#pragma unroll
    for (int k = 0; k < KNN; k++) {
        int j = ip[k];
        const float* p = &ftraw[(((size_t)b << 11) + j) * C + cc];
        float4 a = *reinterpret_cast<const float4*>(p);
        float4 c2 = *reinterpret_cast<const float4*>(p + 4);
        m[0] = fmaxf(m[0], fmaxf(fmaf(a.x, s0.x, h0.x), 0.f));
        m[1] = fmaxf(m[1], fmaxf(fmaf(a.y, s0.y, h0.y), 0.f));
        m[2] = fmaxf(m[2], fmaxf(fmaf(a.z, s0.z, h0.z), 0.f));
        m[3] = fmaxf(m[3], fmaxf(fmaf(a.w, s0.w, h0.w), 0.f));
        m[4] = fmaxf(m[4], fmaxf(fmaf(c2.x, s1.x, h1.x), 0.f));
        m[5] = fmaxf(m[5], fmaxf(fmaf(c2.y, s1.y, h1.y), 0.f));
        m[6] = fmaxf(m[6], fmaxf(fmaf(c2.z, s1.z, h1.z), 0.f));
        m[7] = fmaxf(m[7], fmaxf(fmaf(c2.w, s1.w, h1.w), 0.f));
    }
    unsigned short u[8];
#pragma unroll
    for (int q = 0; q < 8; q++) u[q] = f2bf(m[q]);
    uint4 pk;
    pk.x = (unsigned)u[0] | ((unsigned)u[1] << 16);
    pk.y = (unsigned)u[2] | ((unsigned)u[3] << 16);
    pk.z = (unsigned)u[4] | ((unsigned)u[5] << 16);
    pk.w = (unsigned)u[6] | ((unsigned)u[7] << 16);
    *reinterpret_cast<uint4*>(&out[(((size_t)b << 11) + nb) * C + cc]) = pk;
}

// ---------------------------------------------------------------------------
// fp32 -> bf16 weight conversion (both value-path weight arrays, one launch)
// ---------------------------------------------------------------------------
__global__ __launch_bounds__(256) void wcvt2_kernel(const float* __restrict__ w1,
                                                    unsigned short* __restrict__ o1, int c1,
                                                    const float* __restrict__ w2,
                                                    unsigned short* __restrict__ o2, int c2) {
    int i = blockIdx.x * 256 + threadIdx.x;
    if (i < c1) o1[i] = f2bf(w1[i]);
    else if (i < c1 + c2) o2[i - c1] = f2bf(w2[i - c1]);
}

// ---------------------------------------------------------------------------
extern "C" void kernel_launch(void* const* d_in, const int* in_sizes, int n_in,
                              void* d_out, int out_size, void* d_ws, size_t ws_size,
                              hipStream_t stream) {
    const float* x = (const float*)d_in[0];
    const float* W1 = (const float*)d_in[1];
    const float* b1 = (const float*)d_in[2];
    const float* gm1 = (const float*)d_in[3];
    const float* bt1 = (const float*)d_in[4];
    const float* W2 = (const float*)d_in[5];
    const float* b2 = (const float*)d_in[6];
    const float* gm2 = (const float*)d_in[7];
    const float* bt2 = (const float*)d_in[8];
    const float* W3 = (const float*)d_in[9];
    const float* b3 = (const float*)d_in[10];
    const float* gm3 = (const float*)d_in[11];
    const float* bt3 = (const float*)d_in[12];
    const float* Wg1 = (const float*)d_in[13];
    const float* bg1 = (const float*)d_in[14];
    const float* gmg1 = (const float*)d_in[15];
    const float* btg1 = (const float*)d_in[16];
    const float* Wg2 = (const float*)d_in[17];
    const float* bg2 = (const float*)d_in[18];
    const float* gmg2 = (const float*)d_in[19];
    const float* btg2 = (const float*)d_in[20];
    const float* W4 = (const float*)d_in[21];
    const float* b4 = (const float*)d_in[22];
    const float* gm4 = (const float*)d_in[23];
    const float* bt4 = (const float*)d_in[24];
    float* out = (float*)d_out;
    (void)b4;

    // ---- workspace arena (byte offsets), total 154,214,400 bytes ----
    if (ws_size < 154214400ull) return;
    char* base = (char*)d_ws;
    float* scale = (float*)(base + 0);
    float* shift = (float*)(base + 4096);
    float* nrm = (float*)(base + 8192);
    int* idx = (int*)(base + 73728);
    unsigned short* Wg2h = (unsigned short*)(base + 1122304);
    unsigned short* W4h = (unsigned short*)(base + 1384448);
    // bufD4 (distance keys) / bufLt (g2 transposed fp32 out) share the region.
    float* bufD4 = (float*)(base + 19210240);
    float* bufLt = (float*)(base + 19210240);                   // (8,2048,1024) f32
    unsigned short* bufLh = (unsigned short*)(base + 86319104); // (8,2048,1024) bf16
    char* E = base + 119873536;                                 // early region
    float* h0 = (float*)(E + 0);                                // (8,12,2048)
    float* bufA = (float*)(E + 786432);                         // (8,64,2048)
    float* bufB = (float*)(E + 4980736);                        // (8,64,2048)
    float* bufC = (float*)(E + 9175040);                        // (8,2048,64) raw
    float* bufM1 = (float*)(E + 13369344);                      // (8,128,2048)
    float* bufM2 = (float*)(E + 21757952);                      // (8,2048,128) raw
    unsigned short* bufM3h = (unsigned short*)(E + 30146560);   // (8,2048,128) bf16
    float* part = (float*)(E + 0);   // partials (<=1 MB), early bufs dead by g2

    // weight conversion (value-path weights, single launch)
    wcvt2_kernel<<<2560, 256, 0, stream>>>(Wg2, Wg2h, 1024 * 128, W4, W4h, 512 * 1024);

    // Stage 0/1: 3D KNN + fused covariance features
    knn3_kernel<<<dim3(512, 8), 256, 0, stream>>>(x, idx, h0);

    // conv1: 12 -> 64 (fp32); raw output, BN1 fused into conv2
    gemm_kernel<<<dim3(16, 1, 8), 256, 0, stream>>>(W1, h0, b1, bufA, 64, 12);
    bnstats_kernel<<<64, 256, 0, stream>>>(bufA, gm1, bt1, scale, shift, 64);

    // conv2: 64 -> 64 (BN1+ReLU fused on load); raw out, BN2 fused next
    cgemm_kernel<0, 1, 0><<<dim3(32, 1, 8), 256, 0, stream>>>(W2, bufA, b2, bufB, 64, 64, scale, shift, nullptr);
    bnstats_kernel<<<64, 256, 0, stream>>>(bufB, gm2, bt2, scale, shift, 64);

    // conv3: 64 -> 64 (BN2+ReLU fused on load) -> raw bufA + raw bufC (dual)
    cgemm_kernel<0, 1, 1><<<dim3(32, 1, 8), 256, 0, stream>>>(W3, bufB, b3, bufA, 64, 64, scale, shift, bufC);
    bnstats_kernel<<<64, 256, 0, stream>>>(bufA, gm3, bt3, scale, shift, 64);

    // graph layer 1 KNN: normsbn BN's bufA in place + norms; dist + topk
    normsbn_kernel<<<dim3(8, 8), 256, 0, stream>>>(bufA, scale, shift, nrm, 64);
    for (int c = 0; c < 2; c++) {
        dgemm_kernel<<<dim3(136, 1, 4), 256, 0, stream>>>(
            bufA + (size_t)c * 4 * 64 * N_, nrm + (size_t)c * 4 * N_, bufD4, 64);
        topk_kernel<<<2048, 256, 0, stream>>>(bufD4, idx + (size_t)c * 4 * N_ * KNN);
    }
    gathermax_kernel<<<dim3(512, 8), 256, 0, stream>>>(bufC, idx, scale, shift, bufB, 6);

    // conv g1: 64 -> 128 (input (B,N,64) BN'd) -> raw bufM1 + raw bufM2 (dual)
    cgemm_kernel<1, 0, 1><<<dim3(32, 2, 8), 256, 0, stream>>>(Wg1, bufB, bg1, bufM1, 128, 64, nullptr, nullptr, bufM2);
    bnstats_kernel<<<128, 256, 0, stream>>>(bufM1, gmg1, btg1, scale, shift, 128);

    // graph layer 2 KNN: normsbn BN's bufM1 in place + norms; dist + topk
    normsbn_kernel<<<dim3(8, 8), 256, 0, stream>>>(bufM1, scale, shift, nrm, 128);
    for (int c = 0; c < 2; c++) {
        dgemm_kernel<<<dim3(136, 1, 4), 256, 0, stream>>>(
            bufM1 + (size_t)c * 4 * 128 * N_, nrm + (size_t)c * 4 * N_, bufD4, 128);
        topk_kernel<<<2048, 256, 0, stream>>>(bufD4, idx + (size_t)c * 4 * N_ * KNN);
    }
    gmaxh2_kernel<<<dim3(128, 8), 256, 0, stream>>>(bufM2, idx, scale, shift, bufM3h);

    // conv g2: 128 -> 1024 (bf16 MFMA, transposed fp32 out + fused stats)
    mgemm_kernel<2><<<dim3(16, 8, 8), 256, 0, stream>>>(Wg2h, bufM3h, bg2, bufLt, 1024, 128, part);
    bnfin_kernel<<<1024, 128, 0, stream>>>(part, gmg2, btg2, scale, shift);
    applycvt_kernel<<<8192, 256, 0, stream>>>(bufLt, scale, shift, bufLh);

    // conv4: 1024 -> 512 (bf16 MFMA, fused BN-stats+max epilogue)
    mgemm_kernel<1><<<dim3(16, 4, 8), 256, 0, stream>>>(W4h, bufLh, nullptr, nullptr, 512, 1024, part);
    bnmax_kernel<<<512, 128, 0, stream>>>(part, gm4, bt4, out);
}

// Round 13
// 515.597 us; speedup vs baseline: 1.1721x; 1.1721x over previous
//
#include <hip/hip_runtime.h>
#include <math.h>

#define B_ 8
#define N_ 2048
#define KNN 16

typedef __attribute__((ext_vector_type(4))) float f32x4;
typedef __attribute__((ext_vector_type(8))) short bf16x8;
typedef __attribute__((ext_vector_type(8))) _Float16 f16x8;
typedef __attribute__((address_space(3))) unsigned int lds_u32_t;
typedef __attribute__((address_space(1))) const unsigned int glb_u32_t;

__device__ inline unsigned short f2bf(float f) {
    unsigned int x = __float_as_uint(f);
    unsigned int r = (x + 0x7fffu + ((x >> 16) & 1u)) >> 16;  // RNE
    return (unsigned short)r;
}

// Monotone bijection fp32 -> u32 (handles negatives; order-preserving).
__device__ inline unsigned int fflip(float f) {
    unsigned int u = __float_as_uint(f);
    return u ^ (0x80000000u | (unsigned int)((int)u >> 31));
}

// 64-bit shuffle-xor across the 64-lane wave.
__device__ inline unsigned long long shflx64(unsigned long long v, int m) {
    int lo = __shfl_xor((int)(unsigned int)(v & 0xffffffffull), m, 64);
    int hi = __shfl_xor((int)(unsigned int)(v >> 32), m, 64);
    return ((unsigned long long)(unsigned int)hi << 32) | (unsigned int)lo;
}

// Compare-exchange: a=min, b=max (u64 keys are unique -> total order).
__device__ inline void ce(unsigned long long& a, unsigned long long& b) {
    bool c = a < b;
    unsigned long long lo = c ? a : b;
    unsigned long long hi = c ? b : a;
    a = lo;
    b = hi;
}

// Bitonic sort 16 (ascending), fully unrolled, static indices only.
#define SORT16(q)                                                         \
    _Pragma("unroll") for (int kk_ = 2; kk_ <= 16; kk_ <<= 1)             \
    _Pragma("unroll") for (int jj_ = kk_ >> 1; jj_ > 0; jj_ >>= 1)        \
    _Pragma("unroll") for (int ii_ = 0; ii_ < 16; ii_++) {                \
        int ll_ = ii_ ^ jj_;                                              \
        if (ll_ > ii_) {                                                  \
            if ((ii_ & kk_) == 0) ce(q[ii_], q[ll_]);                     \
            else ce(q[ll_], q[ii_]);                                      \
        }                                                                 \
    }

// Bitonic merge 16 (input bitonic -> ascending).
#define MERGE16(q)                                                        \
    _Pragma("unroll") for (int jj_ = 8; jj_ > 0; jj_ >>= 1)               \
    _Pragma("unroll") for (int ii_ = 0; ii_ < 16; ii_++) {                \
        int ll_ = ii_ ^ jj_;                                              \
        if (ll_ > ii_) ce(q[ii_], q[ll_]);                                \
    }

// Reduce 32 keys (kA[16], kB[16]) -> q[16] = sorted ascending local top-16.
#define TOP16OF32(kA, kB, q)                                              \
    SORT16(kA);                                                           \
    SORT16(kB);                                                           \
    _Pragma("unroll") for (int ii_ = 0; ii_ < 16; ii_++) {                \
        unsigned long long b_ = kB[15 - ii_];                             \
        q[ii_] = kA[ii_] < b_ ? kA[ii_] : b_;                             \
    }                                                                     \
    MERGE16(q);

// Extract the wave's 16 smallest keys in ascending order.
#define EXTRACT16(q, op)                                                  \
    for (int r_ = 0; r_ < KNN; r_++) {                                    \
        unsigned long long mk_ = q[0];                                    \
        _Pragma("unroll") for (int s_ = 32; s_ > 0; s_ >>= 1) {           \
            unsigned long long ok_ = shflx64(mk_, s_);                    \
            if (ok_ < mk_) mk_ = ok_;                                     \
        }                                                                 \
        if (lane == 0) (op)[r_] = (int)(mk_ & 2047u);                     \
        bool pop_ = (q[0] == mk_);                                        \
        _Pragma("unroll") for (int t_ = 0; t_ < 15; t_++)                 \
            q[t_] = pop_ ? q[t_ + 1] : q[t_];                             \
        q[15] = pop_ ? ~0ull : q[15];                                     \
    }

// ---------------------------------------------------------------------------
// KNN on 3D input points + fused covariance features (h0 (B,12,N)).
// ---------------------------------------------------------------------------
__global__ __launch_bounds__(256, 4) void knn3_kernel(const float* __restrict__ x,
                                                      int* __restrict__ idx,
                                                      float* __restrict__ h0) {
    __shared__ float px[N_], py[N_], pz[N_];
    int b = blockIdx.y;
    const float* xb = x + (size_t)b * N_ * 3;
    for (int e = threadIdx.x; e < N_; e += 256) {
        px[e] = xb[e * 3 + 0];
        py[e] = xb[e * 3 + 1];
        pz[e] = xb[e * 3 + 2];
    }
    __syncthreads();

    int wave = threadIdx.x >> 6, lane = threadIdx.x & 63;
    int i = blockIdx.x * 4 + wave;
    float qx = px[i], qy = py[i], qz = pz[i];

    unsigned long long kA[16], kB[16];
#pragma unroll
    for (int t = 0; t < 16; t++) {
        int j = lane + t * 64;
        float dx = px[j] - qx, dy = py[j] - qy, dz = pz[j] - qz;
        float d = dx * dx + dy * dy + dz * dz;
        kA[t] = ((unsigned long long)fflip(d) << 11) | (unsigned int)j;
    }
#pragma unroll
    for (int t = 0; t < 16; t++) {
        int j = lane + (t + 16) * 64;
        float dx = px[j] - qx, dy = py[j] - qy, dz = pz[j] - qz;
        float d = dx * dx + dy * dy + dz * dz;
        kB[t] = ((unsigned long long)fflip(d) << 11) | (unsigned int)j;
    }

    unsigned long long q[16];
    TOP16OF32(kA, kB, q);

    int* op = idx + ((size_t)b * N_ + i) * KNN;
    unsigned int jr[16];
#pragma unroll
    for (int r_ = 0; r_ < KNN; r_++) {
        unsigned long long mk_ = q[0];
#pragma unroll
        for (int s_ = 32; s_ > 0; s_ >>= 1) {
            unsigned long long ok_ = shflx64(mk_, s_);
            if (ok_ < mk_) mk_ = ok_;
        }
        jr[r_] = (unsigned int)(mk_ & 2047u);
        if (lane == 0) op[r_] = (int)jr[r_];
        bool pop_ = (q[0] == mk_);
#pragma unroll
        for (int t_ = 0; t_ < 15; t_++) q[t_] = pop_ ? q[t_ + 1] : q[t_];
        q[15] = pop_ ? ~0ull : q[15];
    }

    float nx[16], ny[16], nz[16];
    float mx = 0.f, my = 0.f, mz = 0.f;
#pragma unroll
    for (int r_ = 0; r_ < 16; r_++) {
        int j = (int)jr[r_];
        nx[r_] = px[j]; ny[r_] = py[j]; nz[r_] = pz[j];
        mx += nx[r_]; my += ny[r_]; mz += nz[r_];
    }
    mx *= (1.f / KNN); my *= (1.f / KNN); mz *= (1.f / KNN);
    float c00 = 0, c01 = 0, c02 = 0, c11 = 0, c12 = 0, c22 = 0;
#pragma unroll
    for (int r_ = 0; r_ < 16; r_++) {
        float dx = nx[r_] - mx, dy = ny[r_] - my, dz = nz[r_] - mz;
        c00 += dx * dx; c01 += dx * dy; c02 += dx * dz;
        c11 += dy * dy; c12 += dy * dz; c22 += dz * dz;
    }
    if (lane == 0) {
        float* hb = h0 + (size_t)b * 12 * N_;
        hb[0 * N_ + i] = qx;
        hb[1 * N_ + i] = qy;
        hb[2 * N_ + i] = qz;
        hb[3 * N_ + i] = c00; hb[4 * N_ + i] = c01; hb[5 * N_ + i] = c02;
        hb[6 * N_ + i] = c01; hb[7 * N_ + i] = c11; hb[8 * N_ + i] = c12;
        hb[9 * N_ + i] = c02; hb[10 * N_ + i] = c12; hb[11 * N_ + i] = c22;
    }
}

// ---------------------------------------------------------------------------
// Old fp32 GEMM (kept only for conv1: C=12 needs bounds checks).
// ---------------------------------------------------------------------------
__global__ __launch_bounds__(256) void gemm_kernel(const float* __restrict__ A,
                                                   const float* __restrict__ X,
                                                   const float* __restrict__ bias,
                                                   float* __restrict__ Y,
                                                   int O, int C) {
    __shared__ float Wt[16][132];
    __shared__ float Xt[16][132];
    const int N = N_;
    int b = blockIdx.z;
    int oB = blockIdx.y * 128, nB = blockIdx.x * 128;
    const float* Xb = X + (size_t)b * C * N;
    int tid = threadIdx.x;
    int tn = tid & 15, to = tid >> 4;

    float acc[8][8];
#pragma unroll
    for (int i = 0; i < 8; i++)
#pragma unroll
        for (int j = 0; j < 8; j++) acc[i][j] = 0.f;

    for (int c0 = 0; c0 < C; c0 += 16) {
#pragma unroll
        for (int r = 0; r < 8; r++) {
            int e = tid + r * 256;
            int k = e & 15, o = e >> 4;
            float v = 0.f;
            if (c0 + k < C && oB + o < O) v = A[(size_t)(oB + o) * C + c0 + k];
            Wt[k][o] = v;
        }
#pragma unroll
        for (int r = 0; r < 8; r++) {
            int e = tid + r * 256;
            int n = e & 127, k = e >> 7;
            float v = 0.f;
            if (c0 + k < C) v = Xb[(size_t)(c0 + k) * N + nB + n];
            Xt[k][n] = v;
        }
        __syncthreads();
#pragma unroll
        for (int k = 0; k < 16; k++) {
            float a[8], xv[8];
#pragma unroll
            for (int i = 0; i < 8; i++) a[i] = Wt[k][to * 8 + i];
#pragma unroll
            for (int m = 0; m < 4; m++) {
                xv[2 * m] = Xt[k][tn * 2 + 32 * m];
                xv[2 * m + 1] = Xt[k][tn * 2 + 32 * m + 1];
            }
#pragma unroll
            for (int i = 0; i < 8; i++)
#pragma unroll
                for (int j = 0; j < 8; j++) acc[i][j] = fmaf(a[i], xv[j], acc[i][j]);
        }
        __syncthreads();
    }

#pragma unroll
    for (int i = 0; i < 8; i++) {
        int o = oB + to * 8 + i;
        if (o >= O) continue;
        float bv = bias[o];
#pragma unroll
        for (int m = 0; m < 4; m++) {
            int n0 = nB + tn * 2 + 32 * m;
            float2 st = make_float2(acc[i][2 * m] + bv, acc[i][2 * m + 1] + bv);
            *reinterpret_cast<float2*>(&Y[((size_t)b * O + o) * N + n0]) = st;
        }
    }
}

// ---------------------------------------------------------------------------
// BN+ReLU + transpose + f16 two-term split: raw (z,C,N) fp32 -> Fh/Fl
// (z,N,C) f16.  v = hi + lo, |v-hi-lo| <= 2^-22 |v|.
// ---------------------------------------------------------------------------
__global__ __launch_bounds__(256) void splitbn_kernel(const float* __restrict__ y,
                                                      const float* __restrict__ scale,
                                                      const float* __restrict__ shift,
                                                      _Float16* __restrict__ fh,
                                                      _Float16* __restrict__ fl, int O) {
    __shared__ float tile[64][65];
    int b = blockIdx.z;
    int n0 = blockIdx.x * 64, o0 = blockIdx.y * 64;
    int t = threadIdx.x;
#pragma unroll
    for (int rr = 0; rr < 16; rr++) {
        int ol = rr * 4 + (t >> 6), nl = t & 63;
        float v = y[((size_t)b * O + o0 + ol) * N_ + n0 + nl];
        v = fmaf(v, scale[o0 + ol], shift[o0 + ol]);
        tile[ol][nl] = fmaxf(v, 0.f);
    }
    __syncthreads();
#pragma unroll
    for (int rr = 0; rr < 2; rr++) {
        int e = t + rr * 256;
        int n = e >> 3, og = (e & 7) * 8;
        f16x8 hv, lv;
#pragma unroll
        for (int j = 0; j < 8; j++) {
            float v = tile[og + j][n];
            _Float16 h = (_Float16)v;
            hv[j] = h;
            lv[j] = (_Float16)(v - (float)h);
        }
        size_t off = ((size_t)b * N_ + n0 + n) * O + o0 + og;
        *reinterpret_cast<uint4*>(&fh[off]) = *reinterpret_cast<uint4*>(&hv);
        *reinterpret_cast<uint4*>(&fl[off]) = *reinterpret_cast<uint4*>(&lv);
    }
}

// ---------------------------------------------------------------------------
// Norms from split f16 (z,N,C): s = sum_c (hi+lo)^2, ascending c.
// ---------------------------------------------------------------------------
__global__ __launch_bounds__(256) void normsh_kernel(const _Float16* __restrict__ fh,
                                                     const _Float16* __restrict__ fl,
                                                     float* __restrict__ nrm, int C) {
    int b = blockIdx.y;
    int i = blockIdx.x * 256 + threadIdx.x;
    const _Float16* ph = fh + ((size_t)(b << 11) + i) * C;
    const _Float16* pl = fl + ((size_t)(b << 11) + i) * C;
    float s = 0.f;
    for (int c = 0; c < C; c += 8) {
        f16x8 h = *reinterpret_cast<const f16x8*>(&ph[c]);
        f16x8 l = *reinterpret_cast<const f16x8*>(&pl[c]);
#pragma unroll
        for (int q = 0; q < 8; q++) {
            float v = (float)h[q] + (float)l[q];
            s = fmaf(v, v, s);
        }
    }
    nrm[(b << 11) + i] = s;
}

// ---------------------------------------------------------------------------
// f16-split MFMA distance GEMM: D = nrm_i + nrm_j - 2*(lo·hi + hi·lo + hi·hi)
// per upper-triangle 128x128 tile; mirror via LDS chunks; D stored as
// PRE-FLIPPED u32 keys. Operands (z,N,C) f16 hi/lo; C%64==0... C>=64.
// ---------------------------------------------------------------------------
__global__ __launch_bounds__(256) void dmfma_kernel(const _Float16* __restrict__ Fh,
                                                    const _Float16* __restrict__ Fl,
                                                    const float* __restrict__ nrm,
                                                    float* __restrict__ D, int C) {
    __shared__ __align__(16) char smem[65536];
    _Float16* Ah = (_Float16*)(smem);
    _Float16* Al = (_Float16*)(smem + 16384);
    _Float16* Bh = (_Float16*)(smem + 32768);
    _Float16* Bl = (_Float16*)(smem + 49152);
    float(*Tt)[132] = (float(*)[132])smem;  // mirror staging (reused)

    int bz = blockIdx.z;
    int t = blockIdx.x;
    int bx = (int)((sqrtf(8.f * (float)t + 1.f) - 1.f) * 0.5f);
    while ((bx + 1) * (bx + 2) / 2 <= t) bx++;
    while (bx * (bx + 1) / 2 > t) bx--;
    int by = t - bx * (bx + 1) / 2;  // by <= bx
    int oB = by * 128, nB = bx * 128;
    const _Float16* Fhb = Fh + (size_t)bz * N_ * C;
    const _Float16* Flb = Fl + (size_t)bz * N_ * C;
    const float* nb = nrm + (size_t)bz * N_;
    float* Db = D + (size_t)bz * N_ * N_;

    int tid = threadIdx.x;
    int lane = tid & 63, w = tid >> 6;
    int wm = w & 1, wn = w >> 1;
    int lr = lane & 15, lg = lane >> 4;
    int lrow = lane >> 3;
    int lcol = ((lane & 7) ^ lrow) * 8;

    f32x4 acc[4][4];
#pragma unroll
    for (int m = 0; m < 4; m++)
#pragma unroll
        for (int n = 0; n < 4; n++) acc[m][n] = (f32x4){0.f, 0.f, 0.f, 0.f};

    for (int c0 = 0; c0 < C; c0 += 64) {
#pragma unroll
        for (int r = 0; r < 4; r++) {
            int seg = r * 4 + w;
            int row = seg * 8 + lrow;
            const _Float16* gah = &Fhb[(size_t)(oB + row) * C + c0 + lcol];
            const _Float16* gal = &Flb[(size_t)(oB + row) * C + c0 + lcol];
            const _Float16* gbh = &Fhb[(size_t)(nB + row) * C + c0 + lcol];
            const _Float16* gbl = &Flb[(size_t)(nB + row) * C + c0 + lcol];
            __builtin_amdgcn_global_load_lds((glb_u32_t*)gah, (lds_u32_t*)&Ah[seg * 512], 16, 0, 0);
            __builtin_amdgcn_global_load_lds((glb_u32_t*)gal, (lds_u32_t*)&Al[seg * 512], 16, 0, 0);
            __builtin_amdgcn_global_load_lds((glb_u32_t*)gbh, (lds_u32_t*)&Bh[seg * 512], 16, 0, 0);
            __builtin_amdgcn_global_load_lds((glb_u32_t*)gbl, (lds_u32_t*)&Bl[seg * 512], 16, 0, 0);
        }
        __syncthreads();
#pragma unroll
        for (int kk = 0; kk < 2; kk++) {
            f16x8 ah[4], al[4], bh[4], bl[4];
#pragma unroll
            for (int m = 0; m < 4; m++) {
                int row = wm * 64 + m * 16 + lr;
                int slot = (kk * 4 + lg) ^ (lr & 7);
                ah[m] = *reinterpret_cast<const f16x8*>(&Ah[row * 64 + slot * 8]);
                al[m] = *reinterpret_cast<const f16x8*>(&Al[row * 64 + slot * 8]);
            }
#pragma unroll
            for (int n = 0; n < 4; n++) {
                int row = wn * 64 + n * 16 + lr;
                int slot = (kk * 4 + lg) ^ (lr & 7);
                bh[n] = *reinterpret_cast<const f16x8*>(&Bh[row * 64 + slot * 8]);
                bl[n] = *reinterpret_cast<const f16x8*>(&Bl[row * 64 + slot * 8]);
            }
#pragma unroll
            for (int m = 0; m < 4; m++)
#pragma unroll
                for (int n = 0; n < 4; n++) {
                    acc[m][n] = __builtin_amdgcn_mfma_f32_16x16x32_f16(al[m], bh[n], acc[m][n], 0, 0, 0);
                    acc[m][n] = __builtin_amdgcn_mfma_f32_16x16x32_f16(ah[m], bl[n], acc[m][n], 0, 0, 0);
                    acc[m][n] = __builtin_amdgcn_mfma_f32_16x16x32_f16(ah[m], bh[n], acc[m][n], 0, 0, 0);
                }
        }
        __syncthreads();
    }

    // epilogue: distance + flip; store flipped bits back into acc; write normal
#pragma unroll
    for (int m = 0; m < 4; m++) {
#pragma unroll
        for (int r = 0; r < 4; r++) {
            int o = oB + wm * 64 + m * 16 + lg * 4 + r;
            float nr_ = nb[o];
#pragma unroll
            for (int n = 0; n < 4; n++) {
                int nv = nB + wn * 64 + n * 16 + lr;
                float val = nr_ + nb[nv] - 2.f * acc[m][n][r];
                unsigned int fk = fflip(val);
                Db[(size_t)o * N_ + nv] = __uint_as_float(fk);
                acc[m][n][r] = __uint_as_float(fk);
            }
        }
    }

    if (bx != by) {
        for (int p = 0; p < 4; p++) {
            __syncthreads();
            if (wm == (p >> 1)) {
#pragma unroll
                for (int mh = 0; mh < 2; mh++) {
                    int m = (p & 1) * 2 + mh;
                    int ib = m * 16 + lg * 4 - (p & 1) * 32;  // in [0,32)
#pragma unroll
                    for (int n = 0; n < 4; n++) {
                        int j = wn * 64 + n * 16 + lr;
#pragma unroll
                        for (int r = 0; r < 4; r++) Tt[ib + r][j] = acc[m][n][r];
                    }
                }
            }
            __syncthreads();
#pragma unroll
            for (int r = 0; r < 4; r++) {
                int e = tid + r * 256;
                int j = e >> 3, i4 = e & 7;
                float4 v;
                v.x = Tt[i4 * 4 + 0][j];
                v.y = Tt[i4 * 4 + 1][j];
                v.z = Tt[i4 * 4 + 2][j];
                v.w = Tt[i4 * 4 + 3][j];
                *reinterpret_cast<float4*>(&Db[(size_t)(nB + j) * N_ + oB + p * 32 + i4 * 4]) = v;
            }
        }
    }
}

// ---------------------------------------------------------------------------
// Conv fp32 GEMM: 64x64 tile, BK=32, float4 micro-tile cols.
// FUSE=1 (XLAYOUT 0): X-load applies y=relu(fmaf(x,xs[c],xh[c])).
// DUALT=1: also write transposed raw output Yt[(b*N+n)*O+o] (bias included).
// ---------------------------------------------------------------------------
template <int XLAYOUT, int FUSE, int DUALT>
__global__ __launch_bounds__(256, 4) void cgemm_kernel(const float* __restrict__ A,
                                                       const float* __restrict__ X,
                                                       const float* __restrict__ bias,
                                                       float* __restrict__ Y,
                                                       int O, int C,
                                                       const float* __restrict__ xs,
                                                       const float* __restrict__ xh,
                                                       float* __restrict__ Yt) {
    __shared__ float Wt[32][68];
    __shared__ float Xt[32][68];
    int b = blockIdx.z;
    int oB = blockIdx.y * 64, nB = blockIdx.x * 64;
    const float* Xb = X + (XLAYOUT == 0 ? (size_t)b * C * N_ : (size_t)b * N_ * C);
    int tid = threadIdx.x;
    int tn = tid & 15, to = tid >> 4;

    float acc[4][4];
#pragma unroll
    for (int i = 0; i < 4; i++)
#pragma unroll
        for (int j = 0; j < 4; j++) acc[i][j] = 0.f;

    for (int c0 = 0; c0 < C; c0 += 32) {
#pragma unroll
        for (int r = 0; r < 2; r++) {
            int e = tid + r * 256;
            int row = e >> 3, c4 = e & 7;
            float4 v = *reinterpret_cast<const float4*>(&A[(size_t)(oB + row) * C + c0 + c4 * 4]);
            Wt[c4 * 4 + 0][row] = v.x;
            Wt[c4 * 4 + 1][row] = v.y;
            Wt[c4 * 4 + 2][row] = v.z;
            Wt[c4 * 4 + 3][row] = v.w;
        }
        if (XLAYOUT == 0) {
#pragma unroll
            for (int r = 0; r < 2; r++) {
                int e = tid + r * 256;
                int k = e >> 4, n4 = e & 15;
                float4 v = *reinterpret_cast<const float4*>(&Xb[(size_t)(c0 + k) * N_ + nB + n4 * 4]);
                if (FUSE) {
                    float sc = xs[c0 + k], sh = xh[c0 + k];
                    v.x = fmaxf(fmaf(v.x, sc, sh), 0.f);
                    v.y = fmaxf(fmaf(v.y, sc, sh), 0.f);
                    v.z = fmaxf(fmaf(v.z, sc, sh), 0.f);
                    v.w = fmaxf(fmaf(v.w, sc, sh), 0.f);
                }
                *reinterpret_cast<float4*>(&Xt[k][n4 * 4]) = v;
            }
        } else {
#pragma unroll
            for (int r = 0; r < 2; r++) {
                int e = tid + r * 256;
                int n = e >> 3, c4 = e & 7;
                float4 v = *reinterpret_cast<const float4*>(&Xb[(size_t)(nB + n) * C + c0 + c4 * 4]);
                Xt[c4 * 4 + 0][n] = v.x;
                Xt[c4 * 4 + 1][n] = v.y;
                Xt[c4 * 4 + 2][n] = v.z;
                Xt[c4 * 4 + 3][n] = v.w;
            }
        }
        __syncthreads();
#pragma unroll
        for (int k = 0; k < 32; k++) {
            float a[4], xv[4];
            *reinterpret_cast<float4*>(&a[0]) = *reinterpret_cast<const float4*>(&Wt[k][to * 4]);
            *reinterpret_cast<float4*>(&xv[0]) = *reinterpret_cast<const float4*>(&Xt[k][tn * 4]);
#pragma unroll
            for (int i = 0; i < 4; i++)
#pragma unroll
                for (int j = 0; j < 4; j++) acc[i][j] = fmaf(a[i], xv[j], acc[i][j]);
        }
        __syncthreads();
    }

    float fin[4][4];
#pragma unroll
    for (int i = 0; i < 4; i++) {
        float bv = bias[oB + to * 4 + i];
#pragma unroll
        for (int j = 0; j < 4; j++) fin[i][j] = acc[i][j] + bv;
    }
#pragma unroll
    for (int i = 0; i < 4; i++) {
        int o = oB + to * 4 + i;
        int n0 = nB + tn * 4;
        float4 st;
        st.x = fin[i][0]; st.y = fin[i][1]; st.z = fin[i][2]; st.w = fin[i][3];
        *reinterpret_cast<float4*>(&Y[((size_t)b * O + o) * N_ + n0]) = st;
    }
    if (DUALT) {
#pragma unroll
        for (int j = 0; j < 4; j++) {
            int n = nB + tn * 4 + j;
            float4 st;
            st.x = fin[0][j]; st.y = fin[1][j]; st.z = fin[2][j]; st.w = fin[3][j];
            *reinterpret_cast<float4*>(&Yt[((size_t)b * N_ + n) * (size_t)O + oB + to * 4]) = st;
        }
    }
}

// ---------------------------------------------------------------------------
// bf16 MFMA GEMM (value path).
// EPI=1 (conv4): no bias/Y — per-block (max,min,sum,sumsq) partials.
// EPI=2 (g2): Y = transposed fp32 (B,N,O) with bias; (sum,sumsq) partials.
// ---------------------------------------------------------------------------
template <int EPI>
__global__ __launch_bounds__(256) void mgemm_kernel(const unsigned short* __restrict__ A,
                                                    const unsigned short* __restrict__ X,
                                                    const float* __restrict__ bias,
                                                    float* __restrict__ Y,
                                                    int O, int C,
                                                    float* __restrict__ part) {
    __shared__ unsigned short At[128 * 64];
    __shared__ unsigned short Bt[128 * 64];
    __shared__ float sred[2][2][64][4];
    int b = blockIdx.z;
    int oB = blockIdx.y * 128, nB = blockIdx.x * 128;
    const unsigned short* Xb = X + (size_t)b * N_ * C;
    int tid = threadIdx.x;
    int lane = tid & 63, w = tid >> 6;
    int wm = w & 1, wn = w >> 1;
    int lr = lane & 15, lg = lane >> 4;
    int lrow = lane >> 3;
    int lcol = ((lane & 7) ^ lrow) * 8;

    f32x4 acc[4][4];
#pragma unroll
    for (int m = 0; m < 4; m++)
#pragma unroll
        for (int n = 0; n < 4; n++) acc[m][n] = (f32x4){0.f, 0.f, 0.f, 0.f};

    for (int c0 = 0; c0 < C; c0 += 64) {
#pragma unroll
        for (int r = 0; r < 4; r++) {
            int seg = r * 4 + w;
            int row = seg * 8 + lrow;
            const unsigned short* ga = &A[(size_t)(oB + row) * C + c0 + lcol];
            const unsigned short* gb = &Xb[(size_t)(nB + row) * C + c0 + lcol];
            __builtin_amdgcn_global_load_lds((glb_u32_t*)ga, (lds_u32_t*)&At[seg * 512], 16, 0, 0);
            __builtin_amdgcn_global_load_lds((glb_u32_t*)gb, (lds_u32_t*)&Bt[seg * 512], 16, 0, 0);
        }
        __syncthreads();
#pragma unroll
        for (int kk = 0; kk < 2; kk++) {
            bf16x8 af[4], bfv[4];
#pragma unroll
            for (int m = 0; m < 4; m++) {
                int row = wm * 64 + m * 16 + lr;
                int slot = (kk * 4 + lg) ^ (lr & 7);
                af[m] = *reinterpret_cast<const bf16x8*>(&At[row * 64 + slot * 8]);
            }
#pragma unroll
            for (int n = 0; n < 4; n++) {
                int row = wn * 64 + n * 16 + lr;
                int slot = (kk * 4 + lg) ^ (lr & 7);
                bfv[n] = *reinterpret_cast<const bf16x8*>(&Bt[row * 64 + slot * 8]);
            }
#pragma unroll
            for (int m = 0; m < 4; m++)
#pragma unroll
                for (int n = 0; n < 4; n++)
                    acc[m][n] = __builtin_amdgcn_mfma_f32_16x16x32_bf16(af[m], bfv[n], acc[m][n], 0, 0, 0);
        }
        __syncthreads();
    }

    if (EPI == 1) {
#pragma unroll
        for (int m = 0; m < 4; m++) {
#pragma unroll
            for (int r = 0; r < 4; r++) {
                float v0 = acc[m][0][r], v1 = acc[m][1][r];
                float v2 = acc[m][2][r], v3 = acc[m][3][r];
                float mx = fmaxf(fmaxf(v0, v1), fmaxf(v2, v3));
                float mn = fminf(fminf(v0, v1), fminf(v2, v3));
                float s = (v0 + v1) + (v2 + v3);
                float s2 = fmaf(v0, v0, fmaf(v1, v1, fmaf(v2, v2, v3 * v3)));
#pragma unroll
                for (int msk = 1; msk <= 8; msk <<= 1) {
                    mx = fmaxf(mx, __shfl_xor(mx, msk, 64));
                    mn = fminf(mn, __shfl_xor(mn, msk, 64));
                    s += __shfl_xor(s, msk, 64);
                    s2 += __shfl_xor(s2, msk, 64);
                }
                if (lr == 0) {
                    int ol = m * 16 + lg * 4 + r;
                    sred[wm][wn][ol][0] = mx;
                    sred[wm][wn][ol][1] = mn;
                    sred[wm][wn][ol][2] = s;
                    sred[wm][wn][ol][3] = s2;
                }
            }
        }
        __syncthreads();
        if (tid < 128) {
            int wmv = tid >> 6, ol = tid & 63;
            float mx = fmaxf(sred[wmv][0][ol][0], sred[wmv][1][ol][0]);
            float mn = fminf(sred[wmv][0][ol][1], sred[wmv][1][ol][1]);
            float s = sred[wmv][0][ol][2] + sred[wmv][1][ol][2];
            float s2 = sred[wmv][0][ol][3] + sred[wmv][1][ol][3];
            int o = oB + wmv * 64 + ol;
            float* pp = &part[((size_t)(o * 8 + b) * 16 + blockIdx.x) * 4];
            pp[0] = mx; pp[1] = mn; pp[2] = s; pp[3] = s2;
        }
    } else {
#pragma unroll
        for (int m = 0; m < 4; m++) {
            int o0 = oB + wm * 64 + m * 16 + lg * 4;
            float4 bv = *reinterpret_cast<const float4*>(&bias[o0]);
            float s[4] = {0.f, 0.f, 0.f, 0.f};
            float s2[4] = {0.f, 0.f, 0.f, 0.f};
#pragma unroll
            for (int n = 0; n < 4; n++) {
                int nv = nB + wn * 64 + n * 16 + lr;
                float4 st;
                st.x = acc[m][n][0] + bv.x;
                st.y = acc[m][n][1] + bv.y;
                st.z = acc[m][n][2] + bv.z;
                st.w = acc[m][n][3] + bv.w;
                *reinterpret_cast<float4*>(&Y[((size_t)b * N_ + nv) * (size_t)O + o0]) = st;
                s[0] += st.x; s2[0] = fmaf(st.x, st.x, s2[0]);
                s[1] += st.y; s2[1] = fmaf(st.y, st.y, s2[1]);
                s[2] += st.z; s2[2] = fmaf(st.z, st.z, s2[2]);
                s[3] += st.w; s2[3] = fmaf(st.w, st.w, s2[3]);
            }
#pragma unroll
            for (int r = 0; r < 4; r++) {
#pragma unroll
                for (int msk = 1; msk <= 8; msk <<= 1) {
                    s[r] += __shfl_xor(s[r], msk, 64);
                    s2[r] += __shfl_xor(s2[r], msk, 64);
                }
                if (lr == 0) {
                    int ol = m * 16 + lg * 4 + r;
                    sred[wm][wn][ol][0] = s[r];
                    sred[wm][wn][ol][1] = s2[r];
                }
            }
        }
        __syncthreads();
        if (tid < 128) {
            int wmv = tid >> 6, ol = tid & 63;
            float s = sred[wmv][0][ol][0] + sred[wmv][1][ol][0];
            float s2 = sred[wmv][0][ol][1] + sred[wmv][1][ol][1];
            int o = oB + wmv * 64 + ol;
            float* pp = &part[((size_t)(o * 8 + b) * 16 + blockIdx.x) * 2];
            pp[0] = s; pp[1] = s2;
        }
    }
}

// ---------------------------------------------------------------------------
// g2 stats finish: reduce 8b x 16nb (sum,sumsq) partials -> scale/shift.
// ---------------------------------------------------------------------------
__global__ __launch_bounds__(128) void bnfin_kernel(const float* __restrict__ part,
                                                    const float* __restrict__ gm,
                                                    const float* __restrict__ bt,
                                                    float* __restrict__ scale,
                                                    float* __restrict__ shift) {
    int o = blockIdx.x;
    int t = threadIdx.x;  // 128 = 8 b x 16 nb
    const float* p = &part[((size_t)(o * 8 + (t >> 4)) * 16 + (t & 15)) * 2];
    float s = p[0], s2 = p[1];
#pragma unroll
    for (int msk = 1; msk <= 32; msk <<= 1) {
        s += __shfl_xor(s, msk, 64);
        s2 += __shfl_xor(s2, msk, 64);
    }
    __shared__ float red[4];
    int wv = t >> 6, lane = t & 63;
    if (lane == 0) { red[wv] = s; red[2 + wv] = s2; }
    __syncthreads();
    if (t == 0) {
        float S = red[0] + red[1], S2 = red[2] + red[3];
        float mu = S * (1.f / (B_ * N_));
        float var = S2 * (1.f / (B_ * N_)) - mu * mu;
        float inv = 1.f / sqrtf(var + 1e-5f);
        float sc = gm[o] * inv;
        scale[o] = sc;
        shift[o] = fmaf(-mu, sc, bt[o]);
    }
}

// ---------------------------------------------------------------------------
// g2 apply: (B,N,1024) fp32 -> BN+ReLU -> bf16 (B,N,1024). Elementwise.
// ---------------------------------------------------------------------------
__global__ __launch_bounds__(256) void applycvt_kernel(const float* __restrict__ yt,
                                                       const float* __restrict__ scale,
                                                       const float* __restrict__ shift,
                                                       unsigned short* __restrict__ outh) {
    size_t i = ((size_t)blockIdx.x * 256 + threadIdx.x) * 8;
    int o = (int)(i & 1023u);
    float4 a = *reinterpret_cast<const float4*>(&yt[i]);
    float4 c = *reinterpret_cast<const float4*>(&yt[i + 4]);
    float4 s0 = *reinterpret_cast<const float4*>(&scale[o]);
    float4 s1 = *reinterpret_cast<const float4*>(&scale[o + 4]);
    float4 h0 = *reinterpret_cast<const float4*>(&shift[o]);
    float4 h1 = *reinterpret_cast<const float4*>(&shift[o + 4]);
    unsigned short u[8];
    u[0] = f2bf(fmaxf(fmaf(a.x, s0.x, h0.x), 0.f));
    u[1] = f2bf(fmaxf(fmaf(a.y, s0.y, h0.y), 0.f));
    u[2] = f2bf(fmaxf(fmaf(a.z, s0.z, h0.z), 0.f));
    u[3] = f2bf(fmaxf(fmaf(a.w, s0.w, h0.w), 0.f));
    u[4] = f2bf(fmaxf(fmaf(c.x, s1.x, h1.x), 0.f));
    u[5] = f2bf(fmaxf(fmaf(c.y, s1.y, h1.y), 0.f));
    u[6] = f2bf(fmaxf(fmaf(c.z, s1.z, h1.z), 0.f));
    u[7] = f2bf(fmaxf(fmaf(c.w, s1.w, h1.w), 0.f));
    uint4 pk;
    pk.x = (unsigned)u[0] | ((unsigned)u[1] << 16);
    pk.y = (unsigned)u[2] | ((unsigned)u[3] << 16);
    pk.z = (unsigned)u[4] | ((unsigned)u[5] << 16);
    pk.w = (unsigned)u[6] | ((unsigned)u[7] << 16);
    *reinterpret_cast<uint4*>(&outh[i]) = pk;
}

// ---------------------------------------------------------------------------
// conv4 finish: reduce partials -> BN stats; out = scale*max+shift (min if <0).
// ---------------------------------------------------------------------------
__global__ __launch_bounds__(128) void bnmax_kernel(const float* __restrict__ part,
                                                    const float* __restrict__ gm,
                                                    const float* __restrict__ bt,
                                                    float* __restrict__ out) {
    int o = blockIdx.x;
    int t = threadIdx.x;          // 128 = 8 b x 16 nb
    int b = t >> 4, nb = t & 15;
    const float* p = &part[((size_t)(o * 8 + b) * 16 + nb) * 4];
    float mx = p[0], mn = p[1], s = p[2], s2 = p[3];

    float ss = s, ss2 = s2;
#pragma unroll
    for (int msk = 1; msk <= 32; msk <<= 1) {
        ss += __shfl_xor(ss, msk, 64);
        ss2 += __shfl_xor(ss2, msk, 64);
    }
    __shared__ float red[4];
    int wv = t >> 6, lane = t & 63;
    if (lane == 0) { red[wv] = ss; red[2 + wv] = ss2; }
    __syncthreads();
    float S = red[0] + red[1], S2 = red[2] + red[3];
    float mu = S * (1.f / (B_ * N_));
    float var = S2 * (1.f / (B_ * N_)) - mu * mu;
    float inv = 1.f / sqrtf(var + 1e-5f);
    float sc = gm[o] * inv;
    float sh = fmaf(-mu, sc, bt[o]);

#pragma unroll
    for (int msk = 1; msk <= 8; msk <<= 1) {
        mx = fmaxf(mx, __shfl_xor(mx, msk, 64));
        mn = fminf(mn, __shfl_xor(mn, msk, 64));
    }
    if (nb == 0) out[b * 512 + o] = fmaf(sc, sc >= 0.f ? mx : mn, sh);
}

// ---------------------------------------------------------------------------
// Per-channel BN stats over (B,N)
// ---------------------------------------------------------------------------
__global__ __launch_bounds__(256) void bnstats_kernel(const float* __restrict__ y,
                                                      const float* __restrict__ gm,
                                                      const float* __restrict__ bt,
                                                      float* __restrict__ scale,
                                                      float* __restrict__ shift, int O) {
    int o = blockIdx.x;
    float s = 0.f, s2 = 0.f;
    for (int e = threadIdx.x; e < B_ * N_; e += 256) {
        int b = e >> 11, n = e & (N_ - 1);
        float v = y[((size_t)b * O + o) * N_ + n];
        s += v;
        s2 = fmaf(v, v, s2);
    }
#pragma unroll
    for (int off = 32; off; off >>= 1) {
        s += __shfl_down(s, off, 64);
        s2 += __shfl_down(s2, off, 64);
    }
    __shared__ float red[8];
    int lane = threadIdx.x & 63, w = threadIdx.x >> 6;
    if (lane == 0) { red[w] = s; red[4 + w] = s2; }
    __syncthreads();
    if (threadIdx.x == 0) {
        s = red[0] + red[1] + red[2] + red[3];
        s2 = red[4] + red[5] + red[6] + red[7];
        float mu = s * (1.f / (B_ * N_));
        float var = s2 * (1.f / (B_ * N_)) - mu * mu;
        float inv = 1.f / sqrtf(var + 1e-5f);
        float sc = gm[o] * inv;
        scale[o] = sc;
        shift[o] = fmaf(-mu, sc, bt[o]);
    }
}

// ---------------------------------------------------------------------------
// Top-16 per row of a (4*2048) x 2048 distance block (PRE-FLIPPED u32 keys).
// ---------------------------------------------------------------------------
__global__ __launch_bounds__(256, 4) void topk_kernel(const float* __restrict__ D,
                                                      int* __restrict__ idx) {
    int wave = threadIdx.x >> 6, lane = threadIdx.x & 63;
    int i = blockIdx.x * 4 + wave;
    const unsigned int* dp = (const unsigned int*)(D + (size_t)i * N_);

    unsigned long long kA[16], kB[16];
#pragma unroll
    for (int t = 0; t < 4; t++) {
        uint4 v = *reinterpret_cast<const uint4*>(&dp[t * 256 + lane * 4]);
        int j0 = t * 256 + lane * 4;
        kA[t * 4 + 0] = ((unsigned long long)v.x << 11) | (unsigned int)(j0 + 0);
        kA[t * 4 + 1] = ((unsigned long long)v.y << 11) | (unsigned int)(j0 + 1);
        kA[t * 4 + 2] = ((unsigned long long)v.z << 11) | (unsigned int)(j0 + 2);
        kA[t * 4 + 3] = ((unsigned long long)v.w << 11) | (unsigned int)(j0 + 3);
    }
#pragma unroll
    for (int t = 4; t < 8; t++) {
        uint4 v = *reinterpret_cast<const uint4*>(&dp[t * 256 + lane * 4]);
        int j0 = t * 256 + lane * 4;
        kB[(t - 4) * 4 + 0] = ((unsigned long long)v.x << 11) | (unsigned int)(j0 + 0);
        kB[(t - 4) * 4 + 1] = ((unsigned long long)v.y << 11) | (unsigned int)(j0 + 1);
        kB[(t - 4) * 4 + 2] = ((unsigned long long)v.z << 11) | (unsigned int)(j0 + 2);
        kB[(t - 4) * 4 + 3] = ((unsigned long long)v.w << 11) | (unsigned int)(j0 + 3);
    }

    unsigned long long q[16];
    TOP16OF32(kA, kB, q);

    int* op = idx + (size_t)i * KNN;
    EXTRACT16(q, op);
}

// ---------------------------------------------------------------------------
// Gather 16 neighbor RAW fp32 rows (B,N,C), apply BN+ReLU per element, max
// over k -> BN'd fp32 (B,N,C).
// ---------------------------------------------------------------------------
__global__ __launch_bounds__(256) void gathermax_kernel(const float* __restrict__ ftraw,
                                                        const int* __restrict__ idx,
                                                        const float* __restrict__ scale,
                                                        const float* __restrict__ shift,
                                                        float* __restrict__ out, int cLog) {
    int C = 1 << cLog;
    int b = blockIdx.y;
    int nb = (blockIdx.x << (8 - cLog)) + (threadIdx.x >> cLog);
    int c = threadIdx.x & (C - 1);
    float sc = scale[c], sh = shift[c];
    const int* ip = idx + (((size_t)b << 11) + nb) * KNN;
    float m = -3.4e38f;
#pragma unroll
    for (int k = 0; k < KNN; k++) {
        int j = ip[k];
        float v = ftraw[(((size_t)b << 11) + j) * C + c];
        m = fmaxf(m, fmaxf(fmaf(v, sc, sh), 0.f));
    }
    out[(((size_t)b << 11) + nb) * C + c] = m;
}

// ---------------------------------------------------------------------------
// Gather-max: RAW fp32 (B,N,128) in, BN+ReLU per element, max -> bf16.
// ---------------------------------------------------------------------------
__global__ __launch_bounds__(256) void gmaxh2_kernel(const float* __restrict__ ftraw,
                                                     const int* __restrict__ idx,
                                                     const float* __restrict__ scale,
                                                     const float* __restrict__ shift,
                                                     unsigned short* __restrict__ out) {
    const int C = 128;
    int b = blockIdx.y;
    int nb = blockIdx.x * 16 + (threadIdx.x >> 4);
    int cc = (threadIdx.x & 15) * 8;
    float4 s0 = *reinterpret_cast<const float4*>(&scale[cc]);
    float4 s1 = *reinterpret_cast<const float4*>(&scale[cc + 4]);
    float4 h0 = *reinterpret_cast<const float4*>(&shift[cc]);
    float4 h1 = *reinterpret_cast<const float4*>(&shift[cc + 4]);
    const int* ip = idx + (((size_t)b << 11) + nb) * KNN;
    float m[8];
#pragma unroll
    for (int q = 0; q < 8; q++) m[q] = -3.4e38f;
#pragma unroll
    for (int k = 0; k < KNN; k++) {
        int j = ip[k];
        const float* p = &ftraw[(((size_t)b << 11) + j) * C + cc];
        float4 a = *reinterpret_cast<const float4*>(p);
        float4 c2 = *reinterpret_cast<const float4*>(p + 4);
        m[0] = fmaxf(m[0], fmaxf(fmaf(a.x, s0.x, h0.x), 0.f));
        m[1] = fmaxf(m[1], fmaxf(fmaf(a.y, s0.y, h0.y), 0.f));
        m[2] = fmaxf(m[2], fmaxf(fmaf(a.z, s0.z, h0.z), 0.f));
        m[3] = fmaxf(m[3], fmaxf(fmaf(a.w, s0.w, h0.w), 0.f));
        m[4] = fmaxf(m[4], fmaxf(fmaf(c2.x, s1.x, h1.x), 0.f));
        m[5] = fmaxf(m[5], fmaxf(fmaf(c2.y, s1.y, h1.y), 0.f));
        m[6] = fmaxf(m[6], fmaxf(fmaf(c2.z, s1.z, h1.z), 0.f));
        m[7] = fmaxf(m[7], fmaxf(fmaf(c2.w, s1.w, h1.w), 0.f));
    }
    unsigned short u[8];
#pragma unroll
    for (int q = 0; q < 8; q++) u[q] = f2bf(m[q]);
    uint4 pk;
    pk.x = (unsigned)u[0] | ((unsigned)u[1] << 16);
    pk.y = (unsigned)u[2] | ((unsigned)u[3] << 16);
    pk.z = (unsigned)u[4] | ((unsigned)u[5] << 16);
    pk.w = (unsigned)u[6] | ((unsigned)u[7] << 16);
    *reinterpret_cast<uint4*>(&out[(((size_t)b << 11) + nb) * C + cc]) = pk;
}

// ---------------------------------------------------------------------------
// fp32 -> bf16 weight conversion (both value-path weight arrays, one launch)
// ---------------------------------------------------------------------------
__global__ __launch_bounds__(256) void wcvt2_kernel(const float* __restrict__ w1,
                                                    unsigned short* __restrict__ o1, int c1,
                                                    const float* __restrict__ w2,
                                                    unsigned short* __restrict__ o2, int c2) {
    int i = blockIdx.x * 256 + threadIdx.x;
    if (i < c1) o1[i] = f2bf(w1[i]);
    else if (i < c1 + c2) o2[i - c1] = f2bf(w2[i - c1]);
}

// ---------------------------------------------------------------------------
extern "C" void kernel_launch(void* const* d_in, const int* in_sizes, int n_in,
                              void* d_out, int out_size, void* d_ws, size_t ws_size,
                              hipStream_t stream) {
    const float* x = (const float*)d_in[0];
    const float* W1 = (const float*)d_in[1];
    const float* b1 = (const float*)d_in[2];
    const float* gm1 = (const float*)d_in[3];
    const float* bt1 = (const float*)d_in[4];
    const float* W2 = (const float*)d_in[5];
    const float* b2 = (const float*)d_in[6];
    const float* gm2 = (const float*)d_in[7];
    const float* bt2 = (const float*)d_in[8];
    const float* W3 = (const float*)d_in[9];
    const float* b3 = (const float*)d_in[10];
    const float* gm3 = (const float*)d_in[11];
    const float* bt3 = (const float*)d_in[12];
    const float* Wg1 = (const float*)d_in[13];
    const float* bg1 = (const float*)d_in[14];
    const float* gmg1 = (const float*)d_in[15];
    const float* btg1 = (const float*)d_in[16];
    const float* Wg2 = (const float*)d_in[17];
    const float* bg2 = (const float*)d_in[18];
    const float* gmg2 = (const float*)d_in[19];
    const float* btg2 = (const float*)d_in[20];
    const float* W4 = (const float*)d_in[21];
    const float* b4 = (const float*)d_in[22];
    const float* gm4 = (const float*)d_in[23];
    const float* bt4 = (const float*)d_in[24];
    float* out = (float*)d_out;
    (void)b4;

    // ---- workspace arena (byte offsets), total 154,214,400 bytes ----
    if (ws_size < 154214400ull) return;
    char* base = (char*)d_ws;
    float* scale = (float*)(base + 0);
    float* shift = (float*)(base + 4096);
    float* nrm = (float*)(base + 8192);
    int* idx = (int*)(base + 73728);
    unsigned short* Wg2h = (unsigned short*)(base + 1122304);
    unsigned short* W4h = (unsigned short*)(base + 1384448);
    _Float16* Fh1 = (_Float16*)(base + 2433024);   // (8,2048,64)  2MB
    _Float16* Fl1 = (_Float16*)(base + 4530176);   // (8,2048,64)  2MB
    _Float16* Fh2 = (_Float16*)(base + 6627328);   // (8,2048,128) 4MB
    _Float16* Fl2 = (_Float16*)(base + 10821632);  // (8,2048,128) 4MB
    float* bufD4 = (float*)(base + 19210240);
    float* bufLt = (float*)(base + 19210240);                   // (8,2048,1024) f32
    unsigned short* bufLh = (unsigned short*)(base + 86319104); // (8,2048,1024) bf16
    char* E = base + 119873536;                                 // early region
    float* h0 = (float*)(E + 0);                                // (8,12,2048)
    float* bufA = (float*)(E + 786432);                         // (8,64,2048) raw
    float* bufB = (float*)(E + 4980736);                        // (8,64,2048)
    float* bufC = (float*)(E + 9175040);                        // (8,2048,64) raw
    float* bufM1 = (float*)(E + 13369344);                      // (8,128,2048) raw
    float* bufM2 = (float*)(E + 21757952);                      // (8,2048,128) raw
    unsigned short* bufM3h = (unsigned short*)(E + 30146560);   // (8,2048,128) bf16
    float* part = (float*)(E + 0);   // partials (<=1 MB), early bufs dead by g2

    // weight conversion (value-path weights, single launch)
    wcvt2_kernel<<<2560, 256, 0, stream>>>(Wg2, Wg2h, 1024 * 128, W4, W4h, 512 * 1024);

    // Stage 0/1: 3D KNN + fused covariance features
    knn3_kernel<<<dim3(512, 8), 256, 0, stream>>>(x, idx, h0);

    // conv1: 12 -> 64 (fp32); raw output, BN1 fused into conv2
    gemm_kernel<<<dim3(16, 1, 8), 256, 0, stream>>>(W1, h0, b1, bufA, 64, 12);
    bnstats_kernel<<<64, 256, 0, stream>>>(bufA, gm1, bt1, scale, shift, 64);

    // conv2: 64 -> 64 (BN1+ReLU fused on load); raw out, BN2 fused next
    cgemm_kernel<0, 1, 0><<<dim3(32, 1, 8), 256, 0, stream>>>(W2, bufA, b2, bufB, 64, 64, scale, shift, nullptr);
    bnstats_kernel<<<64, 256, 0, stream>>>(bufB, gm2, bt2, scale, shift, 64);

    // conv3: 64 -> 64 (BN2+ReLU fused on load) -> raw bufA + raw bufC (dual)
    cgemm_kernel<0, 1, 1><<<dim3(32, 1, 8), 256, 0, stream>>>(W3, bufB, b3, bufA, 64, 64, scale, shift, bufC);
    bnstats_kernel<<<64, 256, 0, stream>>>(bufA, gm3, bt3, scale, shift, 64);

    // graph layer 1 KNN: split BN'd features to f16 hi/lo, norms, MFMA dist
    splitbn_kernel<<<dim3(32, 1, 8), 256, 0, stream>>>(bufA, scale, shift, Fh1, Fl1, 64);
    normsh_kernel<<<dim3(8, 8), 256, 0, stream>>>(Fh1, Fl1, nrm, 64);
    for (int c = 0; c < 2; c++) {
        dmfma_kernel<<<dim3(136, 1, 4), 256, 0, stream>>>(
            Fh1 + (size_t)c * 4 * N_ * 64, Fl1 + (size_t)c * 4 * N_ * 64,
            nrm + (size_t)c * 4 * N_, bufD4, 64);
        topk_kernel<<<2048, 256, 0, stream>>>(bufD4, idx + (size_t)c * 4 * N_ * KNN);
    }
    gathermax_kernel<<<dim3(512, 8), 256, 0, stream>>>(bufC, idx, scale, shift, bufB, 6);

    // conv g1: 64 -> 128 (input (B,N,64) BN'd) -> raw bufM1 + raw bufM2 (dual)
    cgemm_kernel<1, 0, 1><<<dim3(32, 2, 8), 256, 0, stream>>>(Wg1, bufB, bg1, bufM1, 128, 64, nullptr, nullptr, bufM2);
    bnstats_kernel<<<128, 256, 0, stream>>>(bufM1, gmg1, btg1, scale, shift, 128);

    // graph layer 2 KNN: split + norms + MFMA dist
    splitbn_kernel<<<dim3(32, 2, 8), 256, 0, stream>>>(bufM1, scale, shift, Fh2, Fl2, 128);
    normsh_kernel<<<dim3(8, 8), 256, 0, stream>>>(Fh2, Fl2, nrm, 128);
    for (int c = 0; c < 2; c++) {
        dmfma_kernel<<<dim3(136, 1, 4), 256, 0, stream>>>(
            Fh2 + (size_t)c * 4 * N_ * 128, Fl2 + (size_t)c * 4 * N_ * 128,
            nrm + (size_t)c * 4 * N_, bufD4, 128);
        topk_kernel<<<2048, 256, 0, stream>>>(bufD4, idx + (size_t)c * 4 * N_ * KNN);
    }
    gmaxh2_kernel<<<dim3(128, 8), 256, 0, stream>>>(bufM2, idx, scale, shift, bufM3h);

    // conv g2: 128 -> 1024 (bf16 MFMA, transposed fp32 out + fused stats)
    mgemm_kernel<2><<<dim3(16, 8, 8), 256, 0, stream>>>(Wg2h, bufM3h, bg2, bufLt, 1024, 128, part);
    bnfin_kernel<<<1024, 128, 0, stream>>>(part, gmg2, btg2, scale, shift);
    applycvt_kernel<<<8192, 256, 0, stream>>>(bufLt, scale, shift, bufLh);

    // conv4: 1024 -> 512 (bf16 MFMA, fused BN-stats+max epilogue)
    mgemm_kernel<1><<<dim3(16, 4, 8), 256, 0, stream>>>(W4h, bufLh, nullptr, nullptr, 512, 1024, part);
    bnmax_kernel<<<512, 128, 0, stream>>>(part, gm4, bt4, out);
}

// Round 14
// 438.702 us; speedup vs baseline: 1.3776x; 1.1753x over previous
//
#include <hip/hip_runtime.h>
#include <math.h>

#define B_ 8
#define N_ 2048
#define KNN 16

typedef __attribute__((ext_vector_type(4))) float f32x4;
typedef __attribute__((ext_vector_type(8))) short bf16x8;
typedef __attribute__((ext_vector_type(8))) _Float16 f16x8;
typedef __attribute__((address_space(3))) unsigned int lds_u32_t;
typedef __attribute__((address_space(1))) const unsigned int glb_u32_t;

__device__ inline unsigned short f2bf(float f) {
    unsigned int x = __float_as_uint(f);
    unsigned int r = (x + 0x7fffu + ((x >> 16) & 1u)) >> 16;  // RNE
    return (unsigned short)r;
}

// Monotone bijection fp32 -> u32 (handles negatives; order-preserving).
__device__ inline unsigned int fflip(float f) {
    unsigned int u = __float_as_uint(f);
    return u ^ (0x80000000u | (unsigned int)((int)u >> 31));
}

// 64-bit shuffle-xor across the 64-lane wave.
__device__ inline unsigned long long shflx64(unsigned long long v, int m) {
    int lo = __shfl_xor((int)(unsigned int)(v & 0xffffffffull), m, 64);
    int hi = __shfl_xor((int)(unsigned int)(v >> 32), m, 64);
    return ((unsigned long long)(unsigned int)hi << 32) | (unsigned int)lo;
}

// Compare-exchange: a=min, b=max (u64 keys are unique -> total order).
__device__ inline void ce(unsigned long long& a, unsigned long long& b) {
    bool c = a < b;
    unsigned long long lo = c ? a : b;
    unsigned long long hi = c ? b : a;
    a = lo;
    b = hi;
}

// Bitonic sort 16 (ascending), fully unrolled, static indices only.
#define SORT16(q)                                                         \
    _Pragma("unroll") for (int kk_ = 2; kk_ <= 16; kk_ <<= 1)             \
    _Pragma("unroll") for (int jj_ = kk_ >> 1; jj_ > 0; jj_ >>= 1)        \
    _Pragma("unroll") for (int ii_ = 0; ii_ < 16; ii_++) {                \
        int ll_ = ii_ ^ jj_;                                              \
        if (ll_ > ii_) {                                                  \
            if ((ii_ & kk_) == 0) ce(q[ii_], q[ll_]);                     \
            else ce(q[ll_], q[ii_]);                                      \
        }                                                                 \
    }

// Bitonic merge 16 (input bitonic -> ascending).
#define MERGE16(q)                                                        \
    _Pragma("unroll") for (int jj_ = 8; jj_ > 0; jj_ >>= 1)               \
    _Pragma("unroll") for (int ii_ = 0; ii_ < 16; ii_++) {                \
        int ll_ = ii_ ^ jj_;                                              \
        if (ll_ > ii_) ce(q[ii_], q[ll_]);                                \
    }

// Reduce 32 keys (kA[16], kB[16]) -> q[16] = sorted ascending local top-16.
#define TOP16OF32(kA, kB, q)                                              \
    SORT16(kA);                                                           \
    SORT16(kB);                                                           \
    _Pragma("unroll") for (int ii_ = 0; ii_ < 16; ii_++) {                \
        unsigned long long b_ = kB[15 - ii_];                             \
        q[ii_] = kA[ii_] < b_ ? kA[ii_] : b_;                             \
    }                                                                     \
    MERGE16(q);

// Extract the wave's 16 smallest keys in ascending order.
#define EXTRACT16(q, op)                                                  \
    for (int r_ = 0; r_ < KNN; r_++) {                                    \
        unsigned long long mk_ = q[0];                                    \
        _Pragma("unroll") for (int s_ = 32; s_ > 0; s_ >>= 1) {           \
            unsigned long long ok_ = shflx64(mk_, s_);                    \
            if (ok_ < mk_) mk_ = ok_;                                     \
        }                                                                 \
        if (lane == 0) (op)[r_] = (int)(mk_ & 2047u);                     \
        bool pop_ = (q[0] == mk_);                                        \
        _Pragma("unroll") for (int t_ = 0; t_ < 15; t_++)                 \
            q[t_] = pop_ ? q[t_ + 1] : q[t_];                             \
        q[15] = pop_ ? ~0ull : q[15];                                     \
    }

// ---------------------------------------------------------------------------
// KNN on 3D input points + fused covariance features (h0 (B,12,N)).
// ---------------------------------------------------------------------------
__global__ __launch_bounds__(256, 4) void knn3_kernel(const float* __restrict__ x,
                                                      int* __restrict__ idx,
                                                      float* __restrict__ h0) {
    __shared__ float px[N_], py[N_], pz[N_];
    int b = blockIdx.y;
    const float* xb = x + (size_t)b * N_ * 3;
    for (int e = threadIdx.x; e < N_; e += 256) {
        px[e] = xb[e * 3 + 0];
        py[e] = xb[e * 3 + 1];
        pz[e] = xb[e * 3 + 2];
    }
    __syncthreads();

    int wave = threadIdx.x >> 6, lane = threadIdx.x & 63;
    int i = blockIdx.x * 4 + wave;
    float qx = px[i], qy = py[i], qz = pz[i];

    unsigned long long kA[16], kB[16];
#pragma unroll
    for (int t = 0; t < 16; t++) {
        int j = lane + t * 64;
        float dx = px[j] - qx, dy = py[j] - qy, dz = pz[j] - qz;
        float d = dx * dx + dy * dy + dz * dz;
        kA[t] = ((unsigned long long)fflip(d) << 11) | (unsigned int)j;
    }
#pragma unroll
    for (int t = 0; t < 16; t++) {
        int j = lane + (t + 16) * 64;
        float dx = px[j] - qx, dy = py[j] - qy, dz = pz[j] - qz;
        float d = dx * dx + dy * dy + dz * dz;
        kB[t] = ((unsigned long long)fflip(d) << 11) | (unsigned int)j;
    }

    unsigned long long q[16];
    TOP16OF32(kA, kB, q);

    int* op = idx + ((size_t)b * N_ + i) * KNN;
    unsigned int jr[16];
#pragma unroll
    for (int r_ = 0; r_ < KNN; r_++) {
        unsigned long long mk_ = q[0];
#pragma unroll
        for (int s_ = 32; s_ > 0; s_ >>= 1) {
            unsigned long long ok_ = shflx64(mk_, s_);
            if (ok_ < mk_) mk_ = ok_;
        }
        jr[r_] = (unsigned int)(mk_ & 2047u);
        if (lane == 0) op[r_] = (int)jr[r_];
        bool pop_ = (q[0] == mk_);
#pragma unroll
        for (int t_ = 0; t_ < 15; t_++) q[t_] = pop_ ? q[t_ + 1] : q[t_];
        q[15] = pop_ ? ~0ull : q[15];
    }

    float nx[16], ny[16], nz[16];
    float mx = 0.f, my = 0.f, mz = 0.f;
#pragma unroll
    for (int r_ = 0; r_ < 16; r_++) {
        int j = (int)jr[r_];
        nx[r_] = px[j]; ny[r_] = py[j]; nz[r_] = pz[j];
        mx += nx[r_]; my += ny[r_]; mz += nz[r_];
    }
    mx *= (1.f / KNN); my *= (1.f / KNN); mz *= (1.f / KNN);
    float c00 = 0, c01 = 0, c02 = 0, c11 = 0, c12 = 0, c22 = 0;
#pragma unroll
    for (int r_ = 0; r_ < 16; r_++) {
        float dx = nx[r_] - mx, dy = ny[r_] - my, dz = nz[r_] - mz;
        c00 += dx * dx; c01 += dx * dy; c02 += dx * dz;
        c11 += dy * dy; c12 += dy * dz; c22 += dz * dz;
    }
    if (lane == 0) {
        float* hb = h0 + (size_t)b * 12 * N_;
        hb[0 * N_ + i] = qx;
        hb[1 * N_ + i] = qy;
        hb[2 * N_ + i] = qz;
        hb[3 * N_ + i] = c00; hb[4 * N_ + i] = c01; hb[5 * N_ + i] = c02;
        hb[6 * N_ + i] = c01; hb[7 * N_ + i] = c11; hb[8 * N_ + i] = c12;
        hb[9 * N_ + i] = c02; hb[10 * N_ + i] = c12; hb[11 * N_ + i] = c22;
    }
}

// ---------------------------------------------------------------------------
// Old fp32 GEMM (conv1: C=12 needs bounds checks) + fused BN partials
// (per-block sum/sumsq per channel over its 128-col slice).
// ---------------------------------------------------------------------------
__global__ __launch_bounds__(256) void gemm_kernel(const float* __restrict__ A,
                                                   const float* __restrict__ X,
                                                   const float* __restrict__ bias,
                                                   float* __restrict__ Y,
                                                   int O, int C,
                                                   float* __restrict__ part) {
    __shared__ float Wt[16][132];
    __shared__ float Xt[16][132];
    const int N = N_;
    int b = blockIdx.z;
    int oB = blockIdx.y * 128, nB = blockIdx.x * 128;
    const float* Xb = X + (size_t)b * C * N;
    int tid = threadIdx.x;
    int tn = tid & 15, to = tid >> 4;

    float acc[8][8];
#pragma unroll
    for (int i = 0; i < 8; i++)
#pragma unroll
        for (int j = 0; j < 8; j++) acc[i][j] = 0.f;

    for (int c0 = 0; c0 < C; c0 += 16) {
#pragma unroll
        for (int r = 0; r < 8; r++) {
            int e = tid + r * 256;
            int k = e & 15, o = e >> 4;
            float v = 0.f;
            if (c0 + k < C && oB + o < O) v = A[(size_t)(oB + o) * C + c0 + k];
            Wt[k][o] = v;
        }
#pragma unroll
        for (int r = 0; r < 8; r++) {
            int e = tid + r * 256;
            int n = e & 127, k = e >> 7;
            float v = 0.f;
            if (c0 + k < C) v = Xb[(size_t)(c0 + k) * N + nB + n];
            Xt[k][n] = v;
        }
        __syncthreads();
#pragma unroll
        for (int k = 0; k < 16; k++) {
            float a[8], xv[8];
#pragma unroll
            for (int i = 0; i < 8; i++) a[i] = Wt[k][to * 8 + i];
#pragma unroll
            for (int m = 0; m < 4; m++) {
                xv[2 * m] = Xt[k][tn * 2 + 32 * m];
                xv[2 * m + 1] = Xt[k][tn * 2 + 32 * m + 1];
            }
#pragma unroll
            for (int i = 0; i < 8; i++)
#pragma unroll
                for (int j = 0; j < 8; j++) acc[i][j] = fmaf(a[i], xv[j], acc[i][j]);
        }
        __syncthreads();
    }

#pragma unroll
    for (int i = 0; i < 8; i++) {
        int o = oB + to * 8 + i;
        if (o >= O) continue;
        float bv = bias[o];
        float s = 0.f, s2 = 0.f;
#pragma unroll
        for (int m = 0; m < 4; m++) {
            int n0 = nB + tn * 2 + 32 * m;
            float v0 = acc[i][2 * m] + bv, v1 = acc[i][2 * m + 1] + bv;
            *reinterpret_cast<float2*>(&Y[((size_t)b * O + o) * N + n0]) = make_float2(v0, v1);
            s += v0 + v1;
            s2 = fmaf(v0, v0, fmaf(v1, v1, s2));
        }
#pragma unroll
        for (int msk = 1; msk <= 8; msk <<= 1) {
            s += __shfl_xor(s, msk, 64);
            s2 += __shfl_xor(s2, msk, 64);
        }
        if (tn == 0) {
            float* pp = &part[((size_t)(o * 8 + b) * 16 + blockIdx.x) * 2];
            pp[0] = s; pp[1] = s2;
        }
    }
}

// ---------------------------------------------------------------------------
// BN+ReLU + transpose + f16 two-term split: raw (z,C,N) fp32 -> Fh/Fl
// (z,N,C) f16.  v = hi + lo, |v-hi-lo| <= 2^-22 |v|.
// ---------------------------------------------------------------------------
__global__ __launch_bounds__(256) void splitbn_kernel(const float* __restrict__ y,
                                                      const float* __restrict__ scale,
                                                      const float* __restrict__ shift,
                                                      _Float16* __restrict__ fh,
                                                      _Float16* __restrict__ fl, int O) {
    __shared__ float tile[64][65];
    int b = blockIdx.z;
    int n0 = blockIdx.x * 64, o0 = blockIdx.y * 64;
    int t = threadIdx.x;
#pragma unroll
    for (int rr = 0; rr < 16; rr++) {
        int ol = rr * 4 + (t >> 6), nl = t & 63;
        float v = y[((size_t)b * O + o0 + ol) * N_ + n0 + nl];
        v = fmaf(v, scale[o0 + ol], shift[o0 + ol]);
        tile[ol][nl] = fmaxf(v, 0.f);
    }
    __syncthreads();
#pragma unroll
    for (int rr = 0; rr < 2; rr++) {
        int e = t + rr * 256;
        int n = e >> 3, og = (e & 7) * 8;
        f16x8 hv, lv;
#pragma unroll
        for (int j = 0; j < 8; j++) {
            float v = tile[og + j][n];
            _Float16 h = (_Float16)v;
            hv[j] = h;
            lv[j] = (_Float16)(v - (float)h);
        }
        size_t off = ((size_t)b * N_ + n0 + n) * O + o0 + og;
        *reinterpret_cast<uint4*>(&fh[off]) = *reinterpret_cast<uint4*>(&hv);
        *reinterpret_cast<uint4*>(&fl[off]) = *reinterpret_cast<uint4*>(&lv);
    }
}

// ---------------------------------------------------------------------------
// Norms from split f16 (z,N,C): s = sum_c (hi+lo)^2, ascending c.
// ---------------------------------------------------------------------------
__global__ __launch_bounds__(256) void normsh_kernel(const _Float16* __restrict__ fh,
                                                     const _Float16* __restrict__ fl,
                                                     float* __restrict__ nrm, int C) {
    int b = blockIdx.y;
    int i = blockIdx.x * 256 + threadIdx.x;
    const _Float16* ph = fh + ((size_t)(b << 11) + i) * C;
    const _Float16* pl = fl + ((size_t)(b << 11) + i) * C;
    float s = 0.f;
    for (int c = 0; c < C; c += 8) {
        f16x8 h = *reinterpret_cast<const f16x8*>(&ph[c]);
        f16x8 l = *reinterpret_cast<const f16x8*>(&pl[c]);
#pragma unroll
        for (int q = 0; q < 8; q++) {
            float v = (float)h[q] + (float)l[q];
            s = fmaf(v, v, s);
        }
    }
    nrm[(b << 11) + i] = s;
}

// ---------------------------------------------------------------------------
// f16-split MFMA distance GEMM (unchanged from R13).
// ---------------------------------------------------------------------------
__global__ __launch_bounds__(256) void dmfma_kernel(const _Float16* __restrict__ Fh,
                                                    const _Float16* __restrict__ Fl,
                                                    const float* __restrict__ nrm,
                                                    float* __restrict__ D, int C) {
    __shared__ __align__(16) char smem[65536];
    _Float16* Ah = (_Float16*)(smem);
    _Float16* Al = (_Float16*)(smem + 16384);
    _Float16* Bh = (_Float16*)(smem + 32768);
    _Float16* Bl = (_Float16*)(smem + 49152);
    float(*Tt)[132] = (float(*)[132])smem;

    int bz = blockIdx.z;
    int t = blockIdx.x;
    int bx = (int)((sqrtf(8.f * (float)t + 1.f) - 1.f) * 0.5f);
    while ((bx + 1) * (bx + 2) / 2 <= t) bx++;
    while (bx * (bx + 1) / 2 > t) bx--;
    int by = t - bx * (bx + 1) / 2;  // by <= bx
    int oB = by * 128, nB = bx * 128;
    const _Float16* Fhb = Fh + (size_t)bz * N_ * C;
    const _Float16* Flb = Fl + (size_t)bz * N_ * C;
    const float* nb = nrm + (size_t)bz * N_;
    float* Db = D + (size_t)bz * N_ * N_;

    int tid = threadIdx.x;
    int lane = tid & 63, w = tid >> 6;
    int wm = w & 1, wn = w >> 1;
    int lr = lane & 15, lg = lane >> 4;
    int lrow = lane >> 3;
    int lcol = ((lane & 7) ^ lrow) * 8;

    f32x4 acc[4][4];
#pragma unroll
    for (int m = 0; m < 4; m++)
#pragma unroll
        for (int n = 0; n < 4; n++) acc[m][n] = (f32x4){0.f, 0.f, 0.f, 0.f};

    for (int c0 = 0; c0 < C; c0 += 64) {
#pragma unroll
        for (int r = 0; r < 4; r++) {
            int seg = r * 4 + w;
            int row = seg * 8 + lrow;
            const _Float16* gah = &Fhb[(size_t)(oB + row) * C + c0 + lcol];
            const _Float16* gal = &Flb[(size_t)(oB + row) * C + c0 + lcol];
            const _Float16* gbh = &Fhb[(size_t)(nB + row) * C + c0 + lcol];
            const _Float16* gbl = &Flb[(size_t)(nB + row) * C + c0 + lcol];
            __builtin_amdgcn_global_load_lds((glb_u32_t*)gah, (lds_u32_t*)&Ah[seg * 512], 16, 0, 0);
            __builtin_amdgcn_global_load_lds((glb_u32_t*)gal, (lds_u32_t*)&Al[seg * 512], 16, 0, 0);
            __builtin_amdgcn_global_load_lds((glb_u32_t*)gbh, (lds_u32_t*)&Bh[seg * 512], 16, 0, 0);
            __builtin_amdgcn_global_load_lds((glb_u32_t*)gbl, (lds_u32_t*)&Bl[seg * 512], 16, 0, 0);
        }
        __syncthreads();
#pragma unroll
        for (int kk = 0; kk < 2; kk++) {
            f16x8 ah[4], al[4], bh[4], bl[4];
#pragma unroll
            for (int m = 0; m < 4; m++) {
                int row = wm * 64 + m * 16 + lr;
                int slot = (kk * 4 + lg) ^ (lr & 7);
                ah[m] = *reinterpret_cast<const f16x8*>(&Ah[row * 64 + slot * 8]);
                al[m] = *reinterpret_cast<const f16x8*>(&Al[row * 64 + slot * 8]);
            }
#pragma unroll
            for (int n = 0; n < 4; n++) {
                int row = wn * 64 + n * 16 + lr;
                int slot = (kk * 4 + lg) ^ (lr & 7);
                bh[n] = *reinterpret_cast<const f16x8*>(&Bh[row * 64 + slot * 8]);
                bl[n] = *reinterpret_cast<const f16x8*>(&Bl[row * 64 + slot * 8]);
            }
#pragma unroll
            for (int m = 0; m < 4; m++)
#pragma unroll
                for (int n = 0; n < 4; n++) {
                    acc[m][n] = __builtin_amdgcn_mfma_f32_16x16x32_f16(al[m], bh[n], acc[m][n], 0, 0, 0);
                    acc[m][n] = __builtin_amdgcn_mfma_f32_16x16x32_f16(ah[m], bl[n], acc[m][n], 0, 0, 0);
                    acc[m][n] = __builtin_amdgcn_mfma_f32_16x16x32_f16(ah[m], bh[n], acc[m][n], 0, 0, 0);
                }
        }
        __syncthreads();
    }

#pragma unroll
    for (int m = 0; m < 4; m++) {
#pragma unroll
        for (int r = 0; r < 4; r++) {
            int o = oB + wm * 64 + m * 16 + lg * 4 + r;
            float nr_ = nb[o];
#pragma unroll
            for (int n = 0; n < 4; n++) {
                int nv = nB + wn * 64 + n * 16 + lr;
                float val = nr_ + nb[nv] - 2.f * acc[m][n][r];
                unsigned int fk = fflip(val);
                Db[(size_t)o * N_ + nv] = __uint_as_float(fk);
                acc[m][n][r] = __uint_as_float(fk);
            }
        }
    }

    if (bx != by) {
        for (int p = 0; p < 4; p++) {
            __syncthreads();
            if (wm == (p >> 1)) {
#pragma unroll
                for (int mh = 0; mh < 2; mh++) {
                    int m = (p & 1) * 2 + mh;
                    int ib = m * 16 + lg * 4 - (p & 1) * 32;
#pragma unroll
                    for (int n = 0; n < 4; n++) {
                        int j = wn * 64 + n * 16 + lr;
#pragma unroll
                        for (int r = 0; r < 4; r++) Tt[ib + r][j] = acc[m][n][r];
                    }
                }
            }
            __syncthreads();
#pragma unroll
            for (int r = 0; r < 4; r++) {
                int e = tid + r * 256;
                int j = e >> 3, i4 = e & 7;
                float4 v;
                v.x = Tt[i4 * 4 + 0][j];
                v.y = Tt[i4 * 4 + 1][j];
                v.z = Tt[i4 * 4 + 2][j];
                v.w = Tt[i4 * 4 + 3][j];
                *reinterpret_cast<float4*>(&Db[(size_t)(nB + j) * N_ + oB + p * 32 + i4 * 4]) = v;
            }
        }
    }
}

// ---------------------------------------------------------------------------
// Conv fp32 GEMM: 64x64 tile, BK=32, float4 micro-tile cols.
// FUSE=1 (XLAYOUT 0): X-load applies y=relu(fmaf(x,xs[c],xh[c])).
// DUALT=1: also write transposed raw output. Always emits BN partials
// (sum,sumsq per channel over its 64-col slice) to part (32 nb-blocks).
// ---------------------------------------------------------------------------
template <int XLAYOUT, int FUSE, int DUALT>
__global__ __launch_bounds__(256, 4) void cgemm_kernel(const float* __restrict__ A,
                                                       const float* __restrict__ X,
                                                       const float* __restrict__ bias,
                                                       float* __restrict__ Y,
                                                       int O, int C,
                                                       const float* __restrict__ xs,
                                                       const float* __restrict__ xh,
                                                       float* __restrict__ Yt,
                                                       float* __restrict__ part) {
    __shared__ float Wt[32][68];
    __shared__ float Xt[32][68];
    int b = blockIdx.z;
    int oB = blockIdx.y * 64, nB = blockIdx.x * 64;
    const float* Xb = X + (XLAYOUT == 0 ? (size_t)b * C * N_ : (size_t)b * N_ * C);
    int tid = threadIdx.x;
    int tn = tid & 15, to = tid >> 4;

    float acc[4][4];
#pragma unroll
    for (int i = 0; i < 4; i++)
#pragma unroll
        for (int j = 0; j < 4; j++) acc[i][j] = 0.f;

    for (int c0 = 0; c0 < C; c0 += 32) {
#pragma unroll
        for (int r = 0; r < 2; r++) {
            int e = tid + r * 256;
            int row = e >> 3, c4 = e & 7;
            float4 v = *reinterpret_cast<const float4*>(&A[(size_t)(oB + row) * C + c0 + c4 * 4]);
            Wt[c4 * 4 + 0][row] = v.x;
            Wt[c4 * 4 + 1][row] = v.y;
            Wt[c4 * 4 + 2][row] = v.z;
            Wt[c4 * 4 + 3][row] = v.w;
        }
        if (XLAYOUT == 0) {
#pragma unroll
            for (int r = 0; r < 2; r++) {
                int e = tid + r * 256;
                int k = e >> 4, n4 = e & 15;
                float4 v = *reinterpret_cast<const float4*>(&Xb[(size_t)(c0 + k) * N_ + nB + n4 * 4]);
                if (FUSE) {
                    float sc = xs[c0 + k], sh = xh[c0 + k];
                    v.x = fmaxf(fmaf(v.x, sc, sh), 0.f);
                    v.y = fmaxf(fmaf(v.y, sc, sh), 0.f);
                    v.z = fmaxf(fmaf(v.z, sc, sh), 0.f);
                    v.w = fmaxf(fmaf(v.w, sc, sh), 0.f);
                }
                *reinterpret_cast<float4*>(&Xt[k][n4 * 4]) = v;
            }
        } else {
#pragma unroll
            for (int r = 0; r < 2; r++) {
                int e = tid + r * 256;
                int n = e >> 3, c4 = e & 7;
                float4 v = *reinterpret_cast<const float4*>(&Xb[(size_t)(nB + n) * C + c0 + c4 * 4]);
                Xt[c4 * 4 + 0][n] = v.x;
                Xt[c4 * 4 + 1][n] = v.y;
                Xt[c4 * 4 + 2][n] = v.z;
                Xt[c4 * 4 + 3][n] = v.w;
            }
        }
        __syncthreads();
#pragma unroll
        for (int k = 0; k < 32; k++) {
            float a[4], xv[4];
            *reinterpret_cast<float4*>(&a[0]) = *reinterpret_cast<const float4*>(&Wt[k][to * 4]);
            *reinterpret_cast<float4*>(&xv[0]) = *reinterpret_cast<const float4*>(&Xt[k][tn * 4]);
#pragma unroll
            for (int i = 0; i < 4; i++)
#pragma unroll
                for (int j = 0; j < 4; j++) acc[i][j] = fmaf(a[i], xv[j], acc[i][j]);
        }
        __syncthreads();
    }

    float fin[4][4];
#pragma unroll
    for (int i = 0; i < 4; i++) {
        float bv = bias[oB + to * 4 + i];
#pragma unroll
        for (int j = 0; j < 4; j++) fin[i][j] = acc[i][j] + bv;
    }
#pragma unroll
    for (int i = 0; i < 4; i++) {
        int o = oB + to * 4 + i;
        int n0 = nB + tn * 4;
        float4 st;
        st.x = fin[i][0]; st.y = fin[i][1]; st.z = fin[i][2]; st.w = fin[i][3];
        *reinterpret_cast<float4*>(&Y[((size_t)b * O + o) * N_ + n0]) = st;
    }
    if (DUALT) {
#pragma unroll
        for (int j = 0; j < 4; j++) {
            int n = nB + tn * 4 + j;
            float4 st;
            st.x = fin[0][j]; st.y = fin[1][j]; st.z = fin[2][j]; st.w = fin[3][j];
            *reinterpret_cast<float4*>(&Yt[((size_t)b * N_ + n) * (size_t)O + oB + to * 4]) = st;
        }
    }
    // BN partials: per o, sum over this block's 64 cols
#pragma unroll
    for (int i = 0; i < 4; i++) {
        float s = (fin[i][0] + fin[i][1]) + (fin[i][2] + fin[i][3]);
        float s2 = fmaf(fin[i][0], fin[i][0], fmaf(fin[i][1], fin[i][1],
                   fmaf(fin[i][2], fin[i][2], fin[i][3] * fin[i][3])));
#pragma unroll
        for (int msk = 1; msk <= 8; msk <<= 1) {
            s += __shfl_xor(s, msk, 64);
            s2 += __shfl_xor(s2, msk, 64);
        }
        if (tn == 0) {
            int o = oB + to * 4 + i;
            float* pp = &part[((size_t)(o * 8 + b) * 32 + blockIdx.x) * 2];
            pp[0] = s; pp[1] = s2;
        }
    }
}

// ---------------------------------------------------------------------------
// bf16 MFMA GEMM (value path). EPI=1 conv4; EPI=2 g2. (unchanged)
// ---------------------------------------------------------------------------
template <int EPI>
__global__ __launch_bounds__(256) void mgemm_kernel(const unsigned short* __restrict__ A,
                                                    const unsigned short* __restrict__ X,
                                                    const float* __restrict__ bias,
                                                    float* __restrict__ Y,
                                                    int O, int C,
                                                    float* __restrict__ part) {
    __shared__ unsigned short At[128 * 64];
    __shared__ unsigned short Bt[128 * 64];
    __shared__ float sred[2][2][64][4];
    int b = blockIdx.z;
    int oB = blockIdx.y * 128, nB = blockIdx.x * 128;
    const unsigned short* Xb = X + (size_t)b * N_ * C;
    int tid = threadIdx.x;
    int lane = tid & 63, w = tid >> 6;
    int wm = w & 1, wn = w >> 1;
    int lr = lane & 15, lg = lane >> 4;
    int lrow = lane >> 3;
    int lcol = ((lane & 7) ^ lrow) * 8;

    f32x4 acc[4][4];
#pragma unroll
    for (int m = 0; m < 4; m++)
#pragma unroll
        for (int n = 0; n < 4; n++) acc[m][n] = (f32x4){0.f, 0.f, 0.f, 0.f};

    for (int c0 = 0; c0 < C; c0 += 64) {
#pragma unroll
        for (int r = 0; r < 4; r++) {
            int seg = r * 4 + w;
            int row = seg * 8 + lrow;
            const unsigned short* ga = &A[(size_t)(oB + row) * C + c0 + lcol];
            const unsigned short* gb = &Xb[(size_t)(nB + row) * C + c0 + lcol];
            __builtin_amdgcn_global_load_lds((glb_u32_t*)ga, (lds_u32_t*)&At[seg * 512], 16, 0, 0);
            __builtin_amdgcn_global_load_lds((glb_u32_t*)gb, (lds_u32_t*)&Bt[seg * 512], 16, 0, 0);
        }
        __syncthreads();
#pragma unroll
        for (int kk = 0; kk < 2; kk++) {
            bf16x8 af[4], bfv[4];
#pragma unroll
            for (int m = 0; m < 4; m++) {
                int row = wm * 64 + m * 16 + lr;
                int slot = (kk * 4 + lg) ^ (lr & 7);
                af[m] = *reinterpret_cast<const bf16x8*>(&At[row * 64 + slot * 8]);
            }
#pragma unroll
            for (int n = 0; n < 4; n++) {
                int row = wn * 64 + n * 16 + lr;
                int slot = (kk * 4 + lg) ^ (lr & 7);
                bfv[n] = *reinterpret_cast<const bf16x8*>(&Bt[row * 64 + slot * 8]);
            }
#pragma unroll
            for (int m = 0; m < 4; m++)
#pragma unroll
                for (int n = 0; n < 4; n++)
                    acc[m][n] = __builtin_amdgcn_mfma_f32_16x16x32_bf16(af[m], bfv[n], acc[m][n], 0, 0, 0);
        }
        __syncthreads();
    }

    if (EPI == 1) {
#pragma unroll
        for (int m = 0; m < 4; m++) {
#pragma unroll
            for (int r = 0; r < 4; r++) {
                float v0 = acc[m][0][r], v1 = acc[m][1][r];
                float v2 = acc[m][2][r], v3 = acc[m][3][r];
                float mx = fmaxf(fmaxf(v0, v1), fmaxf(v2, v3));
                float mn = fminf(fminf(v0, v1), fminf(v2, v3));
                float s = (v0 + v1) + (v2 + v3);
                float s2 = fmaf(v0, v0, fmaf(v1, v1, fmaf(v2, v2, v3 * v3)));
#pragma unroll
                for (int msk = 1; msk <= 8; msk <<= 1) {
                    mx = fmaxf(mx, __shfl_xor(mx, msk, 64));
                    mn = fminf(mn, __shfl_xor(mn, msk, 64));
                    s += __shfl_xor(s, msk, 64);
                    s2 += __shfl_xor(s2, msk, 64);
                }
                if (lr == 0) {
                    int ol = m * 16 + lg * 4 + r;
                    sred[wm][wn][ol][0] = mx;
                    sred[wm][wn][ol][1] = mn;
                    sred[wm][wn][ol][2] = s;
                    sred[wm][wn][ol][3] = s2;
                }
            }
        }
        __syncthreads();
        if (tid < 128) {
            int wmv = tid >> 6, ol = tid & 63;
            float mx = fmaxf(sred[wmv][0][ol][0], sred[wmv][1][ol][0]);
            float mn = fminf(sred[wmv][0][ol][1], sred[wmv][1][ol][1]);
            float s = sred[wmv][0][ol][2] + sred[wmv][1][ol][2];
            float s2 = sred[wmv][0][ol][3] + sred[wmv][1][ol][3];
            int o = oB + wmv * 64 + ol;
            float* pp = &part[((size_t)(o * 8 + b) * 16 + blockIdx.x) * 4];
            pp[0] = mx; pp[1] = mn; pp[2] = s; pp[3] = s2;
        }
    } else {
#pragma unroll
        for (int m = 0; m < 4; m++) {
            int o0 = oB + wm * 64 + m * 16 + lg * 4;
            float4 bv = *reinterpret_cast<const float4*>(&bias[o0]);
            float s[4] = {0.f, 0.f, 0.f, 0.f};
            float s2[4] = {0.f, 0.f, 0.f, 0.f};
#pragma unroll
            for (int n = 0; n < 4; n++) {
                int nv = nB + wn * 64 + n * 16 + lr;
                float4 st;
                st.x = acc[m][n][0] + bv.x;
                st.y = acc[m][n][1] + bv.y;
                st.z = acc[m][n][2] + bv.z;
                st.w = acc[m][n][3] + bv.w;
                *reinterpret_cast<float4*>(&Y[((size_t)b * N_ + nv) * (size_t)O + o0]) = st;
                s[0] += st.x; s2[0] = fmaf(st.x, st.x, s2[0]);
                s[1] += st.y; s2[1] = fmaf(st.y, st.y, s2[1]);
                s[2] += st.z; s2[2] = fmaf(st.z, st.z, s2[2]);
                s[3] += st.w; s2[3] = fmaf(st.w, st.w, s2[3]);
            }
#pragma unroll
            for (int r = 0; r < 4; r++) {
#pragma unroll
                for (int msk = 1; msk <= 8; msk <<= 1) {
                    s[r] += __shfl_xor(s[r], msk, 64);
                    s2[r] += __shfl_xor(s2[r], msk, 64);
                }
                if (lr == 0) {
                    int ol = m * 16 + lg * 4 + r;
                    sred[wm][wn][ol][0] = s[r];
                    sred[wm][wn][ol][1] = s2[r];
                }
            }
        }
        __syncthreads();
        if (tid < 128) {
            int wmv = tid >> 6, ol = tid & 63;
            float s = sred[wmv][0][ol][0] + sred[wmv][1][ol][0];
            float s2 = sred[wmv][0][ol][1] + sred[wmv][1][ol][1];
            int o = oB + wmv * 64 + ol;
            float* pp = &part[((size_t)(o * 8 + b) * 16 + blockIdx.x) * 2];
            pp[0] = s; pp[1] = s2;
        }
    }
}

// ---------------------------------------------------------------------------
// Stats finish (16 nb-blocks): reduce 8b x 16nb (sum,sumsq) -> scale/shift.
// ---------------------------------------------------------------------------
__global__ __launch_bounds__(128) void bnfin_kernel(const float* __restrict__ part,
                                                    const float* __restrict__ gm,
                                                    const float* __restrict__ bt,
                                                    float* __restrict__ scale,
                                                    float* __restrict__ shift) {
    int o = blockIdx.x;
    int t = threadIdx.x;  // 128 = 8 b x 16 nb
    const float* p = &part[((size_t)(o * 8 + (t >> 4)) * 16 + (t & 15)) * 2];
    float s = p[0], s2 = p[1];
#pragma unroll
    for (int msk = 1; msk <= 32; msk <<= 1) {
        s += __shfl_xor(s, msk, 64);
        s2 += __shfl_xor(s2, msk, 64);
    }
    __shared__ float red[4];
    int wv = t >> 6, lane = t & 63;
    if (lane == 0) { red[wv] = s; red[2 + wv] = s2; }
    __syncthreads();
    if (t == 0) {
        float S = red[0] + red[1], S2 = red[2] + red[3];
        float mu = S * (1.f / (B_ * N_));
        float var = S2 * (1.f / (B_ * N_)) - mu * mu;
        float inv = 1.f / sqrtf(var + 1e-5f);
        float sc = gm[o] * inv;
        scale[o] = sc;
        shift[o] = fmaf(-mu, sc, bt[o]);
    }
}

// ---------------------------------------------------------------------------
// Stats finish (32 nb-blocks): reduce 8b x 32nb (sum,sumsq) -> scale/shift.
// ---------------------------------------------------------------------------
__global__ __launch_bounds__(256) void bnfin32_kernel(const float* __restrict__ part,
                                                      const float* __restrict__ gm,
                                                      const float* __restrict__ bt,
                                                      float* __restrict__ scale,
                                                      float* __restrict__ shift) {
    int o = blockIdx.x;
    int t = threadIdx.x;  // 256 = 8 b x 32 nb
    const float* p = &part[((size_t)(o * 8 + (t >> 5)) * 32 + (t & 31)) * 2];
    float s = p[0], s2 = p[1];
#pragma unroll
    for (int msk = 1; msk <= 32; msk <<= 1) {
        s += __shfl_xor(s, msk, 64);
        s2 += __shfl_xor(s2, msk, 64);
    }
    __shared__ float red[8];
    int wv = t >> 6, lane = t & 63;
    if (lane == 0) { red[wv] = s; red[4 + wv] = s2; }
    __syncthreads();
    if (t == 0) {
        float S = (red[0] + red[1]) + (red[2] + red[3]);
        float S2 = (red[4] + red[5]) + (red[6] + red[7]);
        float mu = S * (1.f / (B_ * N_));
        float var = S2 * (1.f / (B_ * N_)) - mu * mu;
        float inv = 1.f / sqrtf(var + 1e-5f);
        float sc = gm[o] * inv;
        scale[o] = sc;
        shift[o] = fmaf(-mu, sc, bt[o]);
    }
}

// ---------------------------------------------------------------------------
// g2 apply: (B,N,1024) fp32 -> BN+ReLU -> bf16 (B,N,1024). Elementwise.
// ---------------------------------------------------------------------------
__global__ __launch_bounds__(256) void applycvt_kernel(const float* __restrict__ yt,
                                                       const float* __restrict__ scale,
                                                       const float* __restrict__ shift,
                                                       unsigned short* __restrict__ outh) {
    size_t i = ((size_t)blockIdx.x * 256 + threadIdx.x) * 8;
    int o = (int)(i & 1023u);
    float4 a = *reinterpret_cast<const float4*>(&yt[i]);
    float4 c = *reinterpret_cast<const float4*>(&yt[i + 4]);
    float4 s0 = *reinterpret_cast<const float4*>(&scale[o]);
    float4 s1 = *reinterpret_cast<const float4*>(&scale[o + 4]);
    float4 h0 = *reinterpret_cast<const float4*>(&shift[o]);
    float4 h1 = *reinterpret_cast<const float4*>(&shift[o + 4]);
    unsigned short u[8];
    u[0] = f2bf(fmaxf(fmaf(a.x, s0.x, h0.x), 0.f));
    u[1] = f2bf(fmaxf(fmaf(a.y, s0.y, h0.y), 0.f));
    u[2] = f2bf(fmaxf(fmaf(a.z, s0.z, h0.z), 0.f));
    u[3] = f2bf(fmaxf(fmaf(a.w, s0.w, h0.w), 0.f));
    u[4] = f2bf(fmaxf(fmaf(c.x, s1.x, h1.x), 0.f));
    u[5] = f2bf(fmaxf(fmaf(c.y, s1.y, h1.y), 0.f));
    u[6] = f2bf(fmaxf(fmaf(c.z, s1.z, h1.z), 0.f));
    u[7] = f2bf(fmaxf(fmaf(c.w, s1.w, h1.w), 0.f));
    uint4 pk;
    pk.x = (unsigned)u[0] | ((unsigned)u[1] << 16);
    pk.y = (unsigned)u[2] | ((unsigned)u[3] << 16);
    pk.z = (unsigned)u[4] | ((unsigned)u[5] << 16);
    pk.w = (unsigned)u[6] | ((unsigned)u[7] << 16);
    *reinterpret_cast<uint4*>(&outh[i]) = pk;
}

// ---------------------------------------------------------------------------
// conv4 finish: reduce partials -> BN stats; out = scale*max+shift (min if <0).
// ---------------------------------------------------------------------------
__global__ __launch_bounds__(128) void bnmax_kernel(const float* __restrict__ part,
                                                    const float* __restrict__ gm,
                                                    const float* __restrict__ bt,
                                                    float* __restrict__ out) {
    int o = blockIdx.x;
    int t = threadIdx.x;          // 128 = 8 b x 16 nb
    int b = t >> 4, nb = t & 15;
    const float* p = &part[((size_t)(o * 8 + b) * 16 + nb) * 4];
    float mx = p[0], mn = p[1], s = p[2], s2 = p[3];

    float ss = s, ss2 = s2;
#pragma unroll
    for (int msk = 1; msk <= 32; msk <<= 1) {
        ss += __shfl_xor(ss, msk, 64);
        ss2 += __shfl_xor(ss2, msk, 64);
    }
    __shared__ float red[4];
    int wv = t >> 6, lane = t & 63;
    if (lane == 0) { red[wv] = ss; red[2 + wv] = ss2; }
    __syncthreads();
    float S = red[0] + red[1], S2 = red[2] + red[3];
    float mu = S * (1.f / (B_ * N_));
    float var = S2 * (1.f / (B_ * N_)) - mu * mu;
    float inv = 1.f / sqrtf(var + 1e-5f);
    float sc = gm[o] * inv;
    float sh = fmaf(-mu, sc, bt[o]);

#pragma unroll
    for (int msk = 1; msk <= 8; msk <<= 1) {
        mx = fmaxf(mx, __shfl_xor(mx, msk, 64));
        mn = fminf(mn, __shfl_xor(mn, msk, 64));
    }
    if (nb == 0) out[b * 512 + o] = fmaf(sc, sc >= 0.f ? mx : mn, sh);
}

// ---------------------------------------------------------------------------
// Top-16 per row of an (NB*2048) x 2048 distance block (PRE-FLIPPED u32 keys).
// ---------------------------------------------------------------------------
__global__ __launch_bounds__(256, 4) void topk_kernel(const float* __restrict__ D,
                                                      int* __restrict__ idx) {
    int wave = threadIdx.x >> 6, lane = threadIdx.x & 63;
    int i = blockIdx.x * 4 + wave;
    const unsigned int* dp = (const unsigned int*)(D + (size_t)i * N_);

    unsigned long long kA[16], kB[16];
#pragma unroll
    for (int t = 0; t < 4; t++) {
        uint4 v = *reinterpret_cast<const uint4*>(&dp[t * 256 + lane * 4]);
        int j0 = t * 256 + lane * 4;
        kA[t * 4 + 0] = ((unsigned long long)v.x << 11) | (unsigned int)(j0 + 0);
        kA[t * 4 + 1] = ((unsigned long long)v.y << 11) | (unsigned int)(j0 + 1);
        kA[t * 4 + 2] = ((unsigned long long)v.z << 11) | (unsigned int)(j0 + 2);
        kA[t * 4 + 3] = ((unsigned long long)v.w << 11) | (unsigned int)(j0 + 3);
    }
#pragma unroll
    for (int t = 4; t < 8; t++) {
        uint4 v = *reinterpret_cast<const uint4*>(&dp[t * 256 + lane * 4]);
        int j0 = t * 256 + lane * 4;
        kB[(t - 4) * 4 + 0] = ((unsigned long long)v.x << 11) | (unsigned int)(j0 + 0);
        kB[(t - 4) * 4 + 1] = ((unsigned long long)v.y << 11) | (unsigned int)(j0 + 1);
        kB[(t - 4) * 4 + 2] = ((unsigned long long)v.z << 11) | (unsigned int)(j0 + 2);
        kB[(t - 4) * 4 + 3] = ((unsigned long long)v.w << 11) | (unsigned int)(j0 + 3);
    }

    unsigned long long q[16];
    TOP16OF32(kA, kB, q);

    int* op = idx + (size_t)i * KNN;
    EXTRACT16(q, op);
}

// ---------------------------------------------------------------------------
// Gather 16 neighbor RAW fp32 rows (B,N,C), apply BN+ReLU, max -> fp32.
// ---------------------------------------------------------------------------
__global__ __launch_bounds__(256) void gathermax_kernel(const float* __restrict__ ftraw,
                                                        const int* __restrict__ idx,
                                                        const float* __restrict__ scale,
                                                        const float* __restrict__ shift,
                                                        float* __restrict__ out, int cLog) {
    int C = 1 << cLog;
    int b = blockIdx.y;
    int nb = (blockIdx.x << (8 - cLog)) + (threadIdx.x >> cLog);
    int c = threadIdx.x & (C - 1);
    float sc = scale[c], sh = shift[c];
    const int* ip = idx + (((size_t)b << 11) + nb) * KNN;
    float m = -3.4e38f;
#pragma unroll
    for (int k = 0; k < KNN; k++) {
        int j = ip[k];
        float v = ftraw[(((size_t)b << 11) + j) * C + c];
        m = fmaxf(m, fmaxf(fmaf(v, sc, sh), 0.f));
    }
    out[(((size_t)b << 11) + nb) * C + c] = m;
}

// ---------------------------------------------------------------------------
// Gather-max: RAW fp32 (B,N,128) in, BN+ReLU per element, max -> bf16.
// ---------------------------------------------------------------------------
__global__ __launch_bounds__(256) void gmaxh2_kernel(const float* __restrict__ ftraw,
                                                     const int* __restrict__ idx,
                                                     const float* __restrict__ scale,
                                                     const float* __restrict__ shift,
                                                     unsigned short* __restrict__ out) {
    const int C = 128;
    int b = blockIdx.y;
    int nb = blockIdx.x * 16 + (threadIdx.x >> 4);
    int cc = (threadIdx.x & 15) * 8;
    float4 s0 = *reinterpret_cast<const float4*>(&scale[cc]);
    float4 s1 = *reinterpret_cast<const float4*>(&scale[cc + 4]);
    float4 h0 = *reinterpret_cast<const float4*>(&shift[cc]);
    float4 h1 = *reinterpret_cast<const float4*>(&shift[cc + 4]);
    const int* ip = idx + (((size_t)b << 11) + nb) * KNN;
    float m[8];
#pragma unroll
    for (int q = 0; q < 8; q++) m[q] = -3.4e38f;
#pragma unroll
    for (int k = 0; k < KNN; k++) {
        int j = ip[k];
        const float* p = &ftraw[(((size_t)b << 11) + j) * C + cc];
        float4 a = *reinterpret_cast<const float4*>(p);
        float4 c2 = *reinterpret_cast<const float4*>(p + 4);
        m[0] = fmaxf(m[0], fmaxf(fmaf(a.x, s0.x, h0.x), 0.f));
        m[1] = fmaxf(m[1], fmaxf(fmaf(a.y, s0.y, h0.y), 0.f));
        m[2] = fmaxf(m[2], fmaxf(fmaf(a.z, s0.z, h0.z), 0.f));
        m[3] = fmaxf(m[3], fmaxf(fmaf(a.w, s0.w, h0.w), 0.f));
        m[4] = fmaxf(m[4], fmaxf(fmaf(c2.x, s1.x, h1.x), 0.f));
        m[5] = fmaxf(m[5], fmaxf(fmaf(c2.y, s1.y, h1.y), 0.f));
        m[6] = fmaxf(m[6], fmaxf(fmaf(c2.z, s1.z, h1.z), 0.f));
        m[7] = fmaxf(m[7], fmaxf(fmaf(c2.w, s1.w, h1.w), 0.f));
    }
    unsigned short u[8];
#pragma unroll
    for (int q = 0; q < 8; q++) u[q] = f2bf(m[q]);
    uint4 pk;
    pk.x = (unsigned)u[0] | ((unsigned)u[1] << 16);
    pk.y = (unsigned)u[2] | ((unsigned)u[3] << 16);
    pk.z = (unsigned)u[4] | ((unsigned)u[5] << 16);
    pk.w = (unsigned)u[6] | ((unsigned)u[7] << 16);
    *reinterpret_cast<uint4*>(&out[(((size_t)b << 11) + nb) * C + cc]) = pk;
}

// ---------------------------------------------------------------------------
// fp32 -> bf16 weight conversion (both value-path weight arrays, one launch)
// ---------------------------------------------------------------------------
__global__ __launch_bounds__(256) void wcvt2_kernel(const float* __restrict__ w1,
                                                    unsigned short* __restrict__ o1, int c1,
                                                    const float* __restrict__ w2,
                                                    unsigned short* __restrict__ o2, int c2) {
    int i = blockIdx.x * 256 + threadIdx.x;
    if (i < c1) o1[i] = f2bf(w1[i]);
    else if (i < c1 + c2) o2[i - c1] = f2bf(w2[i - c1]);
}

// ---------------------------------------------------------------------------
extern "C" void kernel_launch(void* const* d_in, const int* in_sizes, int n_in,
                              void* d_out, int out_size, void* d_ws, size_t ws_size,
                              hipStream_t stream) {
    const float* x = (const float*)d_in[0];
    const float* W1 = (const float*)d_in[1];
    const float* b1 = (const float*)d_in[2];
    const float* gm1 = (const float*)d_in[3];
    const float* bt1 = (const float*)d_in[4];
    const float* W2 = (const float*)d_in[5];
    const float* b2 = (const float*)d_in[6];
    const float* gm2 = (const float*)d_in[7];
    const float* bt2 = (const float*)d_in[8];
    const float* W3 = (const float*)d_in[9];
    const float* b3 = (const float*)d_in[10];
    const float* gm3 = (const float*)d_in[11];
    const float* bt3 = (const float*)d_in[12];
    const float* Wg1 = (const float*)d_in[13];
    const float* bg1 = (const float*)d_in[14];
    const float* gmg1 = (const float*)d_in[15];
    const float* btg1 = (const float*)d_in[16];
    const float* Wg2 = (const float*)d_in[17];
    const float* bg2 = (const float*)d_in[18];
    const float* gmg2 = (const float*)d_in[19];
    const float* btg2 = (const float*)d_in[20];
    const float* W4 = (const float*)d_in[21];
    const float* b4 = (const float*)d_in[22];
    const float* gm4 = (const float*)d_in[23];
    const float* bt4 = (const float*)d_in[24];
    float* out = (float*)d_out;
    (void)b4;

    // ---- workspace arena (byte offsets), total 154,214,400 bytes ----
    if (ws_size < 154214400ull) return;
    char* base = (char*)d_ws;
    float* scale = (float*)(base + 0);
    float* shift = (float*)(base + 4096);
    float* nrm = (float*)(base + 8192);      // 64KB; conv1 partials alias this
    float* partC1 = (float*)(base + 8192);   // 64*8*16*2*4 = 64KB exact
    int* idx = (int*)(base + 73728);
    unsigned short* Wg2h = (unsigned short*)(base + 1122304);
    unsigned short* W4h = (unsigned short*)(base + 1384448);
    _Float16* Fh1 = (_Float16*)(base + 2433024);   // (8,2048,64)  2MB
    _Float16* Fl1 = (_Float16*)(base + 4530176);   // (8,2048,64)  2MB
    _Float16* Fh2 = (_Float16*)(base + 6627328);   // (8,2048,128) 4MB
    _Float16* Fl2 = (_Float16*)(base + 10821632);  // (8,2048,128) 4MB
    float* bufC = (float*)(base + 15015936);       // (8,2048,64) raw, 4MB
    // bufD8: layer-1 full 8-batch distance keys (134.2MB, 19.2M..153.4M).
    // E-region buffers are all dead during layer-1 dmfma/topk (verified).
    float* bufD8 = (float*)(base + 19210240);
    float* bufD4 = (float*)(base + 19210240);      // layer-2 4-batch chunks
    float* bufLt = (float*)(base + 19210240);      // (8,2048,1024) f32 (post-KNN)
    unsigned short* bufLh = (unsigned short*)(base + 86319104); // bf16 (post-KNN)
    char* E = base + 119873536;
    float* partC = (float*)(E + 0);                // conv2/3/g1 partials (512KB)
    float* h0 = (float*)(E + 0);                   // conv1 input (dead after conv1)
    float* bufA = (float*)(E + 786432);            // (8,64,2048) raw
    float* bufB = (float*)(E + 4980736);           // (8,64,2048)
    float* bufM1 = (float*)(E + 13369344);         // (8,128,2048) raw
    float* bufM2 = (float*)(E + 21757952);         // (8,2048,128) raw
    unsigned short* bufM3h = (unsigned short*)(E + 30146560);   // bf16
    float* part = (float*)(E + 0);                 // mgemm partials (into dead bufs)

    // weight conversion (value-path weights, single launch)
    wcvt2_kernel<<<2560, 256, 0, stream>>>(Wg2, Wg2h, 1024 * 128, W4, W4h, 512 * 1024);

    // Stage 0/1: 3D KNN + fused covariance features
    knn3_kernel<<<dim3(512, 8), 256, 0, stream>>>(x, idx, h0);

    // conv1: 12 -> 64 (fp32) + fused BN1 partials (into nrm slot; nrm written later)
    gemm_kernel<<<dim3(16, 1, 8), 256, 0, stream>>>(W1, h0, b1, bufA, 64, 12, partC1);
    bnfin_kernel<<<64, 128, 0, stream>>>(partC1, gm1, bt1, scale, shift);

    // conv2: 64 -> 64 (BN1+ReLU fused on load) + BN2 partials
    cgemm_kernel<0, 1, 0><<<dim3(32, 1, 8), 256, 0, stream>>>(W2, bufA, b2, bufB, 64, 64, scale, shift, nullptr, partC);
    bnfin32_kernel<<<64, 256, 0, stream>>>(partC, gm2, bt2, scale, shift);

    // conv3: 64 -> 64 (BN2+ReLU fused) -> raw bufA + raw bufC + BN3 partials
    cgemm_kernel<0, 1, 1><<<dim3(32, 1, 8), 256, 0, stream>>>(W3, bufB, b3, bufA, 64, 64, scale, shift, bufC, partC);
    bnfin32_kernel<<<64, 256, 0, stream>>>(partC, gm3, bt3, scale, shift);

    // graph layer 1 KNN: split, norms, single 8-batch MFMA dist + topk
    splitbn_kernel<<<dim3(32, 1, 8), 256, 0, stream>>>(bufA, scale, shift, Fh1, Fl1, 64);
    normsh_kernel<<<dim3(8, 8), 256, 0, stream>>>(Fh1, Fl1, nrm, 64);
    dmfma_kernel<<<dim3(136, 1, 8), 256, 0, stream>>>(Fh1, Fl1, nrm, bufD8, 64);
    topk_kernel<<<4096, 256, 0, stream>>>(bufD8, idx);
    gathermax_kernel<<<dim3(512, 8), 256, 0, stream>>>(bufC, idx, scale, shift, bufB, 6);

    // conv g1: 64 -> 128 -> raw bufM1 + raw bufM2 + BNg1 partials
    cgemm_kernel<1, 0, 1><<<dim3(32, 2, 8), 256, 0, stream>>>(Wg1, bufB, bg1, bufM1, 128, 64, nullptr, nullptr, bufM2, partC);
    bnfin32_kernel<<<128, 256, 0, stream>>>(partC, gmg1, btg1, scale, shift);

    // graph layer 2 KNN: split + norms + 2-chunk MFMA dist (67MB bufD4)
    splitbn_kernel<<<dim3(32, 2, 8), 256, 0, stream>>>(bufM1, scale, shift, Fh2, Fl2, 128);
    normsh_kernel<<<dim3(8, 8), 256, 0, stream>>>(Fh2, Fl2, nrm, 128);
    for (int c = 0; c < 2; c++) {
        dmfma_kernel<<<dim3(136, 1, 4), 256, 0, stream>>>(
            Fh2 + (size_t)c * 4 * N_ * 128, Fl2 + (size_t)c * 4 * N_ * 128,
            nrm + (size_t)c * 4 * N_, bufD4, 128);
        topk_kernel<<<2048, 256, 0, stream>>>(bufD4, idx + (size_t)c * 4 * N_ * KNN);
    }
    gmaxh2_kernel<<<dim3(128, 8), 256, 0, stream>>>(bufM2, idx, scale, shift, bufM3h);

    // conv g2: 128 -> 1024 (bf16 MFMA, transposed fp32 out + fused stats)
    mgemm_kernel<2><<<dim3(16, 8, 8), 256, 0, stream>>>(Wg2h, bufM3h, bg2, bufLt, 1024, 128, part);
    bnfin_kernel<<<1024, 128, 0, stream>>>(part, gmg2, btg2, scale, shift);
    applycvt_kernel<<<8192, 256, 0, stream>>>(bufLt, scale, shift, bufLh);

    // conv4: 1024 -> 512 (bf16 MFMA, fused BN-stats+max epilogue)
    mgemm_kernel<1><<<dim3(16, 4, 8), 256, 0, stream>>>(W4h, bufLh, nullptr, nullptr, 512, 1024, part);
    bnmax_kernel<<<512, 128, 0, stream>>>(part, gm4, bt4, out);
}

// Round 15
// 426.541 us; speedup vs baseline: 1.4169x; 1.0285x over previous
//
#include <hip/hip_runtime.h>
#include <math.h>

#define B_ 8
#define N_ 2048
#define KNN 16

typedef __attribute__((ext_vector_type(4))) float f32x4;
typedef __attribute__((ext_vector_type(8))) short bf16x8;
typedef __attribute__((ext_vector_type(8))) _Float16 f16x8;
typedef __attribute__((address_space(3))) unsigned int lds_u32_t;
typedef __attribute__((address_space(1))) const unsigned int glb_u32_t;

__device__ inline unsigned short f2bf(float f) {
    unsigned int x = __float_as_uint(f);
    unsigned int r = (x + 0x7fffu + ((x >> 16) & 1u)) >> 16;  // RNE
    return (unsigned short)r;
}

// Monotone bijection fp32 -> u32 (handles negatives; order-preserving).
__device__ inline unsigned int fflip(float f) {
    unsigned int u = __float_as_uint(f);
    return u ^ (0x80000000u | (unsigned int)((int)u >> 31));
}

// 64-bit shuffle-xor across the 64-lane wave.
__device__ inline unsigned long long shflx64(unsigned long long v, int m) {
    int lo = __shfl_xor((int)(unsigned int)(v & 0xffffffffull), m, 64);
    int hi = __shfl_xor((int)(unsigned int)(v >> 32), m, 64);
    return ((unsigned long long)(unsigned int)hi << 32) | (unsigned int)lo;
}

// Compare-exchange: a=min, b=max (u64 keys are unique -> total order).
__device__ inline void ce(unsigned long long& a, unsigned long long& b) {
    bool c = a < b;
    unsigned long long lo = c ? a : b;
    unsigned long long hi = c ? b : a;
    a = lo;
    b = hi;
}

// Bitonic sort 16 (ascending), fully unrolled, static indices only.
#define SORT16(q)                                                         \
    _Pragma("unroll") for (int kk_ = 2; kk_ <= 16; kk_ <<= 1)             \
    _Pragma("unroll") for (int jj_ = kk_ >> 1; jj_ > 0; jj_ >>= 1)        \
    _Pragma("unroll") for (int ii_ = 0; ii_ < 16; ii_++) {                \
        int ll_ = ii_ ^ jj_;                                              \
        if (ll_ > ii_) {                                                  \
            if ((ii_ & kk_) == 0) ce(q[ii_], q[ll_]);                     \
            else ce(q[ll_], q[ii_]);                                      \
        }                                                                 \
    }

// Bitonic merge 16 (input bitonic -> ascending).
#define MERGE16(q)                                                        \
    _Pragma("unroll") for (int jj_ = 8; jj_ > 0; jj_ >>= 1)               \
    _Pragma("unroll") for (int ii_ = 0; ii_ < 16; ii_++) {                \
        int ll_ = ii_ ^ jj_;                                              \
        if (ll_ > ii_) ce(q[ii_], q[ll_]);                                \
    }

// Reduce 32 keys (kA[16], kB[16]) -> q[16] = sorted ascending local top-16.
#define TOP16OF32(kA, kB, q)                                              \
    SORT16(kA);                                                           \
    SORT16(kB);                                                           \
    _Pragma("unroll") for (int ii_ = 0; ii_ < 16; ii_++) {                \
        unsigned long long b_ = kB[15 - ii_];                             \
        q[ii_] = kA[ii_] < b_ ? kA[ii_] : b_;                             \
    }                                                                     \
    MERGE16(q);

// Extract the wave's 16 smallest keys in ascending order.
#define EXTRACT16(q, op)                                                  \
    for (int r_ = 0; r_ < KNN; r_++) {                                    \
        unsigned long long mk_ = q[0];                                    \
        _Pragma("unroll") for (int s_ = 32; s_ > 0; s_ >>= 1) {           \
            unsigned long long ok_ = shflx64(mk_, s_);                    \
            if (ok_ < mk_) mk_ = ok_;                                     \
        }                                                                 \
        if (lane == 0) (op)[r_] = (int)(mk_ & 2047u);                     \
        bool pop_ = (q[0] == mk_);                                        \
        _Pragma("unroll") for (int t_ = 0; t_ < 15; t_++)                 \
            q[t_] = pop_ ? q[t_ + 1] : q[t_];                             \
        q[15] = pop_ ? ~0ull : q[15];                                     \
    }

// ---------------------------------------------------------------------------
// KNN on 3D input points + fused covariance features (h0 (B,12,N)).
// idx output dropped (dead: cov fused here; topk overwrites idx later).
// ---------------------------------------------------------------------------
__global__ __launch_bounds__(256, 4) void knn3_kernel(const float* __restrict__ x,
                                                      float* __restrict__ h0) {
    __shared__ float px[N_], py[N_], pz[N_];
    int b = blockIdx.y;
    const float* xb = x + (size_t)b * N_ * 3;
    for (int e = threadIdx.x; e < N_; e += 256) {
        px[e] = xb[e * 3 + 0];
        py[e] = xb[e * 3 + 1];
        pz[e] = xb[e * 3 + 2];
    }
    __syncthreads();

    int wave = threadIdx.x >> 6, lane = threadIdx.x & 63;
    int i = blockIdx.x * 4 + wave;
    float qx = px[i], qy = py[i], qz = pz[i];

    unsigned long long kA[16], kB[16];
#pragma unroll
    for (int t = 0; t < 16; t++) {
        int j = lane + t * 64;
        float dx = px[j] - qx, dy = py[j] - qy, dz = pz[j] - qz;
        float d = dx * dx + dy * dy + dz * dz;
        kA[t] = ((unsigned long long)fflip(d) << 11) | (unsigned int)j;
    }
#pragma unroll
    for (int t = 0; t < 16; t++) {
        int j = lane + (t + 16) * 64;
        float dx = px[j] - qx, dy = py[j] - qy, dz = pz[j] - qz;
        float d = dx * dx + dy * dy + dz * dz;
        kB[t] = ((unsigned long long)fflip(d) << 11) | (unsigned int)j;
    }

    unsigned long long q[16];
    TOP16OF32(kA, kB, q);

    unsigned int jr[16];
#pragma unroll
    for (int r_ = 0; r_ < KNN; r_++) {
        unsigned long long mk_ = q[0];
#pragma unroll
        for (int s_ = 32; s_ > 0; s_ >>= 1) {
            unsigned long long ok_ = shflx64(mk_, s_);
            if (ok_ < mk_) mk_ = ok_;
        }
        jr[r_] = (unsigned int)(mk_ & 2047u);
        bool pop_ = (q[0] == mk_);
#pragma unroll
        for (int t_ = 0; t_ < 15; t_++) q[t_] = pop_ ? q[t_ + 1] : q[t_];
        q[15] = pop_ ? ~0ull : q[15];
    }

    float nx[16], ny[16], nz[16];
    float mx = 0.f, my = 0.f, mz = 0.f;
#pragma unroll
    for (int r_ = 0; r_ < 16; r_++) {
        int j = (int)jr[r_];
        nx[r_] = px[j]; ny[r_] = py[j]; nz[r_] = pz[j];
        mx += nx[r_]; my += ny[r_]; mz += nz[r_];
    }
    mx *= (1.f / KNN); my *= (1.f / KNN); mz *= (1.f / KNN);
    float c00 = 0, c01 = 0, c02 = 0, c11 = 0, c12 = 0, c22 = 0;
#pragma unroll
    for (int r_ = 0; r_ < 16; r_++) {
        float dx = nx[r_] - mx, dy = ny[r_] - my, dz = nz[r_] - mz;
        c00 += dx * dx; c01 += dx * dy; c02 += dx * dz;
        c11 += dy * dy; c12 += dy * dz; c22 += dz * dz;
    }
    if (lane == 0) {
        float* hb = h0 + (size_t)b * 12 * N_;
        hb[0 * N_ + i] = qx;
        hb[1 * N_ + i] = qy;
        hb[2 * N_ + i] = qz;
        hb[3 * N_ + i] = c00; hb[4 * N_ + i] = c01; hb[5 * N_ + i] = c02;
        hb[6 * N_ + i] = c01; hb[7 * N_ + i] = c11; hb[8 * N_ + i] = c12;
        hb[9 * N_ + i] = c02; hb[10 * N_ + i] = c12; hb[11 * N_ + i] = c22;
    }
}

// ---------------------------------------------------------------------------
// Old fp32 GEMM (conv1: C=12 needs bounds checks) + fused BN partials.
// ---------------------------------------------------------------------------
__global__ __launch_bounds__(256) void gemm_kernel(const float* __restrict__ A,
                                                   const float* __restrict__ X,
                                                   const float* __restrict__ bias,
                                                   float* __restrict__ Y,
                                                   int O, int C,
                                                   float* __restrict__ part) {
    __shared__ float Wt[16][132];
    __shared__ float Xt[16][132];
    const int N = N_;
    int b = blockIdx.z;
    int oB = blockIdx.y * 128, nB = blockIdx.x * 128;
    const float* Xb = X + (size_t)b * C * N;
    int tid = threadIdx.x;
    int tn = tid & 15, to = tid >> 4;

    float acc[8][8];
#pragma unroll
    for (int i = 0; i < 8; i++)
#pragma unroll
        for (int j = 0; j < 8; j++) acc[i][j] = 0.f;

    for (int c0 = 0; c0 < C; c0 += 16) {
#pragma unroll
        for (int r = 0; r < 8; r++) {
            int e = tid + r * 256;
            int k = e & 15, o = e >> 4;
            float v = 0.f;
            if (c0 + k < C && oB + o < O) v = A[(size_t)(oB + o) * C + c0 + k];
            Wt[k][o] = v;
        }
#pragma unroll
        for (int r = 0; r < 8; r++) {
            int e = tid + r * 256;
            int n = e & 127, k = e >> 7;
            float v = 0.f;
            if (c0 + k < C) v = Xb[(size_t)(c0 + k) * N + nB + n];
            Xt[k][n] = v;
        }
        __syncthreads();
#pragma unroll
        for (int k = 0; k < 16; k++) {
            float a[8], xv[8];
#pragma unroll
            for (int i = 0; i < 8; i++) a[i] = Wt[k][to * 8 + i];
#pragma unroll
            for (int m = 0; m < 4; m++) {
                xv[2 * m] = Xt[k][tn * 2 + 32 * m];
                xv[2 * m + 1] = Xt[k][tn * 2 + 32 * m + 1];
            }
#pragma unroll
            for (int i = 0; i < 8; i++)
#pragma unroll
                for (int j = 0; j < 8; j++) acc[i][j] = fmaf(a[i], xv[j], acc[i][j]);
        }
        __syncthreads();
    }

#pragma unroll
    for (int i = 0; i < 8; i++) {
        int o = oB + to * 8 + i;
        if (o >= O) continue;
        float bv = bias[o];
        float s = 0.f, s2 = 0.f;
#pragma unroll
        for (int m = 0; m < 4; m++) {
            int n0 = nB + tn * 2 + 32 * m;
            float v0 = acc[i][2 * m] + bv, v1 = acc[i][2 * m + 1] + bv;
            *reinterpret_cast<float2*>(&Y[((size_t)b * O + o) * N + n0]) = make_float2(v0, v1);
            s += v0 + v1;
            s2 = fmaf(v0, v0, fmaf(v1, v1, s2));
        }
#pragma unroll
        for (int msk = 1; msk <= 8; msk <<= 1) {
            s += __shfl_xor(s, msk, 64);
            s2 += __shfl_xor(s2, msk, 64);
        }
        if (tn == 0) {
            float* pp = &part[((size_t)(o * 8 + b) * 16 + blockIdx.x) * 2];
            pp[0] = s; pp[1] = s2;
        }
    }
}

// ---------------------------------------------------------------------------
// BN+ReLU + transpose + f16 two-term split + fused norms.
// raw (z,C,N) fp32 -> Fh/Fl (z,N,C) f16, nrm[z][n] = sum_c (hi+lo)^2.
// NT = C/64 o-tiles processed sequentially per block (deterministic order).
// ---------------------------------------------------------------------------
template <int NT>
__global__ __launch_bounds__(256) void splitbn_kernel(const float* __restrict__ y,
                                                      const float* __restrict__ scale,
                                                      const float* __restrict__ shift,
                                                      _Float16* __restrict__ fh,
                                                      _Float16* __restrict__ fl,
                                                      float* __restrict__ nrm) {
    const int O = NT * 64;
    __shared__ float tile[64][65];
    __shared__ float np[64][8];
    int b = blockIdx.z;
    int n0 = blockIdx.x * 64;
    int t = threadIdx.x;
    float ps[2] = {0.f, 0.f};

#pragma unroll
    for (int ot = 0; ot < NT; ot++) {
        int o0 = ot * 64;
        if (ot) __syncthreads();
#pragma unroll
        for (int rr = 0; rr < 16; rr++) {
            int ol = rr * 4 + (t >> 6), nl = t & 63;
            float v = y[((size_t)b * O + o0 + ol) * N_ + n0 + nl];
            v = fmaf(v, scale[o0 + ol], shift[o0 + ol]);
            tile[ol][nl] = fmaxf(v, 0.f);
        }
        __syncthreads();
#pragma unroll
        for (int rr = 0; rr < 2; rr++) {
            int e = t + rr * 256;
            int n = e >> 3, og = (e & 7) * 8;
            f16x8 hv, lv;
            float s = ps[rr];
#pragma unroll
            for (int j = 0; j < 8; j++) {
                float v = tile[og + j][n];
                _Float16 h = (_Float16)v;
                hv[j] = h;
                _Float16 l = (_Float16)(v - (float)h);
                lv[j] = l;
                float vr = (float)h + (float)l;
                s = fmaf(vr, vr, s);
            }
            ps[rr] = s;
            size_t off = ((size_t)b * N_ + n0 + n) * O + o0 + og;
            *reinterpret_cast<uint4*>(&fh[off]) = *reinterpret_cast<uint4*>(&hv);
            *reinterpret_cast<uint4*>(&fl[off]) = *reinterpret_cast<uint4*>(&lv);
        }
    }
    __syncthreads();
#pragma unroll
    for (int rr = 0; rr < 2; rr++) {
        int e = t + rr * 256;
        np[e >> 3][e & 7] = ps[rr];
    }
    __syncthreads();
    if (t < 64) {
        float s = 0.f;
#pragma unroll
        for (int g = 0; g < 8; g++) s += np[t][g];
        nrm[(b << 11) + n0 + t] = s;
    }
}

// ---------------------------------------------------------------------------
// f16-split MFMA distance GEMM (unchanged from R13/R14).
// ---------------------------------------------------------------------------
__global__ __launch_bounds__(256) void dmfma_kernel(const _Float16* __restrict__ Fh,
                                                    const _Float16* __restrict__ Fl,
                                                    const float* __restrict__ nrm,
                                                    float* __restrict__ D, int C) {
    __shared__ __align__(16) char smem[65536];
    _Float16* Ah = (_Float16*)(smem);
    _Float16* Al = (_Float16*)(smem + 16384);
    _Float16* Bh = (_Float16*)(smem + 32768);
    _Float16* Bl = (_Float16*)(smem + 49152);
    float(*Tt)[132] = (float(*)[132])smem;

    int bz = blockIdx.z;
    int t = blockIdx.x;
    int bx = (int)((sqrtf(8.f * (float)t + 1.f) - 1.f) * 0.5f);
    while ((bx + 1) * (bx + 2) / 2 <= t) bx++;
    while (bx * (bx + 1) / 2 > t) bx--;
    int by = t - bx * (bx + 1) / 2;  // by <= bx
    int oB = by * 128, nB = bx * 128;
    const _Float16* Fhb = Fh + (size_t)bz * N_ * C;
    const _Float16* Flb = Fl + (size_t)bz * N_ * C;
    const float* nb = nrm + (size_t)bz * N_;
    float* Db = D + (size_t)bz * N_ * N_;

    int tid = threadIdx.x;
    int lane = tid & 63, w = tid >> 6;
    int wm = w & 1, wn = w >> 1;
    int lr = lane & 15, lg = lane >> 4;
    int lrow = lane >> 3;
    int lcol = ((lane & 7) ^ lrow) * 8;

    f32x4 acc[4][4];
#pragma unroll
    for (int m = 0; m < 4; m++)
#pragma unroll
        for (int n = 0; n < 4; n++) acc[m][n] = (f32x4){0.f, 0.f, 0.f, 0.f};

    for (int c0 = 0; c0 < C; c0 += 64) {
#pragma unroll
        for (int r = 0; r < 4; r++) {
            int seg = r * 4 + w;
            int row = seg * 8 + lrow;
            const _Float16* gah = &Fhb[(size_t)(oB + row) * C + c0 + lcol];
            const _Float16* gal = &Flb[(size_t)(oB + row) * C + c0 + lcol];
            const _Float16* gbh = &Fhb[(size_t)(nB + row) * C + c0 + lcol];
            const _Float16* gbl = &Flb[(size_t)(nB + row) * C + c0 + lcol];
            __builtin_amdgcn_global_load_lds((glb_u32_t*)gah, (lds_u32_t*)&Ah[seg * 512], 16, 0, 0);
            __builtin_amdgcn_global_load_lds((glb_u32_t*)gal, (lds_u32_t*)&Al[seg * 512], 16, 0, 0);
            __builtin_amdgcn_global_load_lds((glb_u32_t*)gbh, (lds_u32_t*)&Bh[seg * 512], 16, 0, 0);
            __builtin_amdgcn_global_load_lds((glb_u32_t*)gbl, (lds_u32_t*)&Bl[seg * 512], 16, 0, 0);
        }
        __syncthreads();
#pragma unroll
        for (int kk = 0; kk < 2; kk++) {
            f16x8 ah[4], al[4], bh[4], bl[4];
#pragma unroll
            for (int m = 0; m < 4; m++) {
                int row = wm * 64 + m * 16 + lr;
                int slot = (kk * 4 + lg) ^ (lr & 7);
                ah[m] = *reinterpret_cast<const f16x8*>(&Ah[row * 64 + slot * 8]);
                al[m] = *reinterpret_cast<const f16x8*>(&Al[row * 64 + slot * 8]);
            }
#pragma unroll
            for (int n = 0; n < 4; n++) {
                int row = wn * 64 + n * 16 + lr;
                int slot = (kk * 4 + lg) ^ (lr & 7);
                bh[n] = *reinterpret_cast<const f16x8*>(&Bh[row * 64 + slot * 8]);
                bl[n] = *reinterpret_cast<const f16x8*>(&Bl[row * 64 + slot * 8]);
            }
#pragma unroll
            for (int m = 0; m < 4; m++)
#pragma unroll
                for (int n = 0; n < 4; n++) {
                    acc[m][n] = __builtin_amdgcn_mfma_f32_16x16x32_f16(al[m], bh[n], acc[m][n], 0, 0, 0);
                    acc[m][n] = __builtin_amdgcn_mfma_f32_16x16x32_f16(ah[m], bl[n], acc[m][n], 0, 0, 0);
                    acc[m][n] = __builtin_amdgcn_mfma_f32_16x16x32_f16(ah[m], bh[n], acc[m][n], 0, 0, 0);
                }
        }
        __syncthreads();
    }

#pragma unroll
    for (int m = 0; m < 4; m++) {
#pragma unroll
        for (int r = 0; r < 4; r++) {
            int o = oB + wm * 64 + m * 16 + lg * 4 + r;
            float nr_ = nb[o];
#pragma unroll
            for (int n = 0; n < 4; n++) {
                int nv = nB + wn * 64 + n * 16 + lr;
                float val = nr_ + nb[nv] - 2.f * acc[m][n][r];
                unsigned int fk = fflip(val);
                Db[(size_t)o * N_ + nv] = __uint_as_float(fk);
                acc[m][n][r] = __uint_as_float(fk);
            }
        }
    }

    if (bx != by) {
        for (int p = 0; p < 4; p++) {
            __syncthreads();
            if (wm == (p >> 1)) {
#pragma unroll
                for (int mh = 0; mh < 2; mh++) {
                    int m = (p & 1) * 2 + mh;
                    int ib = m * 16 + lg * 4 - (p & 1) * 32;
#pragma unroll
                    for (int n = 0; n < 4; n++) {
                        int j = wn * 64 + n * 16 + lr;
#pragma unroll
                        for (int r = 0; r < 4; r++) Tt[ib + r][j] = acc[m][n][r];
                    }
                }
            }
            __syncthreads();
#pragma unroll
            for (int r = 0; r < 4; r++) {
                int e = tid + r * 256;
                int j = e >> 3, i4 = e & 7;
                float4 v;
                v.x = Tt[i4 * 4 + 0][j];
                v.y = Tt[i4 * 4 + 1][j];
                v.z = Tt[i4 * 4 + 2][j];
                v.w = Tt[i4 * 4 + 3][j];
                *reinterpret_cast<float4*>(&Db[(size_t)(nB + j) * N_ + oB + p * 32 + i4 * 4]) = v;
            }
        }
    }
}

// ---------------------------------------------------------------------------
// Conv fp32 GEMM: 64x64 tile, BK=32, float4 micro-tile cols. (unchanged)
// ---------------------------------------------------------------------------
template <int XLAYOUT, int FUSE, int DUALT>
__global__ __launch_bounds__(256, 4) void cgemm_kernel(const float* __restrict__ A,
                                                       const float* __restrict__ X,
                                                       const float* __restrict__ bias,
                                                       float* __restrict__ Y,
                                                       int O, int C,
                                                       const float* __restrict__ xs,
                                                       const float* __restrict__ xh,
                                                       float* __restrict__ Yt,
                                                       float* __restrict__ part) {
    __shared__ float Wt[32][68];
    __shared__ float Xt[32][68];
    int b = blockIdx.z;
    int oB = blockIdx.y * 64, nB = blockIdx.x * 64;
    const float* Xb = X + (XLAYOUT == 0 ? (size_t)b * C * N_ : (size_t)b * N_ * C);
    int tid = threadIdx.x;
    int tn = tid & 15, to = tid >> 4;

    float acc[4][4];
#pragma unroll
    for (int i = 0; i < 4; i++)
#pragma unroll
        for (int j = 0; j < 4; j++) acc[i][j] = 0.f;

    for (int c0 = 0; c0 < C; c0 += 32) {
#pragma unroll
        for (int r = 0; r < 2; r++) {
            int e = tid + r * 256;
            int row = e >> 3, c4 = e & 7;
            float4 v = *reinterpret_cast<const float4*>(&A[(size_t)(oB + row) * C + c0 + c4 * 4]);
            Wt[c4 * 4 + 0][row] = v.x;
            Wt[c4 * 4 + 1][row] = v.y;
            Wt[c4 * 4 + 2][row] = v.z;
            Wt[c4 * 4 + 3][row] = v.w;
        }
        if (XLAYOUT == 0) {
#pragma unroll
            for (int r = 0; r < 2; r++) {
                int e = tid + r * 256;
                int k = e >> 4, n4 = e & 15;
                float4 v = *reinterpret_cast<const float4*>(&Xb[(size_t)(c0 + k) * N_ + nB + n4 * 4]);
                if (FUSE) {
                    float sc = xs[c0 + k], sh = xh[c0 + k];
                    v.x = fmaxf(fmaf(v.x, sc, sh), 0.f);
                    v.y = fmaxf(fmaf(v.y, sc, sh), 0.f);
                    v.z = fmaxf(fmaf(v.z, sc, sh), 0.f);
                    v.w = fmaxf(fmaf(v.w, sc, sh), 0.f);
                }
                *reinterpret_cast<float4*>(&Xt[k][n4 * 4]) = v;
            }
        } else {
#pragma unroll
            for (int r = 0; r < 2; r++) {
                int e = tid + r * 256;
                int n = e >> 3, c4 = e & 7;
                float4 v = *reinterpret_cast<const float4*>(&Xb[(size_t)(nB + n) * C + c0 + c4 * 4]);
                Xt[c4 * 4 + 0][n] = v.x;
                Xt[c4 * 4 + 1][n] = v.y;
                Xt[c4 * 4 + 2][n] = v.z;
                Xt[c4 * 4 + 3][n] = v.w;
            }
        }
        __syncthreads();
#pragma unroll
        for (int k = 0; k < 32; k++) {
            float a[4], xv[4];
            *reinterpret_cast<float4*>(&a[0]) = *reinterpret_cast<const float4*>(&Wt[k][to * 4]);
            *reinterpret_cast<float4*>(&xv[0]) = *reinterpret_cast<const float4*>(&Xt[k][tn * 4]);
#pragma unroll
            for (int i = 0; i < 4; i++)
#pragma unroll
                for (int j = 0; j < 4; j++) acc[i][j] = fmaf(a[i], xv[j], acc[i][j]);
        }
        __syncthreads();
    }

    float fin[4][4];
#pragma unroll
    for (int i = 0; i < 4; i++) {
        float bv = bias[oB + to * 4 + i];
#pragma unroll
        for (int j = 0; j < 4; j++) fin[i][j] = acc[i][j] + bv;
    }
#pragma unroll
    for (int i = 0; i < 4; i++) {
        int o = oB + to * 4 + i;
        int n0 = nB + tn * 4;
        float4 st;
        st.x = fin[i][0]; st.y = fin[i][1]; st.z = fin[i][2]; st.w = fin[i][3];
        *reinterpret_cast<float4*>(&Y[((size_t)b * O + o) * N_ + n0]) = st;
    }
    if (DUALT) {
#pragma unroll
        for (int j = 0; j < 4; j++) {
            int n = nB + tn * 4 + j;
            float4 st;
            st.x = fin[0][j]; st.y = fin[1][j]; st.z = fin[2][j]; st.w = fin[3][j];
            *reinterpret_cast<float4*>(&Yt[((size_t)b * N_ + n) * (size_t)O + oB + to * 4]) = st;
        }
    }
#pragma unroll
    for (int i = 0; i < 4; i++) {
        float s = (fin[i][0] + fin[i][1]) + (fin[i][2] + fin[i][3]);
        float s2 = fmaf(fin[i][0], fin[i][0], fmaf(fin[i][1], fin[i][1],
                   fmaf(fin[i][2], fin[i][2], fin[i][3] * fin[i][3])));
#pragma unroll
        for (int msk = 1; msk <= 8; msk <<= 1) {
            s += __shfl_xor(s, msk, 64);
            s2 += __shfl_xor(s2, msk, 64);
        }
        if (tn == 0) {
            int o = oB + to * 4 + i;
            float* pp = &part[((size_t)(o * 8 + b) * 32 + blockIdx.x) * 2];
            pp[0] = s; pp[1] = s2;
        }
    }
}

// ---------------------------------------------------------------------------
// bf16 MFMA GEMM (value path).
// EPI=1 (conv4): no bias/Y — per-block (max,min,sum,sumsq) partials.
// EPI=2 (g2): Yh = transposed RAW bf16 (B,N,O) with bias; (sum,sumsq)
//             partials from exact fp32 accumulators.
// ---------------------------------------------------------------------------
template <int EPI>
__global__ __launch_bounds__(256) void mgemm_kernel(const unsigned short* __restrict__ A,
                                                    const unsigned short* __restrict__ X,
                                                    const float* __restrict__ bias,
                                                    unsigned short* __restrict__ Yh,
                                                    int O, int C,
                                                    float* __restrict__ part) {
    __shared__ unsigned short At[128 * 64];
    __shared__ unsigned short Bt[128 * 64];
    __shared__ float sred[2][2][64][4];
    int b = blockIdx.z;
    int oB = blockIdx.y * 128, nB = blockIdx.x * 128;
    const unsigned short* Xb = X + (size_t)b * N_ * C;
    int tid = threadIdx.x;
    int lane = tid & 63, w = tid >> 6;
    int wm = w & 1, wn = w >> 1;
    int lr = lane & 15, lg = lane >> 4;
    int lrow = lane >> 3;
    int lcol = ((lane & 7) ^ lrow) * 8;

    f32x4 acc[4][4];
#pragma unroll
    for (int m = 0; m < 4; m++)
#pragma unroll
        for (int n = 0; n < 4; n++) acc[m][n] = (f32x4){0.f, 0.f, 0.f, 0.f};

    for (int c0 = 0; c0 < C; c0 += 64) {
#pragma unroll
        for (int r = 0; r < 4; r++) {
            int seg = r * 4 + w;
            int row = seg * 8 + lrow;
            const unsigned short* ga = &A[(size_t)(oB + row) * C + c0 + lcol];
            const unsigned short* gb = &Xb[(size_t)(nB + row) * C + c0 + lcol];
            __builtin_amdgcn_global_load_lds((glb_u32_t*)ga, (lds_u32_t*)&At[seg * 512], 16, 0, 0);
            __builtin_amdgcn_global_load_lds((glb_u32_t*)gb, (lds_u32_t*)&Bt[seg * 512], 16, 0, 0);
        }
        __syncthreads();
#pragma unroll
        for (int kk = 0; kk < 2; kk++) {
            bf16x8 af[4], bfv[4];
#pragma unroll
            for (int m = 0; m < 4; m++) {
                int row = wm * 64 + m * 16 + lr;
                int slot = (kk * 4 + lg) ^ (lr & 7);
                af[m] = *reinterpret_cast<const bf16x8*>(&At[row * 64 + slot * 8]);
            }
#pragma unroll
            for (int n = 0; n < 4; n++) {
                int row = wn * 64 + n * 16 + lr;
                int slot = (kk * 4 + lg) ^ (lr & 7);
                bfv[n] = *reinterpret_cast<const bf16x8*>(&Bt[row * 64 + slot * 8]);
            }
#pragma unroll
            for (int m = 0; m < 4; m++)
#pragma unroll
                for (int n = 0; n < 4; n++)
                    acc[m][n] = __builtin_amdgcn_mfma_f32_16x16x32_bf16(af[m], bfv[n], acc[m][n], 0, 0, 0);
        }
        __syncthreads();
    }

    if (EPI == 1) {
#pragma unroll
        for (int m = 0; m < 4; m++) {
#pragma unroll
            for (int r = 0; r < 4; r++) {
                float v0 = acc[m][0][r], v1 = acc[m][1][r];
                float v2 = acc[m][2][r], v3 = acc[m][3][r];
                float mx = fmaxf(fmaxf(v0, v1), fmaxf(v2, v3));
                float mn = fminf(fminf(v0, v1), fminf(v2, v3));
                float s = (v0 + v1) + (v2 + v3);
                float s2 = fmaf(v0, v0, fmaf(v1, v1, fmaf(v2, v2, v3 * v3)));
#pragma unroll
                for (int msk = 1; msk <= 8; msk <<= 1) {
                    mx = fmaxf(mx, __shfl_xor(mx, msk, 64));
                    mn = fminf(mn, __shfl_xor(mn, msk, 64));
                    s += __shfl_xor(s, msk, 64);
                    s2 += __shfl_xor(s2, msk, 64);
                }
                if (lr == 0) {
                    int ol = m * 16 + lg * 4 + r;
                    sred[wm][wn][ol][0] = mx;
                    sred[wm][wn][ol][1] = mn;
                    sred[wm][wn][ol][2] = s;
                    sred[wm][wn][ol][3] = s2;
                }
            }
        }
        __syncthreads();
        if (tid < 128) {
            int wmv = tid >> 6, ol = tid & 63;
            float mx = fmaxf(sred[wmv][0][ol][0], sred[wmv][1][ol][0]);
            float mn = fminf(sred[wmv][0][ol][1], sred[wmv][1][ol][1]);
            float s = sred[wmv][0][ol][2] + sred[wmv][1][ol][2];
            float s2 = sred[wmv][0][ol][3] + sred[wmv][1][ol][3];
            int o = oB + wmv * 64 + ol;
            float* pp = &part[((size_t)(o * 8 + b) * 16 + blockIdx.x) * 4];
            pp[0] = mx; pp[1] = mn; pp[2] = s; pp[3] = s2;
        }
    } else {
#pragma unroll
        for (int m = 0; m < 4; m++) {
            int o0 = oB + wm * 64 + m * 16 + lg * 4;
            float4 bv = *reinterpret_cast<const float4*>(&bias[o0]);
            float s[4] = {0.f, 0.f, 0.f, 0.f};
            float s2[4] = {0.f, 0.f, 0.f, 0.f};
#pragma unroll
            for (int n = 0; n < 4; n++) {
                int nv = nB + wn * 64 + n * 16 + lr;
                float v0 = acc[m][n][0] + bv.x;
                float v1 = acc[m][n][1] + bv.y;
                float v2 = acc[m][n][2] + bv.z;
                float v3 = acc[m][n][3] + bv.w;
                uint2 pk;
                pk.x = (unsigned)f2bf(v0) | ((unsigned)f2bf(v1) << 16);
                pk.y = (unsigned)f2bf(v2) | ((unsigned)f2bf(v3) << 16);
                *reinterpret_cast<uint2*>(&Yh[((size_t)b * N_ + nv) * (size_t)O + o0]) = pk;
                s[0] += v0; s2[0] = fmaf(v0, v0, s2[0]);
                s[1] += v1; s2[1] = fmaf(v1, v1, s2[1]);
                s[2] += v2; s2[2] = fmaf(v2, v2, s2[2]);
                s[3] += v3; s2[3] = fmaf(v3, v3, s2[3]);
            }
#pragma unroll
            for (int r = 0; r < 4; r++) {
#pragma unroll
                for (int msk = 1; msk <= 8; msk <<= 1) {
                    s[r] += __shfl_xor(s[r], msk, 64);
                    s2[r] += __shfl_xor(s2[r], msk, 64);
                }
                if (lr == 0) {
                    int ol = m * 16 + lg * 4 + r;
                    sred[wm][wn][ol][0] = s[r];
                    sred[wm][wn][ol][1] = s2[r];
                }
            }
        }
        __syncthreads();
        if (tid < 128) {
            int wmv = tid >> 6, ol = tid & 63;
            float s = sred[wmv][0][ol][0] + sred[wmv][1][ol][0];
            float s2 = sred[wmv][0][ol][1] + sred[wmv][1][ol][1];
            int o = oB + wmv * 64 + ol;
            float* pp = &part[((size_t)(o * 8 + b) * 16 + blockIdx.x) * 2];
            pp[0] = s; pp[1] = s2;
        }
    }
}

// ---------------------------------------------------------------------------
// Stats finish (16 nb-blocks): reduce 8b x 16nb (sum,sumsq) -> scale/shift.
// ---------------------------------------------------------------------------
__global__ __launch_bounds__(128) void bnfin_kernel(const float* __restrict__ part,
                                                    const float* __restrict__ gm,
                                                    const float* __restrict__ bt,
                                                    float* __restrict__ scale,
                                                    float* __restrict__ shift) {
    int o = blockIdx.x;
    int t = threadIdx.x;  // 128 = 8 b x 16 nb
    const float* p = &part[((size_t)(o * 8 + (t >> 4)) * 16 + (t & 15)) * 2];
    float s = p[0], s2 = p[1];
#pragma unroll
    for (int msk = 1; msk <= 32; msk <<= 1) {
        s += __shfl_xor(s, msk, 64);
        s2 += __shfl_xor(s2, msk, 64);
    }
    __shared__ float red[4];
    int wv = t >> 6, lane = t & 63;
    if (lane == 0) { red[wv] = s; red[2 + wv] = s2; }
    __syncthreads();
    if (t == 0) {
        float S = red[0] + red[1], S2 = red[2] + red[3];
        float mu = S * (1.f / (B_ * N_));
        float var = S2 * (1.f / (B_ * N_)) - mu * mu;
        float inv = 1.f / sqrtf(var + 1e-5f);
        float sc = gm[o] * inv;
        scale[o] = sc;
        shift[o] = fmaf(-mu, sc, bt[o]);
    }
}

// ---------------------------------------------------------------------------
// Stats finish (32 nb-blocks): reduce 8b x 32nb (sum,sumsq) -> scale/shift.
// ---------------------------------------------------------------------------
__global__ __launch_bounds__(256) void bnfin32_kernel(const float* __restrict__ part,
                                                      const float* __restrict__ gm,
                                                      const float* __restrict__ bt,
                                                      float* __restrict__ scale,
                                                      float* __restrict__ shift) {
    int o = blockIdx.x;
    int t = threadIdx.x;  // 256 = 8 b x 32 nb
    const float* p = &part[((size_t)(o * 8 + (t >> 5)) * 32 + (t & 31)) * 2];
    float s = p[0], s2 = p[1];
#pragma unroll
    for (int msk = 1; msk <= 32; msk <<= 1) {
        s += __shfl_xor(s, msk, 64);
        s2 += __shfl_xor(s2, msk, 64);
    }
    __shared__ float red[8];
    int wv = t >> 6, lane = t & 63;
    if (lane == 0) { red[wv] = s; red[4 + wv] = s2; }
    __syncthreads();
    if (t == 0) {
        float S = (red[0] + red[1]) + (red[2] + red[3]);
        float S2 = (red[4] + red[5]) + (red[6] + red[7]);
        float mu = S * (1.f / (B_ * N_));
        float var = S2 * (1.f / (B_ * N_)) - mu * mu;
        float inv = 1.f / sqrtf(var + 1e-5f);
        float sc = gm[o] * inv;
        scale[o] = sc;
        shift[o] = fmaf(-mu, sc, bt[o]);
    }
}

// ---------------------------------------------------------------------------
// g2 apply: raw bf16 (B,N,1024) -> BN+ReLU -> bf16 (B,N,1024). Elementwise.
// ---------------------------------------------------------------------------
__global__ __launch_bounds__(256) void applycvt_kernel(const unsigned short* __restrict__ yh,
                                                       const float* __restrict__ scale,
                                                       const float* __restrict__ shift,
                                                       unsigned short* __restrict__ outh) {
    size_t i = ((size_t)blockIdx.x * 256 + threadIdx.x) * 8;
    int o = (int)(i & 1023u);
    uint4 v = *reinterpret_cast<const uint4*>(&yh[i]);
    float4 s0 = *reinterpret_cast<const float4*>(&scale[o]);
    float4 s1 = *reinterpret_cast<const float4*>(&scale[o + 4]);
    float4 h0 = *reinterpret_cast<const float4*>(&shift[o]);
    float4 h1 = *reinterpret_cast<const float4*>(&shift[o + 4]);
    unsigned int wv[4] = {v.x, v.y, v.z, v.w};
    float sc[8] = {s0.x, s0.y, s0.z, s0.w, s1.x, s1.y, s1.z, s1.w};
    float sh[8] = {h0.x, h0.y, h0.z, h0.w, h1.x, h1.y, h1.z, h1.w};
    unsigned short u[8];
#pragma unroll
    for (int q = 0; q < 4; q++) {
        float lo = __uint_as_float(wv[q] << 16);
        float hi = __uint_as_float(wv[q] & 0xffff0000u);
        u[2 * q] = f2bf(fmaxf(fmaf(lo, sc[2 * q], sh[2 * q]), 0.f));
        u[2 * q + 1] = f2bf(fmaxf(fmaf(hi, sc[2 * q + 1], sh[2 * q + 1]), 0.f));
    }
    uint4 pk;
    pk.x = (unsigned)u[0] | ((unsigned)u[1] << 16);
    pk.y = (unsigned)u[2] | ((unsigned)u[3] << 16);
    pk.z = (unsigned)u[4] | ((unsigned)u[5] << 16);
    pk.w = (unsigned)u[6] | ((unsigned)u[7] << 16);
    *reinterpret_cast<uint4*>(&outh[i]) = pk;
}

// ---------------------------------------------------------------------------
// conv4 finish: reduce partials -> BN stats; out = scale*max+shift (min if <0).
// ---------------------------------------------------------------------------
__global__ __launch_bounds__(128) void bnmax_kernel(const float* __restrict__ part,
                                                    const float* __restrict__ gm,
                                                    const float* __restrict__ bt,
                                                    float* __restrict__ out) {
    int o = blockIdx.x;
    int t = threadIdx.x;          // 128 = 8 b x 16 nb
    int b = t >> 4, nb = t & 15;
    const float* p = &part[((size_t)(o * 8 + b) * 16 + nb) * 4];
    float mx = p[0], mn = p[1], s = p[2], s2 = p[3];

    float ss = s, ss2 = s2;
#pragma unroll
    for (int msk = 1; msk <= 32; msk <<= 1) {
        ss += __shfl_xor(ss, msk, 64);
        ss2 += __shfl_xor(ss2, msk, 64);
    }
    __shared__ float red[4];
    int wv = t >> 6, lane = t & 63;
    if (lane == 0) { red[wv] = ss; red[2 + wv] = ss2; }
    __syncthreads();
    float S = red[0] + red[1], S2 = red[2] + red[3];
    float mu = S * (1.f / (B_ * N_));
    float var = S2 * (1.f / (B_ * N_)) - mu * mu;
    float inv = 1.f / sqrtf(var + 1e-5f);
    float sc = gm[o] * inv;
    float sh = fmaf(-mu, sc, bt[o]);

#pragma unroll
    for (int msk = 1; msk <= 8; msk <<= 1) {
        mx = fmaxf(mx, __shfl_xor(mx, msk, 64));
        mn = fminf(mn, __shfl_xor(mn, msk, 64));
    }
    if (nb == 0) out[b * 512 + o] = fmaf(sc, sc >= 0.f ? mx : mn, sh);
}

// ---------------------------------------------------------------------------
// Top-16 per row of an (NB*2048) x 2048 distance block (PRE-FLIPPED u32 keys).
// ---------------------------------------------------------------------------
__global__ __launch_bounds__(256, 4) void topk_kernel(const float* __restrict__ D,
                                                      int* __restrict__ idx) {
    int wave = threadIdx.x >> 6, lane = threadIdx.x & 63;
    int i = blockIdx.x * 4 + wave;
    const unsigned int* dp = (const unsigned int*)(D + (size_t)i * N_);

    unsigned long long kA[16], kB[16];
#pragma unroll
    for (int t = 0; t < 4; t++) {
        uint4 v = *reinterpret_cast<const uint4*>(&dp[t * 256 + lane * 4]);
        int j0 = t * 256 + lane * 4;
        kA[t * 4 + 0] = ((unsigned long long)v.x << 11) | (unsigned int)(j0 + 0);
        kA[t * 4 + 1] = ((unsigned long long)v.y << 11) | (unsigned int)(j0 + 1);
        kA[t * 4 + 2] = ((unsigned long long)v.z << 11) | (unsigned int)(j0 + 2);
        kA[t * 4 + 3] = ((unsigned long long)v.w << 11) | (unsigned int)(j0 + 3);
    }
#pragma unroll
    for (int t = 4; t < 8; t++) {
        uint4 v = *reinterpret_cast<const uint4*>(&dp[t * 256 + lane * 4]);
        int j0 = t * 256 + lane * 4;
        kB[(t - 4) * 4 + 0] = ((unsigned long long)v.x << 11) | (unsigned int)(j0 + 0);
        kB[(t - 4) * 4 + 1] = ((unsigned long long)v.y << 11) | (unsigned int)(j0 + 1);
        kB[(t - 4) * 4 + 2] = ((unsigned long long)v.z << 11) | (unsigned int)(j0 + 2);
        kB[(t - 4) * 4 + 3] = ((unsigned long long)v.w << 11) | (unsigned int)(j0 + 3);
    }

    unsigned long long q[16];
    TOP16OF32(kA, kB, q);

    int* op = idx + (size_t)i * KNN;
    EXTRACT16(q, op);
}

// ---------------------------------------------------------------------------
// Gather 16 neighbor RAW fp32 rows (B,N,C), apply BN+ReLU, max -> fp32.
// ---------------------------------------------------------------------------
__global__ __launch_bounds__(256) void gathermax_kernel(const float* __restrict__ ftraw,
                                                        const int* __restrict__ idx,
                                                        const float* __restrict__ scale,
                                                        const float* __restrict__ shift,
                                                        float* __restrict__ out, int cLog) {
    int C = 1 << cLog;
    int b = blockIdx.y;
    int nb = (blockIdx.x << (8 - cLog)) + (threadIdx.x >> cLog);
    int c = threadIdx.x & (C - 1);
    float sc = scale[c], sh = shift[c];
    const int* ip = idx + (((size_t)b << 11) + nb) * KNN;
    float m = -3.4e38f;
#pragma unroll
    for (int k = 0; k < KNN; k++) {
        int j = ip[k];
        float v = ftraw[(((size_t)b << 11) + j) * C + c];
        m = fmaxf(m, fmaxf(fmaf(v, sc, sh), 0.f));
    }
    out[(((size_t)b << 11) + nb) * C + c] = m;
}

// ---------------------------------------------------------------------------
// Gather-max: RAW fp32 (B,N,128) in, BN+ReLU per element, max -> bf16.
// ---------------------------------------------------------------------------
__global__ __launch_bounds__(256) void gmaxh2_kernel(const float* __restrict__ ftraw,
                                                     const int* __restrict__ idx,
                                                     const float* __restrict__ scale,
                                                     const float* __restrict__ shift,
                                                     unsigned short* __restrict__ out) {
    const int C = 128;
    int b = blockIdx.y;
    int nb = blockIdx.x * 16 + (threadIdx.x >> 4);
    int cc = (threadIdx.x & 15) * 8;
    float4 s0 = *reinterpret_cast<const float4*>(&scale[cc]);
    float4 s1 = *reinterpret_cast<const float4*>(&scale[cc + 4]);
    float4 h0 = *reinterpret_cast<const float4*>(&shift[cc]);
    float4 h1 = *reinterpret_cast<const float4*>(&shift[cc + 4]);
    const int* ip = idx + (((size_t)b << 11) + nb) * KNN;
    float m[8];
#pragma unroll
    for (int q = 0; q < 8; q++) m[q] = -3.4e38f;
#pragma unroll
    for (int k = 0; k < KNN; k++) {
        int j = ip[k];
        const float* p = &ftraw[(((size_t)b << 11) + j) * C + cc];
        float4 a = *reinterpret_cast<const float4*>(p);
        float4 c2 = *reinterpret_cast<const float4*>(p + 4);
        m[0] = fmaxf(m[0], fmaxf(fmaf(a.x, s0.x, h0.x), 0.f));
        m[1] = fmaxf(m[1], fmaxf(fmaf(a.y, s0.y, h0.y), 0.f));
        m[2] = fmaxf(m[2], fmaxf(fmaf(a.z, s0.z, h0.z), 0.f));
        m[3] = fmaxf(m[3], fmaxf(fmaf(a.w, s0.w, h0.w), 0.f));
        m[4] = fmaxf(m[4], fmaxf(fmaf(c2.x, s1.x, h1.x), 0.f));
        m[5] = fmaxf(m[5], fmaxf(fmaf(c2.y, s1.y, h1.y), 0.f));
        m[6] = fmaxf(m[6], fmaxf(fmaf(c2.z, s1.z, h1.z), 0.f));
        m[7] = fmaxf(m[7], fmaxf(fmaf(c2.w, s1.w, h1.w), 0.f));
    }
    unsigned short u[8];
#pragma unroll
    for (int q = 0; q < 8; q++) u[q] = f2bf(m[q]);
    uint4 pk;
    pk.x = (unsigned)u[0] | ((unsigned)u[1] << 16);
    pk.y = (unsigned)u[2] | ((unsigned)u[3] << 16);
    pk.z = (unsigned)u[4] | ((unsigned)u[5] << 16);
    pk.w = (unsigned)u[6] | ((unsigned)u[7] << 16);
    *reinterpret_cast<uint4*>(&out[(((size_t)b << 11) + nb) * C + cc]) = pk;
}

// ---------------------------------------------------------------------------
// fp32 -> bf16 weight conversion (both value-path weight arrays, one launch)
// ---------------------------------------------------------------------------
__global__ __launch_bounds__(256) void wcvt2_kernel(const float* __restrict__ w1,
                                                    unsigned short* __restrict__ o1, int c1,
                                                    const float* __restrict__ w2,
                                                    unsigned short* __restrict__ o2, int c2) {
    int i = blockIdx.x * 256 + threadIdx.x;
    if (i < c1) o1[i] = f2bf(w1[i]);
    else if (i < c1 + c2) o2[i - c1] = f2bf(w2[i - c1]);
}

// ---------------------------------------------------------------------------
extern "C" void kernel_launch(void* const* d_in, const int* in_sizes, int n_in,
                              void* d_out, int out_size, void* d_ws, size_t ws_size,
                              hipStream_t stream) {
    const float* x = (const float*)d_in[0];
    const float* W1 = (const float*)d_in[1];
    const float* b1 = (const float*)d_in[2];
    const float* gm1 = (const float*)d_in[3];
    const float* bt1 = (const float*)d_in[4];
    const float* W2 = (const float*)d_in[5];
    const float* b2 = (const float*)d_in[6];
    const float* gm2 = (const float*)d_in[7];
    const float* bt2 = (const float*)d_in[8];
    const float* W3 = (const float*)d_in[9];
    const float* b3 = (const float*)d_in[10];
    const float* gm3 = (const float*)d_in[11];
    const float* bt3 = (const float*)d_in[12];
    const float* Wg1 = (const float*)d_in[13];
    const float* bg1 = (const float*)d_in[14];
    const float* gmg1 = (const float*)d_in[15];
    const float* btg1 = (const float*)d_in[16];
    const float* Wg2 = (const float*)d_in[17];
    const float* bg2 = (const float*)d_in[18];
    const float* gmg2 = (const float*)d_in[19];
    const float* btg2 = (const float*)d_in[20];
    const float* W4 = (const float*)d_in[21];
    const float* b4 = (const float*)d_in[22];
    const float* gm4 = (const float*)d_in[23];
    const float* bt4 = (const float*)d_in[24];
    float* out = (float*)d_out;
    (void)b4;

    // ---- workspace arena (byte offsets), total 154,214,400 bytes ----
    if (ws_size < 154214400ull) return;
    char* base = (char*)d_ws;
    float* scale = (float*)(base + 0);
    float* shift = (float*)(base + 4096);
    float* nrm = (float*)(base + 8192);      // 64KB; conv1 partials alias this
    float* partC1 = (float*)(base + 8192);   // 64*8*16*2*4 = 64KB exact
    int* idx = (int*)(base + 73728);
    unsigned short* Wg2h = (unsigned short*)(base + 1122304);
    unsigned short* W4h = (unsigned short*)(base + 1384448);
    _Float16* Fh1 = (_Float16*)(base + 2433024);   // (8,2048,64)  2MB
    _Float16* Fl1 = (_Float16*)(base + 4530176);   // (8,2048,64)  2MB
    _Float16* Fh2 = (_Float16*)(base + 6627328);   // (8,2048,128) 4MB
    _Float16* Fl2 = (_Float16*)(base + 10821632);  // (8,2048,128) 4MB
    float* bufC = (float*)(base + 15015936);       // (8,2048,64) raw, 4MB
    // bufD8: layer-1 full 8-batch distance keys (134.2MB, 19.2M..153.4M).
    float* bufD8 = (float*)(base + 19210240);
    float* bufD4 = (float*)(base + 19210240);      // layer-2 4-batch chunks
    unsigned short* bufLrh = (unsigned short*)(base + 19210240); // g2 raw bf16 (post-KNN)
    unsigned short* bufLh = (unsigned short*)(base + 86319104);  // g2 BN'd bf16
    char* E = base + 119873536;
    float* partC = (float*)(E + 0);                // conv2/3/g1 partials (512KB)
    float* h0 = (float*)(E + 0);                   // conv1 input (dead after conv1)
    float* bufA = (float*)(E + 786432);            // (8,64,2048) raw
    float* bufB = (float*)(E + 4980736);           // (8,64,2048)
    float* bufM1 = (float*)(E + 13369344);         // (8,128,2048) raw
    float* bufM2 = (float*)(E + 21757952);         // (8,2048,128) raw
    unsigned short* bufM3h = (unsigned short*)(E + 30146560);   // bf16
    float* part = (float*)(E + 0);                 // mgemm partials (dead bufs)

    // weight conversion (value-path weights, single launch)
    wcvt2_kernel<<<2560, 256, 0, stream>>>(Wg2, Wg2h, 1024 * 128, W4, W4h, 512 * 1024);

    // Stage 0/1: 3D KNN + fused covariance features (idx output dropped)
    knn3_kernel<<<dim3(512, 8), 256, 0, stream>>>(x, h0);

    // conv1: 12 -> 64 (fp32) + fused BN1 partials
    gemm_kernel<<<dim3(16, 1, 8), 256, 0, stream>>>(W1, h0, b1, bufA, 64, 12, partC1);
    bnfin_kernel<<<64, 128, 0, stream>>>(partC1, gm1, bt1, scale, shift);

    // conv2: 64 -> 64 (BN1+ReLU fused on load) + BN2 partials
    cgemm_kernel<0, 1, 0><<<dim3(32, 1, 8), 256, 0, stream>>>(W2, bufA, b2, bufB, 64, 64, scale, shift, nullptr, partC);
    bnfin32_kernel<<<64, 256, 0, stream>>>(partC, gm2, bt2, scale, shift);

    // conv3: 64 -> 64 (BN2+ReLU fused) -> raw bufA + raw bufC + BN3 partials
    cgemm_kernel<0, 1, 1><<<dim3(32, 1, 8), 256, 0, stream>>>(W3, bufB, b3, bufA, 64, 64, scale, shift, bufC, partC);
    bnfin32_kernel<<<64, 256, 0, stream>>>(partC, gm3, bt3, scale, shift);

    // graph layer 1 KNN: split+norms fused, single 8-batch MFMA dist + topk
    splitbn_kernel<1><<<dim3(32, 1, 8), 256, 0, stream>>>(bufA, scale, shift, Fh1, Fl1, nrm);
    dmfma_kernel<<<dim3(136, 1, 8), 256, 0, stream>>>(Fh1, Fl1, nrm, bufD8, 64);
    topk_kernel<<<4096, 256, 0, stream>>>(bufD8, idx);
    gathermax_kernel<<<dim3(512, 8), 256, 0, stream>>>(bufC, idx, scale, shift, bufB, 6);

    // conv g1: 64 -> 128 -> raw bufM1 + raw bufM2 + BNg1 partials
    cgemm_kernel<1, 0, 1><<<dim3(32, 2, 8), 256, 0, stream>>>(Wg1, bufB, bg1, bufM1, 128, 64, nullptr, nullptr, bufM2, partC);
    bnfin32_kernel<<<128, 256, 0, stream>>>(partC, gmg1, btg1, scale, shift);

    // graph layer 2 KNN: split+norms fused + 2-chunk MFMA dist (bufM2 must
    // survive until gmaxh2, so bufD stays 4-batch / 67MB)
    splitbn_kernel<2><<<dim3(32, 1, 8), 256, 0, stream>>>(bufM1, scale, shift, Fh2, Fl2, nrm);
    for (int c = 0; c < 2; c++) {
        dmfma_kernel<<<dim3(136, 1, 4), 256, 0, stream>>>(
            Fh2 + (size_t)c * 4 * N_ * 128, Fl2 + (size_t)c * 4 * N_ * 128,
            nrm + (size_t)c * 4 * N_, bufD4, 128);
        topk_kernel<<<2048, 256, 0, stream>>>(bufD4, idx + (size_t)c * 4 * N_ * KNN);
    }
    gmaxh2_kernel<<<dim3(128, 8), 256, 0, stream>>>(bufM2, idx, scale, shift, bufM3h);

    // conv g2: 128 -> 1024 (bf16 MFMA, raw bf16 transposed out + fused stats)
    mgemm_kernel<2><<<dim3(16, 8, 8), 256, 0, stream>>>(Wg2h, bufM3h, bg2, bufLrh, 1024, 128, part);
    bnfin_kernel<<<1024, 128, 0, stream>>>(part, gmg2, btg2, scale, shift);
    applycvt_kernel<<<8192, 256, 0, stream>>>(bufLrh, scale, shift, bufLh);

    // conv4: 1024 -> 512 (bf16 MFMA, fused BN-stats+max epilogue)
    mgemm_kernel<1><<<dim3(16, 4, 8), 256, 0, stream>>>(W4h, bufLh, nullptr, nullptr, 512, 1024, part);
    bnmax_kernel<<<512, 128, 0, stream>>>(part, gm4, bt4, out);
}